// Round 3
// baseline (571.091 us; speedup 1.0000x reference)
//
#include <hip/hip_runtime.h>
#include <hip/hip_bf16.h>

// Problem constants (match reference)
constexpr int N    = 8192;     // nodes
constexpr int E    = 131072;   // node-graph edges == trace rows
constexpr int E2   = 524288;   // line-graph edges

constexpr size_t XT_OFF  = (size_t)N * 128;
constexpr size_t XLG_OFF = XT_OFF + (size_t)E * 128;

typedef unsigned short u16;
typedef short s16x8 __attribute__((ext_vector_type(8)));
typedef float f32x4 __attribute__((ext_vector_type(4)));

__device__ __forceinline__ u16 f2bs(float f) {   // f32 -> bf16 bits, RNE
    unsigned x = __float_as_uint(f);
    return (u16)((x + 0x7FFF + ((x >> 16) & 1)) >> 16);
}
__device__ __forceinline__ float bs2f(u16 u) {
    return __uint_as_float((unsigned)u << 16);
}

// ---------------------------------------------------------------------------
// K0: weight pre-transpose f32 [K,N] -> bf16 [N,K] (one launch, all 6 mats)
__global__ __launch_bounds__(256) void k_prep(
    const float* __restrict__ Wl, const float* __restrict__ Wr,
    const float* __restrict__ We, const float* __restrict__ Wl2,
    const float* __restrict__ Wr2, const float* __restrict__ We2,
    u16* __restrict__ Wlt, u16* __restrict__ Wrt, u16* __restrict__ Wet,
    u16* __restrict__ Wl2t, u16* __restrict__ Wr2t, u16* __restrict__ We2t)
{
    const int gid = blockIdx.x * 256 + threadIdx.x;
    const float* src; u16* dst; int base, Kk, sh;
    if      (gid <  65536) { src = Wl;  dst = Wlt;  base = 0;      Kk = 256; sh = 8; }
    else if (gid < 131072) { src = Wr;  dst = Wrt;  base = 65536;  Kk = 256; sh = 8; }
    else if (gid < 163840) { src = We;  dst = Wet;  base = 131072; Kk = 128; sh = 8; }
    else if (gid < 180224) { src = Wl2; dst = Wl2t; base = 163840; Kk = 128; sh = 7; }
    else if (gid < 196608) { src = Wr2; dst = Wr2t; base = 180224; Kk = 128; sh = 7; }
    else                   { src = We2; dst = We2t; base = 196608; Kk = 256; sh = 7; }
    const int l = gid - base;
    const int k = l >> sh, nn = l & ((1 << sh) - 1);
    dst[(size_t)nn * Kk + k] = f2bs(src[l]);
}

// ---------------------------------------------------------------------------
// CSR build: histogram -> single-block scan (shfl) -> scatter
__global__ void k_hist(const int* __restrict__ dst, int* __restrict__ cnt, int nE)
{
    int i = blockIdx.x * 256 + threadIdx.x;
    if (i < nE) atomicAdd(&cnt[dst[i]], 1);
}

__global__ __launch_bounds__(256) void k_scan(
    const int* __restrict__ cnt, int* __restrict__ off, int* __restrict__ cur, int n)
{
    __shared__ int tile[8192];
    __shared__ int wsum[4];
    const int tid = threadIdx.x, lane = tid & 63, wv = tid >> 6;
    int carry = 0;
    for (int base = 0; base < n; base += 8192) {
        for (int i = tid; i < 8192; i += 256) tile[i] = cnt[base + i];
        __syncthreads();
        const int st = tid * 32;
        int s = 0;
        for (int k = 0; k < 32; ++k) { int v = tile[st + k]; tile[st + k] = s; s += v; }
        const int tsum = s;
        int incl = s;
        for (int o = 1; o < 64; o <<= 1) {
            int v = __shfl_up(incl, o);
            if (lane >= o) incl += v;
        }
        if (lane == 63) wsum[wv] = incl;
        __syncthreads();
        int woff = 0;
        for (int wq = 0; wq < wv; ++wq) woff += wsum[wq];
        const int tot = wsum[0] + wsum[1] + wsum[2] + wsum[3];
        const int add = carry + woff + incl - tsum;
        for (int k = 0; k < 32; ++k) {
            int o2 = add + tile[st + k];
            off[base + st + k] = o2;
            cur[base + st + k] = o2;
        }
        carry += tot;
        __syncthreads();
    }
    if (tid == 0) off[n] = carry;
}

__global__ void k_scatter(const int* __restrict__ dst, int* __restrict__ cur,
                          int* __restrict__ eid, int nE)
{
    int i = blockIdx.x * 256 + threadIdx.x;
    if (i < nE) {
        int pos = atomicAdd(&cur[dst[i]], 1);
        eid[pos] = i;
    }
}

// ---------------------------------------------------------------------------
// K1 (MFMA): xl_n/xr_n = concat(x_node,x_log) @ {Wl,Wr} + bias -> bf16 [N,256]
__global__ __launch_bounds__(256) void k_node_gemm(
    const float* __restrict__ x_node, const float* __restrict__ x_log,
    const u16* __restrict__ Wlt, const float* __restrict__ bl,
    const u16* __restrict__ Wrt, const float* __restrict__ br,
    u16* __restrict__ xl, u16* __restrict__ xr)
{
    __shared__ u16 A[32][260];
    const int n0 = blockIdx.x * 32;
    const int tid = threadIdx.x;
    // vectorized f32x4 staging (G13)
    for (int i = tid; i < 32 * 64; i += 256) {
        const int r = i >> 6, k4 = (i & 63) << 2;
        const float* srcp = (k4 < 128) ? &x_node[(size_t)(n0 + r) * 128 + k4]
                                       : &x_log [(size_t)(n0 + r) * 128 + (k4 - 128)];
        const float4 v = *(const float4*)srcp;
        ushort4 o; o.x = f2bs(v.x); o.y = f2bs(v.y); o.z = f2bs(v.z); o.w = f2bs(v.w);
        *(ushort4*)&A[r][k4] = o;
    }
    __syncthreads();
    const int w = tid >> 6, lane = tid & 63, lr = lane & 15, lq = lane >> 4;
    const u16* Wt     = (w < 2) ? Wlt : Wrt;
    const float* bias = (w < 2) ? bl : br;
    u16* outp         = (w < 2) ? xl : xr;
    const int cb = (w & 1) * 128;
    f32x4 acc[2][8] = {};
    for (int kb = 0; kb < 8; ++kb) {
        s16x8 afr0 = *(const s16x8*)&A[lr][kb * 32 + lq * 8];
        s16x8 afr1 = *(const s16x8*)&A[16 + lr][kb * 32 + lq * 8];
#pragma unroll
        for (int ct = 0; ct < 8; ++ct) {
            const int n = cb + ct * 16 + lr;
            s16x8 bfr = *(const s16x8*)&Wt[(size_t)n * 256 + kb * 32 + lq * 8];
            acc[0][ct] = __builtin_amdgcn_mfma_f32_16x16x32_bf16(afr0, bfr, acc[0][ct], 0, 0, 0);
            acc[1][ct] = __builtin_amdgcn_mfma_f32_16x16x32_bf16(afr1, bfr, acc[1][ct], 0, 0, 0);
        }
    }
#pragma unroll
    for (int rt = 0; rt < 2; ++rt)
#pragma unroll
        for (int ct = 0; ct < 8; ++ct) {
            const int col = cb + ct * 16 + lr;
            const float bv = bias[col];
#pragma unroll
            for (int reg = 0; reg < 4; ++reg) {
                const int row = n0 + rt * 16 + lq * 4 + reg;
                outp[(size_t)row * 256 + col] = f2bs(acc[rt][ct][reg] + bv);
            }
        }
}

// ---------------------------------------------------------------------------
// K2 (MFMA): xl_e = trace@Wl2+bl2 (bf16) ; xr_e = trace@Wr2+br2 -> bf16 staged
// row-local in the out-XT region (first 256 B of each row's 512 B f32 span).
__global__ __launch_bounds__(256) void k_trace_gemm(
    const float* __restrict__ x_trace,
    const u16* __restrict__ Wl2t, const float* __restrict__ bl,
    const u16* __restrict__ Wr2t, const float* __restrict__ br,
    u16* __restrict__ xl, u16* __restrict__ xrst)
{
    __shared__ u16 A[32][132];
    const int e0 = blockIdx.x * 32;
    const int tid = threadIdx.x;
    for (int i = tid; i < 32 * 32; i += 256) {
        const int r = i >> 5, k4 = (i & 31) << 2;
        const float4 v = *(const float4*)&x_trace[(size_t)(e0 + r) * 128 + k4];
        ushort4 o; o.x = f2bs(v.x); o.y = f2bs(v.y); o.z = f2bs(v.z); o.w = f2bs(v.w);
        *(ushort4*)&A[r][k4] = o;
    }
    __syncthreads();
    const int w = tid >> 6, lane = tid & 63, lr = lane & 15, lq = lane >> 4;
    const u16* Wt     = (w < 2) ? Wl2t : Wr2t;
    const float* bias = (w < 2) ? bl : br;
    const int cb = (w & 1) * 64;
    f32x4 acc[2][4] = {};
    for (int kb = 0; kb < 4; ++kb) {
        s16x8 afr0 = *(const s16x8*)&A[lr][kb * 32 + lq * 8];
        s16x8 afr1 = *(const s16x8*)&A[16 + lr][kb * 32 + lq * 8];
#pragma unroll
        for (int ct = 0; ct < 4; ++ct) {
            const int n = cb + ct * 16 + lr;
            s16x8 bfr = *(const s16x8*)&Wt[(size_t)n * 128 + kb * 32 + lq * 8];
            acc[0][ct] = __builtin_amdgcn_mfma_f32_16x16x32_bf16(afr0, bfr, acc[0][ct], 0, 0, 0);
            acc[1][ct] = __builtin_amdgcn_mfma_f32_16x16x32_bf16(afr1, bfr, acc[1][ct], 0, 0, 0);
        }
    }
#pragma unroll
    for (int rt = 0; rt < 2; ++rt)
#pragma unroll
        for (int ct = 0; ct < 4; ++ct) {
            const int col = cb + ct * 16 + lr;
            const float bv = bias[col];
#pragma unroll
            for (int reg = 0; reg < 4; ++reg) {
                const int row = e0 + rt * 16 + lq * 4 + reg;
                if (w < 2) xl[(size_t)row * 128 + col]   = f2bs(acc[rt][ct][reg] + bv);
                else       xrst[(size_t)row * 256 + col] = f2bs(acc[rt][ct][reg] + bv);
            }
        }
}

// ---------------------------------------------------------------------------
// K3 (MFMA): fused e-GEMM (trace@We) + layer-1 logits. 32 edges/block.
__global__ __launch_bounds__(256) void k_edge_alpha1(
    const float* __restrict__ x_trace,
    const int* __restrict__ adj,          // [2,E] src then dst
    const u16* __restrict__ xl, const u16* __restrict__ xr,   // [N,256] bf16
    const u16* __restrict__ Wet, const float* __restrict__ att,
    float* __restrict__ alpha)
{
    __shared__ u16 A[32][132];
    __shared__ int ss[32], dd[32];
    const int e0 = blockIdx.x * 32;
    const int tid = threadIdx.x;
    for (int i = tid; i < 32 * 32; i += 256) {
        const int r = i >> 5, k4 = (i & 31) << 2;
        const float4 v = *(const float4*)&x_trace[(size_t)(e0 + r) * 128 + k4];
        ushort4 o; o.x = f2bs(v.x); o.y = f2bs(v.y); o.z = f2bs(v.z); o.w = f2bs(v.w);
        *(ushort4*)&A[r][k4] = o;
    }
    if (tid < 32) { ss[tid] = adj[e0 + tid]; dd[tid] = adj[E + e0 + tid]; }
    __syncthreads();
    const int w = tid >> 6, lane = tid & 63, lr = lane & 15, lq = lane >> 4;
    f32x4 acc[2][4] = {};
    for (int kb = 0; kb < 4; ++kb) {
        s16x8 afr0 = *(const s16x8*)&A[lr][kb * 32 + lq * 8];
        s16x8 afr1 = *(const s16x8*)&A[16 + lr][kb * 32 + lq * 8];
#pragma unroll
        for (int ct = 0; ct < 4; ++ct) {
            const int n = w * 64 + ct * 16 + lr;
            s16x8 bfr = *(const s16x8*)&Wet[(size_t)n * 128 + kb * 32 + lq * 8];
            acc[0][ct] = __builtin_amdgcn_mfma_f32_16x16x32_bf16(afr0, bfr, acc[0][ct], 0, 0, 0);
            acc[1][ct] = __builtin_amdgcn_mfma_f32_16x16x32_bf16(afr1, bfr, acc[1][ct], 0, 0, 0);
        }
    }
    float attv[4];
#pragma unroll
    for (int ct = 0; ct < 4; ++ct) attv[ct] = att[w * 64 + ct * 16 + lr];
    float sums[2][4] = {};
#pragma unroll
    for (int rt = 0; rt < 2; ++rt)
#pragma unroll
        for (int reg = 0; reg < 4; ++reg) {
            const int rowt = rt * 16 + lq * 4 + reg;
            const int s = ss[rowt], d = dd[rowt];
            float acc_s = 0.f;
#pragma unroll
            for (int ct = 0; ct < 4; ++ct) {
                const int col = w * 64 + ct * 16 + lr;
                float m = acc[rt][ct][reg]
                        + bs2f(xl[(size_t)s * 256 + col])
                        + bs2f(xr[(size_t)d * 256 + col]);
                m = m > 0.f ? m : 0.2f * m;
                acc_s += m * attv[ct];
            }
            sums[rt][reg] = acc_s;
        }
#pragma unroll
    for (int rt = 0; rt < 2; ++rt)
#pragma unroll
        for (int reg = 0; reg < 4; ++reg) {
            float p = sums[rt][reg];
            p += __shfl_xor(p, 8);
            p += __shfl_xor(p, 4);
            p += __shfl_xor(p, 2);
            p += __shfl_xor(p, 1);
            if (lr == 0)
                alpha[(size_t)(e0 + rt * 16 + lq * 4 + reg) * 4 + w] = p;
        }
}

// ---------------------------------------------------------------------------
// K4: layer-1 online-softmax + gather. One node per WAVE, 4 dims/lane.
// Predicated batch-8: no scalar tail (invalid slots clamp index, logit=-INF).
__global__ __launch_bounds__(256) void k_fused1(
    const int* __restrict__ adj,
    const int* __restrict__ off, const int* __restrict__ eid,
    const float* __restrict__ alpha,
    const u16* __restrict__ xl,
    const float* __restrict__ bias,
    float* __restrict__ out)
{
    const int wv = __builtin_amdgcn_readfirstlane(threadIdx.x >> 6);
    const int lane = threadIdx.x & 63;
    const int n = blockIdx.x * 4 + wv;
    const int c = lane * 4;            // dims c..c+3
    const int h = lane >> 4;           // head (64 dims / head, 16 lanes / head)
    const int beg = off[n], end = off[n + 1];
    float mx = -INFINITY, den = 0.f;
    float a0 = 0.f, a1 = 0.f, a2 = 0.f, a3 = 0.f;
    int i = beg;
    while (i < end) {
        const int rem = end - i;       // >= 1, wave-uniform
        int ea[8];
#pragma unroll
        for (int k = 0; k < 8; ++k) ea[k] = eid[i + (k < rem ? k : rem - 1)];
        int sa[8];
#pragma unroll
        for (int k = 0; k < 8; ++k) sa[k] = adj[ea[k]];
        float pe[8]; ushort4 xv[8];
#pragma unroll
        for (int k = 0; k < 8; ++k) {
            pe[k] = alpha[(size_t)ea[k] * 4 + h];
            xv[k] = *(const ushort4*)&xl[(size_t)sa[k] * 256 + c];
        }
#pragma unroll
        for (int k = 0; k < 8; ++k) {
            const float p = (k < rem) ? pe[k] : -INFINITY;
            const float mnew = fmaxf(mx, p);
            const float sc = __expf(mx - mnew);
            const float ex = __expf(p - mnew);
            den = den * sc + ex;
            a0 = a0 * sc + ex * bs2f(xv[k].x);
            a1 = a1 * sc + ex * bs2f(xv[k].y);
            a2 = a2 * sc + ex * bs2f(xv[k].z);
            a3 = a3 * sc + ex * bs2f(xv[k].w);
            mx = mnew;
        }
        i += 8;
    }
    const float inv = 1.f / (den + 1e-16f);
    float4 r;
    r.x = a0 * inv + bias[c + 0];
    r.y = a1 * inv + bias[c + 1];
    r.z = a2 * inv + bias[c + 2];
    r.w = a3 * inv + bias[c + 3];
    if (lane < 32) *(float4*)&out[(size_t)n * 128 + c] = r;
    else           *(float4*)&out[XLG_OFF + (size_t)n * 128 + (c - 128)] = r;
}

// ---------------------------------------------------------------------------
// K5 (MFMA): proj = node_out @ e2n_We  [N,128] bf16
__global__ __launch_bounds__(256) void k_proj_gemm(
    const float* __restrict__ out_node, const u16* __restrict__ We2t,  // [128][256]
    u16* __restrict__ proj)
{
    __shared__ u16 A[32][260];
    const int n0 = blockIdx.x * 32;
    const int tid = threadIdx.x;
    for (int i = tid; i < 32 * 64; i += 256) {
        const int r = i >> 6, k4 = (i & 63) << 2;
        const float* srcp = (k4 < 128)
            ? &out_node[(size_t)(n0 + r) * 128 + k4]
            : &out_node[XLG_OFF + (size_t)(n0 + r) * 128 + (k4 - 128)];
        const float4 v = *(const float4*)srcp;
        ushort4 o; o.x = f2bs(v.x); o.y = f2bs(v.y); o.z = f2bs(v.z); o.w = f2bs(v.w);
        *(ushort4*)&A[r][k4] = o;
    }
    __syncthreads();
    const int w = tid >> 6, lane = tid & 63, lr = lane & 15, lq = lane >> 4;
    f32x4 acc[2][2] = {};
    for (int kb = 0; kb < 8; ++kb) {
        s16x8 afr0 = *(const s16x8*)&A[lr][kb * 32 + lq * 8];
        s16x8 afr1 = *(const s16x8*)&A[16 + lr][kb * 32 + lq * 8];
#pragma unroll
        for (int ct = 0; ct < 2; ++ct) {
            const int col = w * 32 + ct * 16 + lr;
            s16x8 bfr = *(const s16x8*)&We2t[(size_t)col * 256 + kb * 32 + lq * 8];
            acc[0][ct] = __builtin_amdgcn_mfma_f32_16x16x32_bf16(afr0, bfr, acc[0][ct], 0, 0, 0);
            acc[1][ct] = __builtin_amdgcn_mfma_f32_16x16x32_bf16(afr1, bfr, acc[1][ct], 0, 0, 0);
        }
    }
#pragma unroll
    for (int rt = 0; rt < 2; ++rt)
#pragma unroll
        for (int ct = 0; ct < 2; ++ct) {
            const int col = w * 32 + ct * 16 + lr;
#pragma unroll
            for (int reg = 0; reg < 4; ++reg) {
                const int row = n0 + rt * 16 + lq * 4 + reg;
                proj[(size_t)row * 128 + col] = f2bs(acc[rt][ct][reg]);
            }
        }
}

// ---------------------------------------------------------------------------
// K6: layer-2 fused logits + online softmax + aggregate. One row per WAVE,
// 2 dims/lane. xr staged bf16 row-local in out-XT (read own row, then
// overwrite own row -> no cross-wave hazard). Predicated batch-8, no tail.
__global__ __launch_bounds__(256) void k_fused2(
    const int* __restrict__ eadj,
    const int* __restrict__ efea,
    const int* __restrict__ off, const int* __restrict__ eid,
    const u16* __restrict__ xl,        // [E,128] trace@Wl2+bl2 bf16
    const u16* __restrict__ proj,      // [N,128] bf16
    const float* __restrict__ att,
    const float* __restrict__ bias,
    float* __restrict__ out)
{
    const int wv = __builtin_amdgcn_readfirstlane(threadIdx.x >> 6);
    const int lane = threadIdx.x & 63;
    const int d = blockIdx.x * 4 + wv;
    const int c = lane * 2;            // dims c, c+1 (head = lane>>4, 16 lanes/head)
    const u16* xrst = (const u16*)(out + XT_OFF);
    const unsigned xrp = *(const unsigned*)&xrst[(size_t)d * 256 + c];
    const float xr0 = bs2f((u16)(xrp & 0xffff));
    const float xr1 = bs2f((u16)(xrp >> 16));
    const float av0 = att[c], av1 = att[c + 1];
    const int beg = off[d], end = off[d + 1];
    float mx = -INFINITY, den = 0.f, a0 = 0.f, a1 = 0.f;
    int i = beg;
    while (i < end) {
        const int rem = end - i;       // >= 1, wave-uniform
        int e2a[8];
#pragma unroll
        for (int k = 0; k < 8; ++k) e2a[k] = eid[i + (k < rem ? k : rem - 1)];
        int sa[8], nfa[8];
#pragma unroll
        for (int k = 0; k < 8; ++k) { sa[k] = eadj[e2a[k]]; nfa[k] = efea[e2a[k]]; }
        unsigned xv[8], pv[8];
#pragma unroll
        for (int k = 0; k < 8; ++k) {
            xv[k] = *(const unsigned*)&xl[(size_t)sa[k] * 128 + c];
            pv[k] = *(const unsigned*)&proj[(size_t)nfa[k] * 128 + c];
        }
#pragma unroll
        for (int k = 0; k < 8; ++k) {
            const float x0 = bs2f((u16)(xv[k] & 0xffff));
            const float x1 = bs2f((u16)(xv[k] >> 16));
            float m0 = x0 + xr0 + bs2f((u16)(pv[k] & 0xffff));
            float m1 = x1 + xr1 + bs2f((u16)(pv[k] >> 16));
            m0 = m0 > 0.f ? m0 : 0.2f * m0;
            m1 = m1 > 0.f ? m1 : 0.2f * m1;
            float pp = m0 * av0 + m1 * av1;
            pp += __shfl_xor(pp, 8, 16);
            pp += __shfl_xor(pp, 4, 16);
            pp += __shfl_xor(pp, 2, 16);
            pp += __shfl_xor(pp, 1, 16);
            const float p = (k < rem) ? pp : -INFINITY;
            const float mnew = fmaxf(mx, p);
            const float sc = __expf(mx - mnew);
            const float ex = __expf(p - mnew);
            den = den * sc + ex;
            a0 = a0 * sc + ex * x0;
            a1 = a1 * sc + ex * x1;
            mx = mnew;
        }
        i += 8;
    }
    const float inv = 1.f / (den + 1e-16f);
    float2 o2;
    o2.x = a0 * inv + bias[c];
    o2.y = a1 * inv + bias[c + 1];
    *(float2*)&out[XT_OFF + (size_t)d * 128 + c] = o2;
}

// ---------------------------------------------------------------------------
extern "C" void kernel_launch(void* const* d_in, const int* in_sizes, int n_in,
                              void* d_out, int out_size, void* d_ws, size_t ws_size,
                              hipStream_t stream)
{
    const float* x_node   = (const float*)d_in[0];
    const float* x_trace  = (const float*)d_in[1];
    const float* x_log    = (const float*)d_in[2];
    const int*   node_adj = (const int*)d_in[3];
    const int*   edge_adj = (const int*)d_in[4];
    const int*   efea     = (const int*)d_in[5];
    const float* n2n_Wl   = (const float*)d_in[6];
    const float* n2n_bl   = (const float*)d_in[7];
    const float* n2n_Wr   = (const float*)d_in[8];
    const float* n2n_br   = (const float*)d_in[9];
    const float* n2n_We   = (const float*)d_in[10];
    const float* n2n_att  = (const float*)d_in[11];
    const float* n2n_bias = (const float*)d_in[12];
    const float* e2n_Wl   = (const float*)d_in[13];
    const float* e2n_bl   = (const float*)d_in[14];
    const float* e2n_Wr   = (const float*)d_in[15];
    const float* e2n_br   = (const float*)d_in[16];
    const float* e2n_We   = (const float*)d_in[17];
    const float* e2n_att  = (const float*)d_in[18];
    const float* e2n_bias = (const float*)d_in[19];
    float* out = (float*)d_out;

    // ---- workspace layout (~48.7 MB, unchanged) ----
    char* w = (char*)d_ws;
    int* cnt1 = (int*)w; w += (size_t)N * 4;         // zeroed below
    int* cnt2 = (int*)w; w += (size_t)E * 4;         // zeroed below
    int* off1 = (int*)w; w += (size_t)(N + 4) * 4;
    int* cur1 = (int*)w; w += (size_t)N * 4;
    int* eid1 = (int*)w; w += (size_t)E * 4;
    int* off2 = (int*)w; w += (size_t)(E + 4) * 4;
    int* cur2 = (int*)w; w += (size_t)E * 4;
    int* eid2 = (int*)w; w += (size_t)E2 * 4;
    u16* xl_n = (u16*)w; w += (size_t)N * 256 * 2;
    u16* xr_n = (u16*)w; w += (size_t)N * 256 * 2;
    u16* xl_e = (u16*)w; w += (size_t)E * 128 * 2;
    u16* proj = (u16*)w; w += (size_t)N * 128 * 2;
    float* alpha_n = (float*)w; w += (size_t)E * 4 * 4;
    u16* Wlt  = (u16*)w; w += (size_t)65536 * 2;
    u16* Wrt  = (u16*)w; w += (size_t)65536 * 2;
    u16* Wet  = (u16*)w; w += (size_t)32768 * 2;
    u16* Wl2t = (u16*)w; w += (size_t)16384 * 2;
    u16* Wr2t = (u16*)w; w += (size_t)16384 * 2;
    u16* We2t = (u16*)w; w += (size_t)32768 * 2;

    hipMemsetAsync(d_ws, 0, (size_t)(N + E) * 4, stream);

    // ---- prep + CSR builds ----
    k_prep<<<896, 256, 0, stream>>>(n2n_Wl, n2n_Wr, n2n_We, e2n_Wl, e2n_Wr, e2n_We,
                                    Wlt, Wrt, Wet, Wl2t, Wr2t, We2t);
    k_hist<<<E / 256, 256, 0, stream>>>(node_adj + E, cnt1, E);
    k_scan<<<1, 256, 0, stream>>>(cnt1, off1, cur1, N);
    k_scatter<<<E / 256, 256, 0, stream>>>(node_adj + E, cur1, eid1, E);
    k_hist<<<E2 / 256, 256, 0, stream>>>(edge_adj + E2, cnt2, E2);
    k_scan<<<1, 256, 0, stream>>>(cnt2, off2, cur2, E);
    k_scatter<<<E2 / 256, 256, 0, stream>>>(edge_adj + E2, cur2, eid2, E2);

    // ---- layer 1 ----
    k_node_gemm<<<N / 32, 256, 0, stream>>>(x_node, x_log, Wlt, n2n_bl, Wrt, n2n_br,
                                            xl_n, xr_n);
    k_edge_alpha1<<<E / 32, 256, 0, stream>>>(x_trace, node_adj, xl_n, xr_n,
                                              Wet, n2n_att, alpha_n);
    k_fused1<<<N / 4, 256, 0, stream>>>(node_adj, off1, eid1, alpha_n, xl_n, n2n_bias, out);

    // ---- layer 2 ----
    k_proj_gemm<<<N / 32, 256, 0, stream>>>(out, We2t, proj);
    k_trace_gemm<<<E / 32, 256, 0, stream>>>(x_trace, Wl2t, e2n_bl, Wr2t, e2n_br,
                                             xl_e, (u16*)(out + XT_OFF));
    k_fused2<<<E / 4, 256, 0, stream>>>(edge_adj, efea, off2, eid2, xl_e, proj,
                                        e2n_att, e2n_bias, out);
}

// Round 4
// 472.688 us; speedup vs baseline: 1.2082x; 1.2082x over previous
//
#include <hip/hip_runtime.h>
#include <hip/hip_bf16.h>

// Problem constants (match reference)
constexpr int N    = 8192;     // nodes
constexpr int E    = 131072;   // node-graph edges == trace rows
constexpr int E2   = 524288;   // line-graph edges

constexpr size_t XT_OFF  = (size_t)N * 128;
constexpr size_t XLG_OFF = XT_OFF + (size_t)E * 128;

typedef unsigned short u16;
typedef short s16x8 __attribute__((ext_vector_type(8)));
typedef float f32x4 __attribute__((ext_vector_type(4)));

__device__ __forceinline__ u16 f2bs(float f) {   // f32 -> bf16 bits, RNE
    unsigned x = __float_as_uint(f);
    return (u16)((x + 0x7FFF + ((x >> 16) & 1)) >> 16);
}
__device__ __forceinline__ float bs2f(u16 u) {
    return __uint_as_float((unsigned)u << 16);
}

// ---------------------------------------------------------------------------
// K0: weight pre-transpose f32 [K,N] -> bf16 [N,K] (one launch, all 6 mats)
__global__ __launch_bounds__(256) void k_prep(
    const float* __restrict__ Wl, const float* __restrict__ Wr,
    const float* __restrict__ We, const float* __restrict__ Wl2,
    const float* __restrict__ Wr2, const float* __restrict__ We2,
    u16* __restrict__ Wlt, u16* __restrict__ Wrt, u16* __restrict__ Wet,
    u16* __restrict__ Wl2t, u16* __restrict__ Wr2t, u16* __restrict__ We2t)
{
    const int gid = blockIdx.x * 256 + threadIdx.x;
    const float* src; u16* dst; int base, Kk, sh;
    if      (gid <  65536) { src = Wl;  dst = Wlt;  base = 0;      Kk = 256; sh = 8; }
    else if (gid < 131072) { src = Wr;  dst = Wrt;  base = 65536;  Kk = 256; sh = 8; }
    else if (gid < 163840) { src = We;  dst = Wet;  base = 131072; Kk = 128; sh = 8; }
    else if (gid < 180224) { src = Wl2; dst = Wl2t; base = 163840; Kk = 128; sh = 7; }
    else if (gid < 196608) { src = Wr2; dst = Wr2t; base = 180224; Kk = 128; sh = 7; }
    else                   { src = We2; dst = We2t; base = 196608; Kk = 256; sh = 7; }
    const int l = gid - base;
    const int k = l >> sh, nn = l & ((1 << sh) - 1);
    dst[(size_t)nn * Kk + k] = f2bs(src[l]);
}

// ---------------------------------------------------------------------------
// CSR build: histogram -> single-block scan -> payload scatter
__global__ void k_hist(const int* __restrict__ dst, int* __restrict__ cnt, int nE)
{
    int i = blockIdx.x * 256 + threadIdx.x;
    if (i < nE) atomicAdd(&cnt[dst[i]], 1);
}

// 1024-thread single-block scan, 8 items/thread per 8192-tile
__global__ __launch_bounds__(1024) void k_scan(
    const int* __restrict__ cnt, int* __restrict__ off, int* __restrict__ cur, int n)
{
    __shared__ int tile[8192];
    __shared__ int wsum[16];
    const int tid = threadIdx.x, lane = tid & 63, wv = tid >> 6;
    int carry = 0;
    for (int base = 0; base < n; base += 8192) {
        for (int i = tid; i < 8192; i += 1024) tile[i] = cnt[base + i];
        __syncthreads();
        const int st = tid * 8;
        int s = 0;
        for (int k = 0; k < 8; ++k) { int v = tile[st + k]; tile[st + k] = s; s += v; }
        const int tsum = s;
        int incl = s;
        for (int o = 1; o < 64; o <<= 1) {
            int v = __shfl_up(incl, o);
            if (lane >= o) incl += v;
        }
        if (lane == 63) wsum[wv] = incl;
        __syncthreads();
        int woff = 0;
        for (int wq = 0; wq < wv; ++wq) woff += wsum[wq];
        int tot = 0;
        for (int wq = 0; wq < 16; ++wq) tot += wsum[wq];
        const int add = carry + woff + incl - tsum;
        for (int k = 0; k < 8; ++k) {
            int o2 = add + tile[st + k];
            off[base + st + k] = o2;
            cur[base + st + k] = o2;
        }
        carry += tot;
        __syncthreads();
    }
    if (tid == 0) off[n] = carry;
}

// layer-1 scatter: payload = src node; also inverse map pos1[e] for alpha write
__global__ void k_scatter1(const int* __restrict__ adj, int* __restrict__ cur,
                           int* __restrict__ srcc, int* __restrict__ pos1, int nE)
{
    int i = blockIdx.x * 256 + threadIdx.x;
    if (i < nE) {
        int pos = atomicAdd(&cur[adj[nE + i]], 1);
        srcc[pos] = adj[i];
        pos1[i] = pos;
    }
}

// layer-2 scatter: payload = {src line-edge, node-feature idx}
__global__ void k_scatter2(const int* __restrict__ eadj, const int* __restrict__ efea,
                           int* __restrict__ cur, int2* __restrict__ sf2, int nE)
{
    int i = blockIdx.x * 256 + threadIdx.x;
    if (i < nE) {
        int pos = atomicAdd(&cur[eadj[nE + i]], 1);
        sf2[pos] = make_int2(eadj[i], efea[i]);
    }
}

// ---------------------------------------------------------------------------
// K1 (MFMA): xl_n/xr_n = concat(x_node,x_log) @ {Wl,Wr} + bias -> bf16 [N,256]
__global__ __launch_bounds__(256) void k_node_gemm(
    const float* __restrict__ x_node, const float* __restrict__ x_log,
    const u16* __restrict__ Wlt, const float* __restrict__ bl,
    const u16* __restrict__ Wrt, const float* __restrict__ br,
    u16* __restrict__ xl, u16* __restrict__ xr)
{
    __shared__ u16 A[32][260];
    const int n0 = blockIdx.x * 32;
    const int tid = threadIdx.x;
    for (int i = tid; i < 32 * 64; i += 256) {
        const int r = i >> 6, k4 = (i & 63) << 2;
        const float* srcp = (k4 < 128) ? &x_node[(size_t)(n0 + r) * 128 + k4]
                                       : &x_log [(size_t)(n0 + r) * 128 + (k4 - 128)];
        const float4 v = *(const float4*)srcp;
        ushort4 o; o.x = f2bs(v.x); o.y = f2bs(v.y); o.z = f2bs(v.z); o.w = f2bs(v.w);
        *(ushort4*)&A[r][k4] = o;
    }
    __syncthreads();
    const int w = tid >> 6, lane = tid & 63, lr = lane & 15, lq = lane >> 4;
    const u16* Wt     = (w < 2) ? Wlt : Wrt;
    const float* bias = (w < 2) ? bl : br;
    u16* outp         = (w < 2) ? xl : xr;
    const int cb = (w & 1) * 128;
    f32x4 acc[2][8] = {};
    for (int kb = 0; kb < 8; ++kb) {
        s16x8 afr0 = *(const s16x8*)&A[lr][kb * 32 + lq * 8];
        s16x8 afr1 = *(const s16x8*)&A[16 + lr][kb * 32 + lq * 8];
#pragma unroll
        for (int ct = 0; ct < 8; ++ct) {
            const int n = cb + ct * 16 + lr;
            s16x8 bfr = *(const s16x8*)&Wt[(size_t)n * 256 + kb * 32 + lq * 8];
            acc[0][ct] = __builtin_amdgcn_mfma_f32_16x16x32_bf16(afr0, bfr, acc[0][ct], 0, 0, 0);
            acc[1][ct] = __builtin_amdgcn_mfma_f32_16x16x32_bf16(afr1, bfr, acc[1][ct], 0, 0, 0);
        }
    }
#pragma unroll
    for (int rt = 0; rt < 2; ++rt)
#pragma unroll
        for (int ct = 0; ct < 8; ++ct) {
            const int col = cb + ct * 16 + lr;
            const float bv = bias[col];
#pragma unroll
            for (int reg = 0; reg < 4; ++reg) {
                const int row = n0 + rt * 16 + lq * 4 + reg;
                outp[(size_t)row * 256 + col] = f2bs(acc[rt][ct][reg] + bv);
            }
        }
}

// ---------------------------------------------------------------------------
// K2 (MFMA): xl_e = trace@Wl2+bl2 (bf16) ; xr_e = trace@Wr2+br2 -> bf16 staged
// row-local in the out-XT region (first 256 B of each row's 512 B f32 span).
__global__ __launch_bounds__(256) void k_trace_gemm(
    const float* __restrict__ x_trace,
    const u16* __restrict__ Wl2t, const float* __restrict__ bl,
    const u16* __restrict__ Wr2t, const float* __restrict__ br,
    u16* __restrict__ xl, u16* __restrict__ xrst)
{
    __shared__ u16 A[32][132];
    const int e0 = blockIdx.x * 32;
    const int tid = threadIdx.x;
    for (int i = tid; i < 32 * 32; i += 256) {
        const int r = i >> 5, k4 = (i & 31) << 2;
        const float4 v = *(const float4*)&x_trace[(size_t)(e0 + r) * 128 + k4];
        ushort4 o; o.x = f2bs(v.x); o.y = f2bs(v.y); o.z = f2bs(v.z); o.w = f2bs(v.w);
        *(ushort4*)&A[r][k4] = o;
    }
    __syncthreads();
    const int w = tid >> 6, lane = tid & 63, lr = lane & 15, lq = lane >> 4;
    const u16* Wt     = (w < 2) ? Wl2t : Wr2t;
    const float* bias = (w < 2) ? bl : br;
    const int cb = (w & 1) * 64;
    f32x4 acc[2][4] = {};
    for (int kb = 0; kb < 4; ++kb) {
        s16x8 afr0 = *(const s16x8*)&A[lr][kb * 32 + lq * 8];
        s16x8 afr1 = *(const s16x8*)&A[16 + lr][kb * 32 + lq * 8];
#pragma unroll
        for (int ct = 0; ct < 4; ++ct) {
            const int n = cb + ct * 16 + lr;
            s16x8 bfr = *(const s16x8*)&Wt[(size_t)n * 128 + kb * 32 + lq * 8];
            acc[0][ct] = __builtin_amdgcn_mfma_f32_16x16x32_bf16(afr0, bfr, acc[0][ct], 0, 0, 0);
            acc[1][ct] = __builtin_amdgcn_mfma_f32_16x16x32_bf16(afr1, bfr, acc[1][ct], 0, 0, 0);
        }
    }
#pragma unroll
    for (int rt = 0; rt < 2; ++rt)
#pragma unroll
        for (int ct = 0; ct < 4; ++ct) {
            const int col = cb + ct * 16 + lr;
            const float bv = bias[col];
#pragma unroll
            for (int reg = 0; reg < 4; ++reg) {
                const int row = e0 + rt * 16 + lq * 4 + reg;
                if (w < 2) xl[(size_t)row * 128 + col]   = f2bs(acc[rt][ct][reg] + bv);
                else       xrst[(size_t)row * 256 + col] = f2bs(acc[rt][ct][reg] + bv);
            }
        }
}

// ---------------------------------------------------------------------------
// K3 (MFMA): fused e-GEMM (trace@We) + layer-1 logits. 32 edges/block.
// Writes alpha at CSR position (pos1) so k_fused1 reads it sequentially.
__global__ __launch_bounds__(256) void k_edge_alpha1(
    const float* __restrict__ x_trace,
    const int* __restrict__ adj,          // [2,E] src then dst
    const int* __restrict__ pos1,
    const u16* __restrict__ xl, const u16* __restrict__ xr,   // [N,256] bf16
    const u16* __restrict__ Wet, const float* __restrict__ att,
    float* __restrict__ alpha)
{
    __shared__ u16 A[32][132];
    __shared__ int ss[32], dd[32], pp[32];
    const int e0 = blockIdx.x * 32;
    const int tid = threadIdx.x;
    for (int i = tid; i < 32 * 32; i += 256) {
        const int r = i >> 5, k4 = (i & 31) << 2;
        const float4 v = *(const float4*)&x_trace[(size_t)(e0 + r) * 128 + k4];
        ushort4 o; o.x = f2bs(v.x); o.y = f2bs(v.y); o.z = f2bs(v.z); o.w = f2bs(v.w);
        *(ushort4*)&A[r][k4] = o;
    }
    if (tid < 32) {
        ss[tid] = adj[e0 + tid];
        dd[tid] = adj[E + e0 + tid];
        pp[tid] = pos1[e0 + tid];
    }
    __syncthreads();
    const int w = tid >> 6, lane = tid & 63, lr = lane & 15, lq = lane >> 4;
    f32x4 acc[2][4] = {};
    for (int kb = 0; kb < 4; ++kb) {
        s16x8 afr0 = *(const s16x8*)&A[lr][kb * 32 + lq * 8];
        s16x8 afr1 = *(const s16x8*)&A[16 + lr][kb * 32 + lq * 8];
#pragma unroll
        for (int ct = 0; ct < 4; ++ct) {
            const int n = w * 64 + ct * 16 + lr;
            s16x8 bfr = *(const s16x8*)&Wet[(size_t)n * 128 + kb * 32 + lq * 8];
            acc[0][ct] = __builtin_amdgcn_mfma_f32_16x16x32_bf16(afr0, bfr, acc[0][ct], 0, 0, 0);
            acc[1][ct] = __builtin_amdgcn_mfma_f32_16x16x32_bf16(afr1, bfr, acc[1][ct], 0, 0, 0);
        }
    }
    float attv[4];
#pragma unroll
    for (int ct = 0; ct < 4; ++ct) attv[ct] = att[w * 64 + ct * 16 + lr];
    float sums[2][4] = {};
#pragma unroll
    for (int rt = 0; rt < 2; ++rt)
#pragma unroll
        for (int reg = 0; reg < 4; ++reg) {
            const int rowt = rt * 16 + lq * 4 + reg;
            const int s = ss[rowt], d = dd[rowt];
            float acc_s = 0.f;
#pragma unroll
            for (int ct = 0; ct < 4; ++ct) {
                const int col = w * 64 + ct * 16 + lr;
                float m = acc[rt][ct][reg]
                        + bs2f(xl[(size_t)s * 256 + col])
                        + bs2f(xr[(size_t)d * 256 + col]);
                m = m > 0.f ? m : 0.2f * m;
                acc_s += m * attv[ct];
            }
            sums[rt][reg] = acc_s;
        }
#pragma unroll
    for (int rt = 0; rt < 2; ++rt)
#pragma unroll
        for (int reg = 0; reg < 4; ++reg) {
            float p = sums[rt][reg];
            p += __shfl_xor(p, 8);
            p += __shfl_xor(p, 4);
            p += __shfl_xor(p, 2);
            p += __shfl_xor(p, 1);
            if (lr == 0)
                alpha[(size_t)pp[rt * 16 + lq * 4 + reg] * 4 + w] = p;
        }
}

// ---------------------------------------------------------------------------
// K4: layer-1 online-softmax + gather. One node per WAVE, 4 dims/lane.
// CSR payload arrays (src_csr, alpha_csr) -> sequential loads + ONE gather level.
// Predicated batch-8 (deg avg 16 -> padding waste ~25%).
__global__ __launch_bounds__(256) void k_fused1(
    const int* __restrict__ off, const int* __restrict__ srcc,
    const float* __restrict__ alphac,
    const u16* __restrict__ xl,
    const float* __restrict__ bias,
    float* __restrict__ out)
{
    const int wv = __builtin_amdgcn_readfirstlane(threadIdx.x >> 6);
    const int lane = threadIdx.x & 63;
    const int n = blockIdx.x * 4 + wv;
    const int c = lane * 4;            // dims c..c+3
    const int h = lane >> 4;           // head (64 dims / head, 16 lanes / head)
    const int beg = off[n], end = off[n + 1];
    float mx = -INFINITY, den = 0.f;
    float a0 = 0.f, a1 = 0.f, a2 = 0.f, a3 = 0.f;
    int i = beg;
    while (i < end) {
        const int rem = end - i;       // >= 1, wave-uniform
        int sa[8]; float pe[8];
#pragma unroll
        for (int k = 0; k < 8; ++k) {
            const int idx = i + (k < rem ? k : rem - 1);
            sa[k] = srcc[idx];
            pe[k] = alphac[(size_t)idx * 4 + h];
        }
        ushort4 xv[8];
#pragma unroll
        for (int k = 0; k < 8; ++k)
            xv[k] = *(const ushort4*)&xl[(size_t)sa[k] * 256 + c];
#pragma unroll
        for (int k = 0; k < 8; ++k) {
            const float p = (k < rem) ? pe[k] : -INFINITY;
            const float mnew = fmaxf(mx, p);
            const float sc = __expf(mx - mnew);
            const float ex = __expf(p - mnew);
            den = den * sc + ex;
            a0 = a0 * sc + ex * bs2f(xv[k].x);
            a1 = a1 * sc + ex * bs2f(xv[k].y);
            a2 = a2 * sc + ex * bs2f(xv[k].z);
            a3 = a3 * sc + ex * bs2f(xv[k].w);
            mx = mnew;
        }
        i += 8;
    }
    const float inv = 1.f / (den + 1e-16f);
    float4 r;
    r.x = a0 * inv + bias[c + 0];
    r.y = a1 * inv + bias[c + 1];
    r.z = a2 * inv + bias[c + 2];
    r.w = a3 * inv + bias[c + 3];
    if (lane < 32) *(float4*)&out[(size_t)n * 128 + c] = r;
    else           *(float4*)&out[XLG_OFF + (size_t)n * 128 + (c - 128)] = r;
}

// ---------------------------------------------------------------------------
// K5 (MFMA): proj = node_out @ e2n_We  [N,128] bf16
__global__ __launch_bounds__(256) void k_proj_gemm(
    const float* __restrict__ out_node, const u16* __restrict__ We2t,  // [128][256]
    u16* __restrict__ proj)
{
    __shared__ u16 A[32][260];
    const int n0 = blockIdx.x * 32;
    const int tid = threadIdx.x;
    for (int i = tid; i < 32 * 64; i += 256) {
        const int r = i >> 6, k4 = (i & 63) << 2;
        const float* srcp = (k4 < 128)
            ? &out_node[(size_t)(n0 + r) * 128 + k4]
            : &out_node[XLG_OFF + (size_t)(n0 + r) * 128 + (k4 - 128)];
        const float4 v = *(const float4*)srcp;
        ushort4 o; o.x = f2bs(v.x); o.y = f2bs(v.y); o.z = f2bs(v.z); o.w = f2bs(v.w);
        *(ushort4*)&A[r][k4] = o;
    }
    __syncthreads();
    const int w = tid >> 6, lane = tid & 63, lr = lane & 15, lq = lane >> 4;
    f32x4 acc[2][2] = {};
    for (int kb = 0; kb < 8; ++kb) {
        s16x8 afr0 = *(const s16x8*)&A[lr][kb * 32 + lq * 8];
        s16x8 afr1 = *(const s16x8*)&A[16 + lr][kb * 32 + lq * 8];
#pragma unroll
        for (int ct = 0; ct < 2; ++ct) {
            const int col = w * 32 + ct * 16 + lr;
            s16x8 bfr = *(const s16x8*)&We2t[(size_t)col * 256 + kb * 32 + lq * 8];
            acc[0][ct] = __builtin_amdgcn_mfma_f32_16x16x32_bf16(afr0, bfr, acc[0][ct], 0, 0, 0);
            acc[1][ct] = __builtin_amdgcn_mfma_f32_16x16x32_bf16(afr1, bfr, acc[1][ct], 0, 0, 0);
        }
    }
#pragma unroll
    for (int rt = 0; rt < 2; ++rt)
#pragma unroll
        for (int ct = 0; ct < 2; ++ct) {
            const int col = w * 32 + ct * 16 + lr;
#pragma unroll
            for (int reg = 0; reg < 4; ++reg) {
                const int row = n0 + rt * 16 + lq * 4 + reg;
                proj[(size_t)row * 128 + col] = f2bs(acc[rt][ct][reg]);
            }
        }
}

// ---------------------------------------------------------------------------
// K6: layer-2 fused logits + online softmax + aggregate. One row per WAVE,
// 2 dims/lane. CSR payload int2 {s, nf} -> sequential load + ONE gather level.
// Predicated batch-4 (deg avg 4 -> padding waste ~1.4x, not 2x).
__global__ __launch_bounds__(256) void k_fused2(
    const int* __restrict__ off, const int2* __restrict__ sf2,
    const u16* __restrict__ xl,        // [E,128] trace@Wl2+bl2 bf16
    const u16* __restrict__ proj,      // [N,128] bf16
    const float* __restrict__ att,
    const float* __restrict__ bias,
    float* __restrict__ out)
{
    const int wv = __builtin_amdgcn_readfirstlane(threadIdx.x >> 6);
    const int lane = threadIdx.x & 63;
    const int d = blockIdx.x * 4 + wv;
    const int c = lane * 2;            // dims c, c+1 (head = lane>>4, 16 lanes/head)
    const u16* xrst = (const u16*)(out + XT_OFF);
    const unsigned xrp = *(const unsigned*)&xrst[(size_t)d * 256 + c];
    const float xr0 = bs2f((u16)(xrp & 0xffff));
    const float xr1 = bs2f((u16)(xrp >> 16));
    const float av0 = att[c], av1 = att[c + 1];
    const int beg = off[d], end = off[d + 1];
    float mx = -INFINITY, den = 0.f, a0 = 0.f, a1 = 0.f;
    int i = beg;
    while (i < end) {
        const int rem = end - i;       // >= 1, wave-uniform
        int2 sf[4];
#pragma unroll
        for (int k = 0; k < 4; ++k) sf[k] = sf2[i + (k < rem ? k : rem - 1)];
        unsigned xv[4], pv[4];
#pragma unroll
        for (int k = 0; k < 4; ++k) {
            xv[k] = *(const unsigned*)&xl[(size_t)sf[k].x * 128 + c];
            pv[k] = *(const unsigned*)&proj[(size_t)sf[k].y * 128 + c];
        }
#pragma unroll
        for (int k = 0; k < 4; ++k) {
            const float x0 = bs2f((u16)(xv[k] & 0xffff));
            const float x1 = bs2f((u16)(xv[k] >> 16));
            float m0 = x0 + xr0 + bs2f((u16)(pv[k] & 0xffff));
            float m1 = x1 + xr1 + bs2f((u16)(pv[k] >> 16));
            m0 = m0 > 0.f ? m0 : 0.2f * m0;
            m1 = m1 > 0.f ? m1 : 0.2f * m1;
            float pp = m0 * av0 + m1 * av1;
            pp += __shfl_xor(pp, 8, 16);
            pp += __shfl_xor(pp, 4, 16);
            pp += __shfl_xor(pp, 2, 16);
            pp += __shfl_xor(pp, 1, 16);
            const float p = (k < rem) ? pp : -INFINITY;
            const float mnew = fmaxf(mx, p);
            const float sc = __expf(mx - mnew);
            const float ex = __expf(p - mnew);
            den = den * sc + ex;
            a0 = a0 * sc + ex * x0;
            a1 = a1 * sc + ex * x1;
            mx = mnew;
        }
        i += 4;
    }
    const float inv = 1.f / (den + 1e-16f);
    float2 o2;
    o2.x = a0 * inv + bias[c];
    o2.y = a1 * inv + bias[c + 1];
    *(float2*)&out[XT_OFF + (size_t)d * 128 + c] = o2;
}

// ---------------------------------------------------------------------------
extern "C" void kernel_launch(void* const* d_in, const int* in_sizes, int n_in,
                              void* d_out, int out_size, void* d_ws, size_t ws_size,
                              hipStream_t stream)
{
    const float* x_node   = (const float*)d_in[0];
    const float* x_trace  = (const float*)d_in[1];
    const float* x_log    = (const float*)d_in[2];
    const int*   node_adj = (const int*)d_in[3];
    const int*   edge_adj = (const int*)d_in[4];
    const int*   efea     = (const int*)d_in[5];
    const float* n2n_Wl   = (const float*)d_in[6];
    const float* n2n_bl   = (const float*)d_in[7];
    const float* n2n_Wr   = (const float*)d_in[8];
    const float* n2n_br   = (const float*)d_in[9];
    const float* n2n_We   = (const float*)d_in[10];
    const float* n2n_att  = (const float*)d_in[11];
    const float* n2n_bias = (const float*)d_in[12];
    const float* e2n_Wl   = (const float*)d_in[13];
    const float* e2n_bl   = (const float*)d_in[14];
    const float* e2n_Wr   = (const float*)d_in[15];
    const float* e2n_br   = (const float*)d_in[16];
    const float* e2n_We   = (const float*)d_in[17];
    const float* e2n_att  = (const float*)d_in[18];
    const float* e2n_bias = (const float*)d_in[19];
    float* out = (float*)d_out;

    // ---- workspace layout (~51 MB) ----
    char* w = (char*)d_ws;
    int*  cnt1   = (int*)w;   w += (size_t)N * 4;        // zeroed below
    int*  cnt2   = (int*)w;   w += (size_t)E * 4;        // zeroed below
    int*  off1   = (int*)w;   w += (size_t)(N + 4) * 4;
    int*  cur1   = (int*)w;   w += (size_t)N * 4;
    int*  src1   = (int*)w;   w += (size_t)E * 4;        // CSR payload: src node
    int*  pos1   = (int*)w;   w += (size_t)E * 4;        // edge -> CSR pos
    float* alphac = (float*)w; w += (size_t)E * 4 * 4;   // CSR-ordered alpha [E][4]
    int*  off2   = (int*)w;   w += (size_t)(E + 4) * 4;
    int*  cur2   = (int*)w;   w += (size_t)E * 4;
    int2* sf2    = (int2*)w;  w += (size_t)E2 * 8;       // CSR payload: {s, nf}
    u16*  xl_n   = (u16*)w;   w += (size_t)N * 256 * 2;
    u16*  xr_n   = (u16*)w;   w += (size_t)N * 256 * 2;
    u16*  xl_e   = (u16*)w;   w += (size_t)E * 128 * 2;
    u16*  proj   = (u16*)w;   w += (size_t)N * 128 * 2;
    u16*  Wlt    = (u16*)w;   w += (size_t)65536 * 2;
    u16*  Wrt    = (u16*)w;   w += (size_t)65536 * 2;
    u16*  Wet    = (u16*)w;   w += (size_t)32768 * 2;
    u16*  Wl2t   = (u16*)w;   w += (size_t)16384 * 2;
    u16*  Wr2t   = (u16*)w;   w += (size_t)16384 * 2;
    u16*  We2t   = (u16*)w;   w += (size_t)32768 * 2;

    hipMemsetAsync(d_ws, 0, (size_t)(N + E) * 4, stream);

    // ---- prep + CSR builds ----
    k_prep<<<896, 256, 0, stream>>>(n2n_Wl, n2n_Wr, n2n_We, e2n_Wl, e2n_Wr, e2n_We,
                                    Wlt, Wrt, Wet, Wl2t, Wr2t, We2t);
    k_hist<<<E / 256, 256, 0, stream>>>(node_adj + E, cnt1, E);
    k_scan<<<1, 1024, 0, stream>>>(cnt1, off1, cur1, N);
    k_scatter1<<<E / 256, 256, 0, stream>>>(node_adj, cur1, src1, pos1, E);
    k_hist<<<E2 / 256, 256, 0, stream>>>(edge_adj + E2, cnt2, E2);
    k_scan<<<1, 1024, 0, stream>>>(cnt2, off2, cur2, E);
    k_scatter2<<<E2 / 256, 256, 0, stream>>>(edge_adj, efea, cur2, sf2, E2);

    // ---- layer 1 ----
    k_node_gemm<<<N / 32, 256, 0, stream>>>(x_node, x_log, Wlt, n2n_bl, Wrt, n2n_br,
                                            xl_n, xr_n);
    k_edge_alpha1<<<E / 32, 256, 0, stream>>>(x_trace, node_adj, pos1, xl_n, xr_n,
                                              Wet, n2n_att, alphac);
    k_fused1<<<N / 4, 256, 0, stream>>>(off1, src1, alphac, xl_n, n2n_bias, out);

    // ---- layer 2 ----
    k_proj_gemm<<<N / 32, 256, 0, stream>>>(out, We2t, proj);
    k_trace_gemm<<<E / 32, 256, 0, stream>>>(x_trace, Wl2t, e2n_bl, Wr2t, e2n_br,
                                             xl_e, (u16*)(out + XT_OFF));
    k_fused2<<<E / 4, 256, 0, stream>>>(off2, sf2, xl_e, proj,
                                        e2n_att, e2n_bias, out);
}

// Round 6
// 469.395 us; speedup vs baseline: 1.2167x; 1.0070x over previous
//
#include <hip/hip_runtime.h>
#include <hip/hip_bf16.h>

// Problem constants (match reference)
constexpr int N    = 8192;     // nodes
constexpr int E    = 131072;   // node-graph edges == trace rows
constexpr int E2   = 524288;   // line-graph edges

constexpr size_t XT_OFF  = (size_t)N * 128;
constexpr size_t XLG_OFF = XT_OFF + (size_t)E * 128;

typedef unsigned short u16;
typedef short s16x8 __attribute__((ext_vector_type(8)));
typedef float f32x4 __attribute__((ext_vector_type(4)));

__device__ __forceinline__ u16 f2bs(float f) {   // f32 -> bf16 bits, RNE
    unsigned x = __float_as_uint(f);
    return (u16)((x + 0x7FFF + ((x >> 16) & 1)) >> 16);
}
__device__ __forceinline__ float bs2f(u16 u) {
    return __uint_as_float((unsigned)u << 16);
}

// ---------------------------------------------------------------------------
// K0: weight pre-transpose f32 [K,Ncol] -> bf16 [Ncol,K] (one launch, all 6).
// Wet/Wl2t/Wr2t rows are PERMUTED within each 64-col window so that the MFMA
// output position (ct*16+lr) computes original col (lr*4+ct): lane lr then
// owns 4 CONTIGUOUS cols -> ushort4 gathers/stores in k_edge_mm.
__global__ __launch_bounds__(256) void k_prep(
    const float* __restrict__ Wl, const float* __restrict__ Wr,
    const float* __restrict__ We, const float* __restrict__ Wl2,
    const float* __restrict__ Wr2, const float* __restrict__ We2,
    u16* __restrict__ Wlt, u16* __restrict__ Wrt, u16* __restrict__ Wet,
    u16* __restrict__ Wl2t, u16* __restrict__ Wr2t, u16* __restrict__ We2t)
{
    const int gid = blockIdx.x * 256 + threadIdx.x;
    const float* src; u16* dst; int base, Kk, sh, perm;
    if      (gid <  65536) { src = Wl;  dst = Wlt;  base = 0;      Kk = 256; sh = 8; perm = 0; }
    else if (gid < 131072) { src = Wr;  dst = Wrt;  base = 65536;  Kk = 256; sh = 8; perm = 0; }
    else if (gid < 163840) { src = We;  dst = Wet;  base = 131072; Kk = 128; sh = 8; perm = 1; }
    else if (gid < 180224) { src = Wl2; dst = Wl2t; base = 163840; Kk = 128; sh = 7; perm = 1; }
    else if (gid < 196608) { src = Wr2; dst = Wr2t; base = 180224; Kk = 128; sh = 7; perm = 1; }
    else                   { src = We2; dst = We2t; base = 196608; Kk = 256; sh = 7; perm = 0; }
    const int l = gid - base;
    const int k = l >> sh, nn = l & ((1 << sh) - 1);
    int ns = nn;
    if (perm) ns = (nn & ~63) | ((nn & 3) << 4) | ((nn >> 2) & 15);
    dst[(size_t)ns * Kk + k] = f2bs(src[l]);
}

// ---------------------------------------------------------------------------
// CSR build: histogram -> single-block scan -> payload scatter
__global__ void k_hist(const int* __restrict__ dst, int* __restrict__ cnt, int nE)
{
    int i = blockIdx.x * 256 + threadIdx.x;
    if (i < nE) atomicAdd(&cnt[dst[i]], 1);
}

// 1024-thread single-block scan, 8 items/thread per 8192-tile
__global__ __launch_bounds__(1024) void k_scan(
    const int* __restrict__ cnt, int* __restrict__ off, int* __restrict__ cur, int n)
{
    __shared__ int tile[8192];
    __shared__ int wsum[16];
    const int tid = threadIdx.x, lane = tid & 63, wv = tid >> 6;
    int carry = 0;
    for (int base = 0; base < n; base += 8192) {
        for (int i = tid; i < 8192; i += 1024) tile[i] = cnt[base + i];
        __syncthreads();
        const int st = tid * 8;
        int s = 0;
        for (int k = 0; k < 8; ++k) { int v = tile[st + k]; tile[st + k] = s; s += v; }
        const int tsum = s;
        int incl = s;
        for (int o = 1; o < 64; o <<= 1) {
            int v = __shfl_up(incl, o);
            if (lane >= o) incl += v;
        }
        if (lane == 63) wsum[wv] = incl;
        __syncthreads();
        int woff = 0;
        for (int wq = 0; wq < wv; ++wq) woff += wsum[wq];
        int tot = 0;
        for (int wq = 0; wq < 16; ++wq) tot += wsum[wq];
        const int add = carry + woff + incl - tsum;
        for (int k = 0; k < 8; ++k) {
            int o2 = add + tile[st + k];
            off[base + st + k] = o2;
            cur[base + st + k] = o2;
        }
        carry += tot;
        __syncthreads();
    }
    if (tid == 0) off[n] = carry;
}

// layer-1 scatter: payload = src node; also inverse map pos1[e] for alpha write
__global__ void k_scatter1(const int* __restrict__ adj, int* __restrict__ cur,
                           int* __restrict__ srcc, int* __restrict__ pos1, int nE)
{
    int i = blockIdx.x * 256 + threadIdx.x;
    if (i < nE) {
        int pos = atomicAdd(&cur[adj[nE + i]], 1);
        srcc[pos] = adj[i];
        pos1[i] = pos;
    }
}

// layer-2 scatter: payload = {src line-edge, node-feature idx}
__global__ void k_scatter2(const int* __restrict__ eadj, const int* __restrict__ efea,
                           int* __restrict__ cur, int2* __restrict__ sf2, int nE)
{
    int i = blockIdx.x * 256 + threadIdx.x;
    if (i < nE) {
        int pos = atomicAdd(&cur[eadj[nE + i]], 1);
        sf2[pos] = make_int2(eadj[i], efea[i]);
    }
}

// ---------------------------------------------------------------------------
// K1 (MFMA): xl_n/xr_n = concat(x_node,x_log) @ {Wl,Wr} + bias -> bf16 [N,256]
__global__ __launch_bounds__(256) void k_node_gemm(
    const float* __restrict__ x_node, const float* __restrict__ x_log,
    const u16* __restrict__ Wlt, const float* __restrict__ bl,
    const u16* __restrict__ Wrt, const float* __restrict__ br,
    u16* __restrict__ xl, u16* __restrict__ xr)
{
    __shared__ u16 A[32][260];
    const int n0 = blockIdx.x * 32;
    const int tid = threadIdx.x;
    for (int i = tid; i < 32 * 64; i += 256) {
        const int r = i >> 6, k4 = (i & 63) << 2;
        const float* srcp = (k4 < 128) ? &x_node[(size_t)(n0 + r) * 128 + k4]
                                       : &x_log [(size_t)(n0 + r) * 128 + (k4 - 128)];
        const float4 v = *(const float4*)srcp;
        ushort4 o; o.x = f2bs(v.x); o.y = f2bs(v.y); o.z = f2bs(v.z); o.w = f2bs(v.w);
        *(ushort4*)&A[r][k4] = o;
    }
    __syncthreads();
    const int w = tid >> 6, lane = tid & 63, lr = lane & 15, lq = lane >> 4;
    const u16* Wt     = (w < 2) ? Wlt : Wrt;
    const float* bias = (w < 2) ? bl : br;
    u16* outp         = (w < 2) ? xl : xr;
    const int cb = (w & 1) * 128;
    f32x4 acc[2][8] = {};
    for (int kb = 0; kb < 8; ++kb) {
        s16x8 afr0 = *(const s16x8*)&A[lr][kb * 32 + lq * 8];
        s16x8 afr1 = *(const s16x8*)&A[16 + lr][kb * 32 + lq * 8];
#pragma unroll
        for (int ct = 0; ct < 8; ++ct) {
            const int n = cb + ct * 16 + lr;
            s16x8 bfr = *(const s16x8*)&Wt[(size_t)n * 256 + kb * 32 + lq * 8];
            acc[0][ct] = __builtin_amdgcn_mfma_f32_16x16x32_bf16(afr0, bfr, acc[0][ct], 0, 0, 0);
            acc[1][ct] = __builtin_amdgcn_mfma_f32_16x16x32_bf16(afr1, bfr, acc[1][ct], 0, 0, 0);
        }
    }
#pragma unroll
    for (int rt = 0; rt < 2; ++rt)
#pragma unroll
        for (int ct = 0; ct < 8; ++ct) {
            const int col = cb + ct * 16 + lr;
            const float bv = bias[col];
#pragma unroll
            for (int reg = 0; reg < 4; ++reg) {
                const int row = n0 + rt * 16 + lq * 4 + reg;
                outp[(size_t)row * 256 + col] = f2bs(acc[rt][ct][reg] + bv);
            }
        }
}

// ---------------------------------------------------------------------------
// K3 (MFMA, fused): stages x_trace tile ONCE, computes
//   (a) layer-1 logits: trace@We + gather(xl_n,xr_n) -> alpha (CSR order)
//   (b) layer-2 left:   trace@Wl2+bl2 -> xl_e bf16          (waves 0,1)
//   (c) layer-2 right:  trace@Wr2+br2 -> xrst bf16 staging   (waves 2,3)
// Weights permuted (k_prep) so lane lr owns 4 contiguous cols -> 8B accesses.
__global__ __launch_bounds__(256) void k_edge_mm(
    const float* __restrict__ x_trace,
    const int* __restrict__ adj,          // [2,E] src then dst
    const int* __restrict__ pos1,
    const u16* __restrict__ xl_n, const u16* __restrict__ xr_n,  // [N,256] bf16
    const u16* __restrict__ Wet,                                  // [256][128] perm
    const u16* __restrict__ Wl2t, const float* __restrict__ bl2,  // [128][128] perm
    const u16* __restrict__ Wr2t, const float* __restrict__ br2,
    const float* __restrict__ att,
    float* __restrict__ alpha, u16* __restrict__ xl_e, u16* __restrict__ xrst)
{
    __shared__ u16 A[32][132];
    __shared__ int ss[32], dd[32], pp[32];
    const int e0 = blockIdx.x * 32;
    const int tid = threadIdx.x;
    for (int i = tid; i < 32 * 32; i += 256) {
        const int r = i >> 5, k4 = (i & 31) << 2;
        const float4 v = *(const float4*)&x_trace[(size_t)(e0 + r) * 128 + k4];
        ushort4 o; o.x = f2bs(v.x); o.y = f2bs(v.y); o.z = f2bs(v.z); o.w = f2bs(v.w);
        *(ushort4*)&A[r][k4] = o;
    }
    if (tid < 32) {
        ss[tid] = adj[e0 + tid];
        dd[tid] = adj[E + e0 + tid];
        pp[tid] = pos1[e0 + tid];
    }
    __syncthreads();
    const int w = tid >> 6, lane = tid & 63, lr = lane & 15, lq = lane >> 4;
    const u16* Wt2  = (w < 2) ? Wl2t : Wr2t;
    const float* b2 = (w < 2) ? bl2 : br2;
    const int cb2 = (w & 1) * 64;
    f32x4 acc1[2][4] = {};   // layer-1 logits, cols w*64 + lr*4 + ct
    f32x4 acc2[2][4] = {};   // layer-2, cols cb2 + lr*4 + ct
    for (int kb = 0; kb < 4; ++kb) {
        s16x8 afr0 = *(const s16x8*)&A[lr][kb * 32 + lq * 8];
        s16x8 afr1 = *(const s16x8*)&A[16 + lr][kb * 32 + lq * 8];
#pragma unroll
        for (int ct = 0; ct < 4; ++ct) {
            const int n1 = w * 64 + ct * 16 + lr;
            s16x8 bfr = *(const s16x8*)&Wet[(size_t)n1 * 128 + kb * 32 + lq * 8];
            acc1[0][ct] = __builtin_amdgcn_mfma_f32_16x16x32_bf16(afr0, bfr, acc1[0][ct], 0, 0, 0);
            acc1[1][ct] = __builtin_amdgcn_mfma_f32_16x16x32_bf16(afr1, bfr, acc1[1][ct], 0, 0, 0);
        }
#pragma unroll
        for (int ct = 0; ct < 4; ++ct) {
            const int n2 = cb2 + ct * 16 + lr;
            s16x8 bfr = *(const s16x8*)&Wt2[(size_t)n2 * 128 + kb * 32 + lq * 8];
            acc2[0][ct] = __builtin_amdgcn_mfma_f32_16x16x32_bf16(afr0, bfr, acc2[0][ct], 0, 0, 0);
            acc2[1][ct] = __builtin_amdgcn_mfma_f32_16x16x32_bf16(afr1, bfr, acc2[1][ct], 0, 0, 0);
        }
    }
    // ---- layer-2 epilogue: 4 contiguous cols per lane -> one 8B store/row
    {
        const float4 b2q = *(const float4*)&b2[cb2 + lr * 4];
#pragma unroll
        for (int rt = 0; rt < 2; ++rt)
#pragma unroll
            for (int reg = 0; reg < 4; ++reg) {
                const int row = e0 + rt * 16 + lq * 4 + reg;
                ushort4 o;
                o.x = f2bs(acc2[rt][0][reg] + b2q.x);
                o.y = f2bs(acc2[rt][1][reg] + b2q.y);
                o.z = f2bs(acc2[rt][2][reg] + b2q.z);
                o.w = f2bs(acc2[rt][3][reg] + b2q.w);
                if (w < 2) *(ushort4*)&xl_e[(size_t)row * 128 + cb2 + lr * 4] = o;
                else       *(ushort4*)&xrst[(size_t)row * 256 + cb2 + lr * 4] = o;
            }
    }
    // ---- layer-1 logits: 8B gathers (4 contiguous cols), leaky, dot(att)
    const float4 attq = *(const float4*)&att[w * 64 + lr * 4];
    const int co = w * 64 + lr * 4;
    float sums[2][4];
#pragma unroll
    for (int rt = 0; rt < 2; ++rt) {
        ushort4 xlv[4], xrv[4];
#pragma unroll
        for (int reg = 0; reg < 4; ++reg) {
            const int rowt = rt * 16 + lq * 4 + reg;
            xlv[reg] = *(const ushort4*)&xl_n[(size_t)ss[rowt] * 256 + co];
            xrv[reg] = *(const ushort4*)&xr_n[(size_t)dd[rowt] * 256 + co];
        }
#pragma unroll
        for (int reg = 0; reg < 4; ++reg) {
            float m0 = acc1[rt][0][reg] + bs2f(xlv[reg].x) + bs2f(xrv[reg].x);
            float m1 = acc1[rt][1][reg] + bs2f(xlv[reg].y) + bs2f(xrv[reg].y);
            float m2 = acc1[rt][2][reg] + bs2f(xlv[reg].z) + bs2f(xrv[reg].z);
            float m3 = acc1[rt][3][reg] + bs2f(xlv[reg].w) + bs2f(xrv[reg].w);
            m0 = m0 > 0.f ? m0 : 0.2f * m0;
            m1 = m1 > 0.f ? m1 : 0.2f * m1;
            m2 = m2 > 0.f ? m2 : 0.2f * m2;
            m3 = m3 > 0.f ? m3 : 0.2f * m3;
            sums[rt][reg] = m0 * attq.x + m1 * attq.y + m2 * attq.z + m3 * attq.w;
        }
    }
#pragma unroll
    for (int rt = 0; rt < 2; ++rt)
#pragma unroll
        for (int reg = 0; reg < 4; ++reg) {
            float p = sums[rt][reg];
            p += __shfl_xor(p, 8);
            p += __shfl_xor(p, 4);
            p += __shfl_xor(p, 2);
            p += __shfl_xor(p, 1);
            if (lr == 0)
                alpha[(size_t)pp[rt * 16 + lq * 4 + reg] * 4 + w] = p;
        }
}

// ---------------------------------------------------------------------------
// K4: layer-1 online-softmax + gather. One node per WAVE, 4 dims/lane.
// CSR payload arrays (src_csr, alpha_csr) -> sequential loads + ONE gather level.
__global__ __launch_bounds__(256) void k_fused1(
    const int* __restrict__ off, const int* __restrict__ srcc,
    const float* __restrict__ alphac,
    const u16* __restrict__ xl,
    const float* __restrict__ bias,
    float* __restrict__ out)
{
    const int wv = __builtin_amdgcn_readfirstlane(threadIdx.x >> 6);
    const int lane = threadIdx.x & 63;
    const int n = blockIdx.x * 4 + wv;
    const int c = lane * 4;            // dims c..c+3
    const int h = lane >> 4;           // head (64 dims / head, 16 lanes / head)
    const int beg = off[n], end = off[n + 1];
    float mx = -INFINITY, den = 0.f;
    float a0 = 0.f, a1 = 0.f, a2 = 0.f, a3 = 0.f;
    int i = beg;
    while (i < end) {
        const int rem = end - i;       // >= 1, wave-uniform
        int sa[8]; float pe[8];
#pragma unroll
        for (int k = 0; k < 8; ++k) {
            const int idx = i + (k < rem ? k : rem - 1);
            sa[k] = srcc[idx];
            pe[k] = alphac[(size_t)idx * 4 + h];
        }
        ushort4 xv[8];
#pragma unroll
        for (int k = 0; k < 8; ++k)
            xv[k] = *(const ushort4*)&xl[(size_t)sa[k] * 256 + c];
#pragma unroll
        for (int k = 0; k < 8; ++k) {
            const float p = (k < rem) ? pe[k] : -INFINITY;
            const float mnew = fmaxf(mx, p);
            const float sc = __expf(mx - mnew);
            const float ex = __expf(p - mnew);
            den = den * sc + ex;
            a0 = a0 * sc + ex * bs2f(xv[k].x);
            a1 = a1 * sc + ex * bs2f(xv[k].y);
            a2 = a2 * sc + ex * bs2f(xv[k].z);
            a3 = a3 * sc + ex * bs2f(xv[k].w);
            mx = mnew;
        }
        i += 8;
    }
    const float inv = 1.f / (den + 1e-16f);
    float4 r;
    r.x = a0 * inv + bias[c + 0];
    r.y = a1 * inv + bias[c + 1];
    r.z = a2 * inv + bias[c + 2];
    r.w = a3 * inv + bias[c + 3];
    if (lane < 32) *(float4*)&out[(size_t)n * 128 + c] = r;
    else           *(float4*)&out[XLG_OFF + (size_t)n * 128 + (c - 128)] = r;
}

// ---------------------------------------------------------------------------
// K5 (MFMA): proj = node_out @ e2n_We  [N,128] bf16
__global__ __launch_bounds__(256) void k_proj_gemm(
    const float* __restrict__ out_node, const u16* __restrict__ We2t,  // [128][256]
    u16* __restrict__ proj)
{
    __shared__ u16 A[32][260];
    const int n0 = blockIdx.x * 32;
    const int tid = threadIdx.x;
    for (int i = tid; i < 32 * 64; i += 256) {
        const int r = i >> 6, k4 = (i & 63) << 2;
        const float* srcp = (k4 < 128)
            ? &out_node[(size_t)(n0 + r) * 128 + k4]
            : &out_node[XLG_OFF + (size_t)(n0 + r) * 128 + (k4 - 128)];
        const float4 v = *(const float4*)srcp;
        ushort4 o; o.x = f2bs(v.x); o.y = f2bs(v.y); o.z = f2bs(v.z); o.w = f2bs(v.w);
        *(ushort4*)&A[r][k4] = o;
    }
    __syncthreads();
    const int w = tid >> 6, lane = tid & 63, lr = lane & 15, lq = lane >> 4;
    f32x4 acc[2][2] = {};
    for (int kb = 0; kb < 8; ++kb) {
        s16x8 afr0 = *(const s16x8*)&A[lr][kb * 32 + lq * 8];
        s16x8 afr1 = *(const s16x8*)&A[16 + lr][kb * 32 + lq * 8];
#pragma unroll
        for (int ct = 0; ct < 2; ++ct) {
            const int col = w * 32 + ct * 16 + lr;
            s16x8 bfr = *(const s16x8*)&We2t[(size_t)col * 256 + kb * 32 + lq * 8];
            acc[0][ct] = __builtin_amdgcn_mfma_f32_16x16x32_bf16(afr0, bfr, acc[0][ct], 0, 0, 0);
            acc[1][ct] = __builtin_amdgcn_mfma_f32_16x16x32_bf16(afr1, bfr, acc[1][ct], 0, 0, 0);
        }
    }
#pragma unroll
    for (int rt = 0; rt < 2; ++rt)
#pragma unroll
        for (int ct = 0; ct < 2; ++ct) {
            const int col = w * 32 + ct * 16 + lr;
#pragma unroll
            for (int reg = 0; reg < 4; ++reg) {
                const int row = n0 + rt * 16 + lq * 4 + reg;
                proj[(size_t)row * 128 + col] = f2bs(acc[rt][ct][reg]);
            }
        }
}

// ---------------------------------------------------------------------------
// K6: layer-2 fused logits + online softmax + aggregate. One row per WAVE,
// 2 dims/lane. CSR payload int2 {s, nf} -> sequential load + ONE gather level.
__global__ __launch_bounds__(256) void k_fused2(
    const int* __restrict__ off, const int2* __restrict__ sf2,
    const u16* __restrict__ xl,        // [E,128] trace@Wl2+bl2 bf16
    const u16* __restrict__ proj,      // [N,128] bf16
    const float* __restrict__ att,
    const float* __restrict__ bias,
    float* __restrict__ out)
{
    const int wv = __builtin_amdgcn_readfirstlane(threadIdx.x >> 6);
    const int lane = threadIdx.x & 63;
    const int d = blockIdx.x * 4 + wv;
    const int c = lane * 2;            // dims c, c+1 (head = lane>>4, 16 lanes/head)
    const u16* xrst = (const u16*)(out + XT_OFF);
    const unsigned xrp = *(const unsigned*)&xrst[(size_t)d * 256 + c];
    const float xr0 = bs2f((u16)(xrp & 0xffff));
    const float xr1 = bs2f((u16)(xrp >> 16));
    const float av0 = att[c], av1 = att[c + 1];
    const int beg = off[d], end = off[d + 1];
    float mx = -INFINITY, den = 0.f, a0 = 0.f, a1 = 0.f;
    int i = beg;
    while (i < end) {
        const int rem = end - i;       // >= 1, wave-uniform
        int2 sf[4];
#pragma unroll
        for (int k = 0; k < 4; ++k) sf[k] = sf2[i + (k < rem ? k : rem - 1)];
        unsigned xv[4], pv[4];
#pragma unroll
        for (int k = 0; k < 4; ++k) {
            xv[k] = *(const unsigned*)&xl[(size_t)sf[k].x * 128 + c];
            pv[k] = *(const unsigned*)&proj[(size_t)sf[k].y * 128 + c];
        }
#pragma unroll
        for (int k = 0; k < 4; ++k) {
            const float x0 = bs2f((u16)(xv[k] & 0xffff));
            const float x1 = bs2f((u16)(xv[k] >> 16));
            float m0 = x0 + xr0 + bs2f((u16)(pv[k] & 0xffff));
            float m1 = x1 + xr1 + bs2f((u16)(pv[k] >> 16));
            m0 = m0 > 0.f ? m0 : 0.2f * m0;
            m1 = m1 > 0.f ? m1 : 0.2f * m1;
            float pp = m0 * av0 + m1 * av1;
            pp += __shfl_xor(pp, 8, 16);
            pp += __shfl_xor(pp, 4, 16);
            pp += __shfl_xor(pp, 2, 16);
            pp += __shfl_xor(pp, 1, 16);
            const float p = (k < rem) ? pp : -INFINITY;
            const float mnew = fmaxf(mx, p);
            const float sc = __expf(mx - mnew);
            const float ex = __expf(p - mnew);
            den = den * sc + ex;
            a0 = a0 * sc + ex * x0;
            a1 = a1 * sc + ex * x1;
            mx = mnew;
        }
        i += 4;
    }
    const float inv = 1.f / (den + 1e-16f);
    float2 o2;
    o2.x = a0 * inv + bias[c];
    o2.y = a1 * inv + bias[c + 1];
    *(float2*)&out[XT_OFF + (size_t)d * 128 + c] = o2;
}

// ---------------------------------------------------------------------------
extern "C" void kernel_launch(void* const* d_in, const int* in_sizes, int n_in,
                              void* d_out, int out_size, void* d_ws, size_t ws_size,
                              hipStream_t stream)
{
    const float* x_node   = (const float*)d_in[0];
    const float* x_trace  = (const float*)d_in[1];
    const float* x_log    = (const float*)d_in[2];
    const int*   node_adj = (const int*)d_in[3];
    const int*   edge_adj = (const int*)d_in[4];
    const int*   efea     = (const int*)d_in[5];
    const float* n2n_Wl   = (const float*)d_in[6];
    const float* n2n_bl   = (const float*)d_in[7];
    const float* n2n_Wr   = (const float*)d_in[8];
    const float* n2n_br   = (const float*)d_in[9];
    const float* n2n_We   = (const float*)d_in[10];
    const float* n2n_att  = (const float*)d_in[11];
    const float* n2n_bias = (const float*)d_in[12];
    const float* e2n_Wl   = (const float*)d_in[13];
    const float* e2n_bl   = (const float*)d_in[14];
    const float* e2n_Wr   = (const float*)d_in[15];
    const float* e2n_br   = (const float*)d_in[16];
    const float* e2n_We   = (const float*)d_in[17];
    const float* e2n_att  = (const float*)d_in[18];
    const float* e2n_bias = (const float*)d_in[19];
    float* out = (float*)d_out;

    // ---- workspace layout (~51 MB) ----
    char* w = (char*)d_ws;
    int*  cnt1   = (int*)w;   w += (size_t)N * 4;        // zeroed below
    int*  cnt2   = (int*)w;   w += (size_t)E * 4;        // zeroed below
    int*  off1   = (int*)w;   w += (size_t)(N + 4) * 4;
    int*  cur1   = (int*)w;   w += (size_t)N * 4;
    int*  src1   = (int*)w;   w += (size_t)E * 4;        // CSR payload: src node
    int*  pos1   = (int*)w;   w += (size_t)E * 4;        // edge -> CSR pos
    float* alphac = (float*)w; w += (size_t)E * 4 * 4;   // CSR-ordered alpha [E][4]
    int*  off2   = (int*)w;   w += (size_t)(E + 4) * 4;
    int*  cur2   = (int*)w;   w += (size_t)E * 4;
    int2* sf2    = (int2*)w;  w += (size_t)E2 * 8;       // CSR payload: {s, nf}
    u16*  xl_n   = (u16*)w;   w += (size_t)N * 256 * 2;
    u16*  xr_n   = (u16*)w;   w += (size_t)N * 256 * 2;
    u16*  xl_e   = (u16*)w;   w += (size_t)E * 128 * 2;
    u16*  proj   = (u16*)w;   w += (size_t)N * 128 * 2;
    u16*  Wlt    = (u16*)w;   w += (size_t)65536 * 2;
    u16*  Wrt    = (u16*)w;   w += (size_t)65536 * 2;
    u16*  Wet    = (u16*)w;   w += (size_t)32768 * 2;
    u16*  Wl2t   = (u16*)w;   w += (size_t)16384 * 2;
    u16*  Wr2t   = (u16*)w;   w += (size_t)16384 * 2;
    u16*  We2t   = (u16*)w;   w += (size_t)32768 * 2;

    hipMemsetAsync(d_ws, 0, (size_t)(N + E) * 4, stream);

    // ---- prep + CSR builds ----
    k_prep<<<896, 256, 0, stream>>>(n2n_Wl, n2n_Wr, n2n_We, e2n_Wl, e2n_Wr, e2n_We,
                                    Wlt, Wrt, Wet, Wl2t, Wr2t, We2t);
    k_hist<<<E / 256, 256, 0, stream>>>(node_adj + E, cnt1, E);
    k_scan<<<1, 1024, 0, stream>>>(cnt1, off1, cur1, N);
    k_scatter1<<<E / 256, 256, 0, stream>>>(node_adj, cur1, src1, pos1, E);
    k_hist<<<E2 / 256, 256, 0, stream>>>(edge_adj + E2, cnt2, E2);
    k_scan<<<1, 1024, 0, stream>>>(cnt2, off2, cur2, E);
    k_scatter2<<<E2 / 256, 256, 0, stream>>>(edge_adj, efea, cur2, sf2, E2);

    // ---- layer 1 (+ layer-2 trace GEMMs fused into k_edge_mm) ----
    k_node_gemm<<<N / 32, 256, 0, stream>>>(x_node, x_log, Wlt, n2n_bl, Wrt, n2n_br,
                                            xl_n, xr_n);
    k_edge_mm<<<E / 32, 256, 0, stream>>>(x_trace, node_adj, pos1, xl_n, xr_n,
                                          Wet, Wl2t, e2n_bl, Wr2t, e2n_br,
                                          n2n_att, alphac, xl_e, (u16*)(out + XT_OFF));
    k_fused1<<<N / 4, 256, 0, stream>>>(off1, src1, alphac, xl_n, n2n_bias, out);

    // ---- layer 2 ----
    k_proj_gemm<<<N / 32, 256, 0, stream>>>(out, We2t, proj);
    k_fused2<<<E / 4, 256, 0, stream>>>(off2, sf2, xl_e, proj,
                                        e2n_att, e2n_bias, out);
}

// Round 7
// 453.846 us; speedup vs baseline: 1.2583x; 1.0343x over previous
//
#include <hip/hip_runtime.h>
#include <hip/hip_bf16.h>

// Problem constants (match reference)
constexpr int N    = 8192;     // nodes
constexpr int E    = 131072;   // node-graph edges == trace rows
constexpr int E2   = 524288;   // line-graph edges

constexpr size_t XT_OFF  = (size_t)N * 128;
constexpr size_t XLG_OFF = XT_OFF + (size_t)E * 128;

typedef unsigned short u16;
typedef short s16x8 __attribute__((ext_vector_type(8)));
typedef float f32x4 __attribute__((ext_vector_type(4)));

__device__ __forceinline__ u16 f2bs(float f) {   // f32 -> bf16 bits, RNE
    unsigned x = __float_as_uint(f);
    return (u16)((x + 0x7FFF + ((x >> 16) & 1)) >> 16);
}
__device__ __forceinline__ float bs2f(u16 u) {
    return __uint_as_float((unsigned)u << 16);
}

// ---------------------------------------------------------------------------
// K0: weight pre-transpose f32 [K,Ncol] -> bf16 [Ncol,K] (one launch, all 6).
// Wet/Wl2t/Wr2t rows are PERMUTED within each 64-col window so that the MFMA
// output position (ct*16+lr) computes original col (lr*4+ct): lane lr then
// owns 4 CONTIGUOUS cols -> ushort4 gathers/stores in k_edge_mm.
__global__ __launch_bounds__(256) void k_prep(
    const float* __restrict__ Wl, const float* __restrict__ Wr,
    const float* __restrict__ We, const float* __restrict__ Wl2,
    const float* __restrict__ Wr2, const float* __restrict__ We2,
    u16* __restrict__ Wlt, u16* __restrict__ Wrt, u16* __restrict__ Wet,
    u16* __restrict__ Wl2t, u16* __restrict__ Wr2t, u16* __restrict__ We2t)
{
    const int gid = blockIdx.x * 256 + threadIdx.x;
    const float* src; u16* dst; int base, Kk, sh, perm;
    if      (gid <  65536) { src = Wl;  dst = Wlt;  base = 0;      Kk = 256; sh = 8; perm = 0; }
    else if (gid < 131072) { src = Wr;  dst = Wrt;  base = 65536;  Kk = 256; sh = 8; perm = 0; }
    else if (gid < 163840) { src = We;  dst = Wet;  base = 131072; Kk = 128; sh = 8; perm = 1; }
    else if (gid < 180224) { src = Wl2; dst = Wl2t; base = 163840; Kk = 128; sh = 7; perm = 1; }
    else if (gid < 196608) { src = Wr2; dst = Wr2t; base = 180224; Kk = 128; sh = 7; perm = 1; }
    else                   { src = We2; dst = We2t; base = 196608; Kk = 256; sh = 7; perm = 0; }
    const int l = gid - base;
    const int k = l >> sh, nn = l & ((1 << sh) - 1);
    int ns = nn;
    if (perm) ns = (nn & ~63) | ((nn & 3) << 4) | ((nn >> 2) & 15);
    dst[(size_t)ns * Kk + k] = f2bs(src[l]);
}

// ---------------------------------------------------------------------------
// CSR build: histogram -> single-block scan -> payload scatter
__global__ void k_hist(const int* __restrict__ dst, int* __restrict__ cnt, int nE)
{
    int i = blockIdx.x * 256 + threadIdx.x;
    if (i < nE) atomicAdd(&cnt[dst[i]], 1);
}

// 1024-thread single-block scan, 8 items/thread per 8192-tile
__global__ __launch_bounds__(1024) void k_scan(
    const int* __restrict__ cnt, int* __restrict__ off, int* __restrict__ cur, int n)
{
    __shared__ int tile[8192];
    __shared__ int wsum[16];
    const int tid = threadIdx.x, lane = tid & 63, wv = tid >> 6;
    int carry = 0;
    for (int base = 0; base < n; base += 8192) {
        for (int i = tid; i < 8192; i += 1024) tile[i] = cnt[base + i];
        __syncthreads();
        const int st = tid * 8;
        int s = 0;
        for (int k = 0; k < 8; ++k) { int v = tile[st + k]; tile[st + k] = s; s += v; }
        const int tsum = s;
        int incl = s;
        for (int o = 1; o < 64; o <<= 1) {
            int v = __shfl_up(incl, o);
            if (lane >= o) incl += v;
        }
        if (lane == 63) wsum[wv] = incl;
        __syncthreads();
        int woff = 0;
        for (int wq = 0; wq < wv; ++wq) woff += wsum[wq];
        int tot = 0;
        for (int wq = 0; wq < 16; ++wq) tot += wsum[wq];
        const int add = carry + woff + incl - tsum;
        for (int k = 0; k < 8; ++k) {
            int o2 = add + tile[st + k];
            off[base + st + k] = o2;
            cur[base + st + k] = o2;
        }
        carry += tot;
        __syncthreads();
    }
    if (tid == 0) off[n] = carry;
}

// layer-1 scatter: payload = src node; also inverse map pos1[e] for alpha write
__global__ void k_scatter1(const int* __restrict__ adj, int* __restrict__ cur,
                           int* __restrict__ srcc, int* __restrict__ pos1, int nE)
{
    int i = blockIdx.x * 256 + threadIdx.x;
    if (i < nE) {
        int pos = atomicAdd(&cur[adj[nE + i]], 1);
        srcc[pos] = adj[i];
        pos1[i] = pos;
    }
}

// layer-2 scatter: payload = {src line-edge, node-feature idx}
__global__ void k_scatter2(const int* __restrict__ eadj, const int* __restrict__ efea,
                           int* __restrict__ cur, int2* __restrict__ sf2, int nE)
{
    int i = blockIdx.x * 256 + threadIdx.x;
    if (i < nE) {
        int pos = atomicAdd(&cur[eadj[nE + i]], 1);
        sf2[pos] = make_int2(eadj[i], efea[i]);
    }
}

// ---------------------------------------------------------------------------
// K1 (MFMA): xl_n/xr_n = concat(x_node,x_log) @ {Wl,Wr} + bias -> bf16 [N,256]
__global__ __launch_bounds__(256) void k_node_gemm(
    const float* __restrict__ x_node, const float* __restrict__ x_log,
    const u16* __restrict__ Wlt, const float* __restrict__ bl,
    const u16* __restrict__ Wrt, const float* __restrict__ br,
    u16* __restrict__ xl, u16* __restrict__ xr)
{
    __shared__ u16 A[32][260];
    const int n0 = blockIdx.x * 32;
    const int tid = threadIdx.x;
    for (int i = tid; i < 32 * 64; i += 256) {
        const int r = i >> 6, k4 = (i & 63) << 2;
        const float* srcp = (k4 < 128) ? &x_node[(size_t)(n0 + r) * 128 + k4]
                                       : &x_log [(size_t)(n0 + r) * 128 + (k4 - 128)];
        const float4 v = *(const float4*)srcp;
        ushort4 o; o.x = f2bs(v.x); o.y = f2bs(v.y); o.z = f2bs(v.z); o.w = f2bs(v.w);
        *(ushort4*)&A[r][k4] = o;
    }
    __syncthreads();
    const int w = tid >> 6, lane = tid & 63, lr = lane & 15, lq = lane >> 4;
    const u16* Wt     = (w < 2) ? Wlt : Wrt;
    const float* bias = (w < 2) ? bl : br;
    u16* outp         = (w < 2) ? xl : xr;
    const int cb = (w & 1) * 128;
    f32x4 acc[2][8] = {};
    for (int kb = 0; kb < 8; ++kb) {
        s16x8 afr0 = *(const s16x8*)&A[lr][kb * 32 + lq * 8];
        s16x8 afr1 = *(const s16x8*)&A[16 + lr][kb * 32 + lq * 8];
#pragma unroll
        for (int ct = 0; ct < 8; ++ct) {
            const int n = cb + ct * 16 + lr;
            s16x8 bfr = *(const s16x8*)&Wt[(size_t)n * 256 + kb * 32 + lq * 8];
            acc[0][ct] = __builtin_amdgcn_mfma_f32_16x16x32_bf16(afr0, bfr, acc[0][ct], 0, 0, 0);
            acc[1][ct] = __builtin_amdgcn_mfma_f32_16x16x32_bf16(afr1, bfr, acc[1][ct], 0, 0, 0);
        }
    }
#pragma unroll
    for (int rt = 0; rt < 2; ++rt)
#pragma unroll
        for (int ct = 0; ct < 8; ++ct) {
            const int col = cb + ct * 16 + lr;
            const float bv = bias[col];
#pragma unroll
            for (int reg = 0; reg < 4; ++reg) {
                const int row = n0 + rt * 16 + lq * 4 + reg;
                outp[(size_t)row * 256 + col] = f2bs(acc[rt][ct][reg] + bv);
            }
        }
}

// ---------------------------------------------------------------------------
// K3 (MFMA, fused, WAVE-SPECIALIZED): 512 threads, 32 edges/block.
//   waves 0-3 (role 0): layer-1 logits — EARLY gathers (xl_n/xr_n) issued
//                       before the acc1 MFMA loop, consumed after.
//   waves 4-7 (role 1): layer-2 GEMMs (Wl2 -> xl_e, Wr2 -> xrst staging).
// Each wave's serial chain is ~half of the previous fused version; gather
// latency hides under the MFMA/weight-load phase.
__global__ __launch_bounds__(512) void k_edge_mm(
    const float* __restrict__ x_trace,
    const int* __restrict__ adj,          // [2,E] src then dst
    const int* __restrict__ pos1,
    const u16* __restrict__ xl_n, const u16* __restrict__ xr_n,  // [N,256] bf16
    const u16* __restrict__ Wet,                                  // [256][128] perm
    const u16* __restrict__ Wl2t, const float* __restrict__ bl2,  // [128][128] perm
    const u16* __restrict__ Wr2t, const float* __restrict__ br2,
    const float* __restrict__ att,
    float* __restrict__ alpha, u16* __restrict__ xl_e, u16* __restrict__ xrst)
{
    __shared__ u16 A[32][132];
    __shared__ int ss[32], dd[32], pp[32];
    const int e0 = blockIdx.x * 32;
    const int tid = threadIdx.x;
    for (int i = tid; i < 32 * 32; i += 512) {
        const int r = i >> 5, k4 = (i & 31) << 2;
        const float4 v = *(const float4*)&x_trace[(size_t)(e0 + r) * 128 + k4];
        ushort4 o; o.x = f2bs(v.x); o.y = f2bs(v.y); o.z = f2bs(v.z); o.w = f2bs(v.w);
        *(ushort4*)&A[r][k4] = o;
    }
    if (tid < 32) {
        ss[tid] = adj[e0 + tid];
        dd[tid] = adj[E + e0 + tid];
        pp[tid] = pos1[e0 + tid];
    }
    __syncthreads();
    const int w8 = tid >> 6;           // 0..7
    const int role = w8 >> 2;          // 0: logits, 1: layer-2 GEMM
    const int w = w8 & 3;
    const int lane = tid & 63, lr = lane & 15, lq = lane >> 4;

    if (role == 0) {
        // ---- EARLY gathers: issue all 16 8B loads before the MFMA loop
        const int co = w * 64 + lr * 4;
        ushort4 xlv[2][4], xrv[2][4];
#pragma unroll
        for (int rt = 0; rt < 2; ++rt)
#pragma unroll
            for (int reg = 0; reg < 4; ++reg) {
                const int rowt = rt * 16 + lq * 4 + reg;
                xlv[rt][reg] = *(const ushort4*)&xl_n[(size_t)ss[rowt] * 256 + co];
                xrv[rt][reg] = *(const ushort4*)&xr_n[(size_t)dd[rowt] * 256 + co];
            }
        // ---- acc1 MFMA: trace@We for head w (cols w*64 + lr*4 + ct)
        f32x4 acc1[2][4] = {};
        for (int kb = 0; kb < 4; ++kb) {
            s16x8 afr0 = *(const s16x8*)&A[lr][kb * 32 + lq * 8];
            s16x8 afr1 = *(const s16x8*)&A[16 + lr][kb * 32 + lq * 8];
#pragma unroll
            for (int ct = 0; ct < 4; ++ct) {
                const int n1 = w * 64 + ct * 16 + lr;
                s16x8 bfr = *(const s16x8*)&Wet[(size_t)n1 * 128 + kb * 32 + lq * 8];
                acc1[0][ct] = __builtin_amdgcn_mfma_f32_16x16x32_bf16(afr0, bfr, acc1[0][ct], 0, 0, 0);
                acc1[1][ct] = __builtin_amdgcn_mfma_f32_16x16x32_bf16(afr1, bfr, acc1[1][ct], 0, 0, 0);
            }
        }
        // ---- logits: combine gathers + acc1, leaky, dot(att), reduce
        const float4 attq = *(const float4*)&att[w * 64 + lr * 4];
        float sums[2][4];
#pragma unroll
        for (int rt = 0; rt < 2; ++rt)
#pragma unroll
            for (int reg = 0; reg < 4; ++reg) {
                float m0 = acc1[rt][0][reg] + bs2f(xlv[rt][reg].x) + bs2f(xrv[rt][reg].x);
                float m1 = acc1[rt][1][reg] + bs2f(xlv[rt][reg].y) + bs2f(xrv[rt][reg].y);
                float m2 = acc1[rt][2][reg] + bs2f(xlv[rt][reg].z) + bs2f(xrv[rt][reg].z);
                float m3 = acc1[rt][3][reg] + bs2f(xlv[rt][reg].w) + bs2f(xrv[rt][reg].w);
                m0 = m0 > 0.f ? m0 : 0.2f * m0;
                m1 = m1 > 0.f ? m1 : 0.2f * m1;
                m2 = m2 > 0.f ? m2 : 0.2f * m2;
                m3 = m3 > 0.f ? m3 : 0.2f * m3;
                sums[rt][reg] = m0 * attq.x + m1 * attq.y + m2 * attq.z + m3 * attq.w;
            }
#pragma unroll
        for (int rt = 0; rt < 2; ++rt)
#pragma unroll
            for (int reg = 0; reg < 4; ++reg) {
                float p = sums[rt][reg];
                p += __shfl_xor(p, 8);
                p += __shfl_xor(p, 4);
                p += __shfl_xor(p, 2);
                p += __shfl_xor(p, 1);
                if (lr == 0)
                    alpha[(size_t)pp[rt * 16 + lq * 4 + reg] * 4 + w] = p;
            }
    } else {
        // ---- acc2 MFMA: trace@{Wl2,Wr2} (w<2 -> xl_e cols, else xrst cols)
        const u16* Wt2  = (w < 2) ? Wl2t : Wr2t;
        const float* b2 = (w < 2) ? bl2 : br2;
        const int cb2 = (w & 1) * 64;
        f32x4 acc2[2][4] = {};
        for (int kb = 0; kb < 4; ++kb) {
            s16x8 afr0 = *(const s16x8*)&A[lr][kb * 32 + lq * 8];
            s16x8 afr1 = *(const s16x8*)&A[16 + lr][kb * 32 + lq * 8];
#pragma unroll
            for (int ct = 0; ct < 4; ++ct) {
                const int n2 = cb2 + ct * 16 + lr;
                s16x8 bfr = *(const s16x8*)&Wt2[(size_t)n2 * 128 + kb * 32 + lq * 8];
                acc2[0][ct] = __builtin_amdgcn_mfma_f32_16x16x32_bf16(afr0, bfr, acc2[0][ct], 0, 0, 0);
                acc2[1][ct] = __builtin_amdgcn_mfma_f32_16x16x32_bf16(afr1, bfr, acc2[1][ct], 0, 0, 0);
            }
        }
        const float4 b2q = *(const float4*)&b2[cb2 + lr * 4];
#pragma unroll
        for (int rt = 0; rt < 2; ++rt)
#pragma unroll
            for (int reg = 0; reg < 4; ++reg) {
                const int row = e0 + rt * 16 + lq * 4 + reg;
                ushort4 o;
                o.x = f2bs(acc2[rt][0][reg] + b2q.x);
                o.y = f2bs(acc2[rt][1][reg] + b2q.y);
                o.z = f2bs(acc2[rt][2][reg] + b2q.z);
                o.w = f2bs(acc2[rt][3][reg] + b2q.w);
                if (w < 2) *(ushort4*)&xl_e[(size_t)row * 128 + cb2 + lr * 4] = o;
                else       *(ushort4*)&xrst[(size_t)row * 256 + cb2 + lr * 4] = o;
            }
    }
}

// ---------------------------------------------------------------------------
// K4: layer-1 online-softmax + gather. One node per WAVE, 4 dims/lane.
// CSR payload arrays (src_csr, alpha_csr) -> sequential loads + ONE gather level.
__global__ __launch_bounds__(256) void k_fused1(
    const int* __restrict__ off, const int* __restrict__ srcc,
    const float* __restrict__ alphac,
    const u16* __restrict__ xl,
    const float* __restrict__ bias,
    float* __restrict__ out)
{
    const int wv = __builtin_amdgcn_readfirstlane(threadIdx.x >> 6);
    const int lane = threadIdx.x & 63;
    const int n = blockIdx.x * 4 + wv;
    const int c = lane * 4;            // dims c..c+3
    const int h = lane >> 4;           // head (64 dims / head, 16 lanes / head)
    const int beg = off[n], end = off[n + 1];
    float mx = -INFINITY, den = 0.f;
    float a0 = 0.f, a1 = 0.f, a2 = 0.f, a3 = 0.f;
    int i = beg;
    while (i < end) {
        const int rem = end - i;       // >= 1, wave-uniform
        int sa[8]; float pe[8];
#pragma unroll
        for (int k = 0; k < 8; ++k) {
            const int idx = i + (k < rem ? k : rem - 1);
            sa[k] = srcc[idx];
            pe[k] = alphac[(size_t)idx * 4 + h];
        }
        ushort4 xv[8];
#pragma unroll
        for (int k = 0; k < 8; ++k)
            xv[k] = *(const ushort4*)&xl[(size_t)sa[k] * 256 + c];
#pragma unroll
        for (int k = 0; k < 8; ++k) {
            const float p = (k < rem) ? pe[k] : -INFINITY;
            const float mnew = fmaxf(mx, p);
            const float sc = __expf(mx - mnew);
            const float ex = __expf(p - mnew);
            den = den * sc + ex;
            a0 = a0 * sc + ex * bs2f(xv[k].x);
            a1 = a1 * sc + ex * bs2f(xv[k].y);
            a2 = a2 * sc + ex * bs2f(xv[k].z);
            a3 = a3 * sc + ex * bs2f(xv[k].w);
            mx = mnew;
        }
        i += 8;
    }
    const float inv = 1.f / (den + 1e-16f);
    float4 r;
    r.x = a0 * inv + bias[c + 0];
    r.y = a1 * inv + bias[c + 1];
    r.z = a2 * inv + bias[c + 2];
    r.w = a3 * inv + bias[c + 3];
    if (lane < 32) *(float4*)&out[(size_t)n * 128 + c] = r;
    else           *(float4*)&out[XLG_OFF + (size_t)n * 128 + (c - 128)] = r;
}

// ---------------------------------------------------------------------------
// K5 (MFMA): proj = node_out @ e2n_We  [N,128] bf16
__global__ __launch_bounds__(256) void k_proj_gemm(
    const float* __restrict__ out_node, const u16* __restrict__ We2t,  // [128][256]
    u16* __restrict__ proj)
{
    __shared__ u16 A[32][260];
    const int n0 = blockIdx.x * 32;
    const int tid = threadIdx.x;
    for (int i = tid; i < 32 * 64; i += 256) {
        const int r = i >> 6, k4 = (i & 63) << 2;
        const float* srcp = (k4 < 128)
            ? &out_node[(size_t)(n0 + r) * 128 + k4]
            : &out_node[XLG_OFF + (size_t)(n0 + r) * 128 + (k4 - 128)];
        const float4 v = *(const float4*)srcp;
        ushort4 o; o.x = f2bs(v.x); o.y = f2bs(v.y); o.z = f2bs(v.z); o.w = f2bs(v.w);
        *(ushort4*)&A[r][k4] = o;
    }
    __syncthreads();
    const int w = tid >> 6, lane = tid & 63, lr = lane & 15, lq = lane >> 4;
    f32x4 acc[2][2] = {};
    for (int kb = 0; kb < 8; ++kb) {
        s16x8 afr0 = *(const s16x8*)&A[lr][kb * 32 + lq * 8];
        s16x8 afr1 = *(const s16x8*)&A[16 + lr][kb * 32 + lq * 8];
#pragma unroll
        for (int ct = 0; ct < 2; ++ct) {
            const int col = w * 32 + ct * 16 + lr;
            s16x8 bfr = *(const s16x8*)&We2t[(size_t)col * 256 + kb * 32 + lq * 8];
            acc[0][ct] = __builtin_amdgcn_mfma_f32_16x16x32_bf16(afr0, bfr, acc[0][ct], 0, 0, 0);
            acc[1][ct] = __builtin_amdgcn_mfma_f32_16x16x32_bf16(afr1, bfr, acc[1][ct], 0, 0, 0);
        }
    }
#pragma unroll
    for (int rt = 0; rt < 2; ++rt)
#pragma unroll
        for (int ct = 0; ct < 2; ++ct) {
            const int col = w * 32 + ct * 16 + lr;
#pragma unroll
            for (int reg = 0; reg < 4; ++reg) {
                const int row = n0 + rt * 16 + lq * 4 + reg;
                proj[(size_t)row * 128 + col] = f2bs(acc[rt][ct][reg]);
            }
        }
}

// ---------------------------------------------------------------------------
// K6: layer-2 fused logits + online softmax + aggregate. One row per WAVE,
// 2 dims/lane. CSR payload int2 {s, nf} -> sequential load + ONE gather level.
__global__ __launch_bounds__(256) void k_fused2(
    const int* __restrict__ off, const int2* __restrict__ sf2,
    const u16* __restrict__ xl,        // [E,128] trace@Wl2+bl2 bf16
    const u16* __restrict__ proj,      // [N,128] bf16
    const float* __restrict__ att,
    const float* __restrict__ bias,
    float* __restrict__ out)
{
    const int wv = __builtin_amdgcn_readfirstlane(threadIdx.x >> 6);
    const int lane = threadIdx.x & 63;
    const int d = blockIdx.x * 4 + wv;
    const int c = lane * 2;            // dims c, c+1 (head = lane>>4, 16 lanes/head)
    const u16* xrst = (const u16*)(out + XT_OFF);
    const unsigned xrp = *(const unsigned*)&xrst[(size_t)d * 256 + c];
    const float xr0 = bs2f((u16)(xrp & 0xffff));
    const float xr1 = bs2f((u16)(xrp >> 16));
    const float av0 = att[c], av1 = att[c + 1];
    const int beg = off[d], end = off[d + 1];
    float mx = -INFINITY, den = 0.f, a0 = 0.f, a1 = 0.f;
    int i = beg;
    while (i < end) {
        const int rem = end - i;       // >= 1, wave-uniform
        int2 sf[4];
#pragma unroll
        for (int k = 0; k < 4; ++k) sf[k] = sf2[i + (k < rem ? k : rem - 1)];
        unsigned xv[4], pv[4];
#pragma unroll
        for (int k = 0; k < 4; ++k) {
            xv[k] = *(const unsigned*)&xl[(size_t)sf[k].x * 128 + c];
            pv[k] = *(const unsigned*)&proj[(size_t)sf[k].y * 128 + c];
        }
#pragma unroll
        for (int k = 0; k < 4; ++k) {
            const float x0 = bs2f((u16)(xv[k] & 0xffff));
            const float x1 = bs2f((u16)(xv[k] >> 16));
            float m0 = x0 + xr0 + bs2f((u16)(pv[k] & 0xffff));
            float m1 = x1 + xr1 + bs2f((u16)(pv[k] >> 16));
            m0 = m0 > 0.f ? m0 : 0.2f * m0;
            m1 = m1 > 0.f ? m1 : 0.2f * m1;
            float pp = m0 * av0 + m1 * av1;
            pp += __shfl_xor(pp, 8, 16);
            pp += __shfl_xor(pp, 4, 16);
            pp += __shfl_xor(pp, 2, 16);
            pp += __shfl_xor(pp, 1, 16);
            const float p = (k < rem) ? pp : -INFINITY;
            const float mnew = fmaxf(mx, p);
            const float sc = __expf(mx - mnew);
            const float ex = __expf(p - mnew);
            den = den * sc + ex;
            a0 = a0 * sc + ex * x0;
            a1 = a1 * sc + ex * x1;
            mx = mnew;
        }
        i += 4;
    }
    const float inv = 1.f / (den + 1e-16f);
    float2 o2;
    o2.x = a0 * inv + bias[c];
    o2.y = a1 * inv + bias[c + 1];
    *(float2*)&out[XT_OFF + (size_t)d * 128 + c] = o2;
}

// ---------------------------------------------------------------------------
extern "C" void kernel_launch(void* const* d_in, const int* in_sizes, int n_in,
                              void* d_out, int out_size, void* d_ws, size_t ws_size,
                              hipStream_t stream)
{
    const float* x_node   = (const float*)d_in[0];
    const float* x_trace  = (const float*)d_in[1];
    const float* x_log    = (const float*)d_in[2];
    const int*   node_adj = (const int*)d_in[3];
    const int*   edge_adj = (const int*)d_in[4];
    const int*   efea     = (const int*)d_in[5];
    const float* n2n_Wl   = (const float*)d_in[6];
    const float* n2n_bl   = (const float*)d_in[7];
    const float* n2n_Wr   = (const float*)d_in[8];
    const float* n2n_br   = (const float*)d_in[9];
    const float* n2n_We   = (const float*)d_in[10];
    const float* n2n_att  = (const float*)d_in[11];
    const float* n2n_bias = (const float*)d_in[12];
    const float* e2n_Wl   = (const float*)d_in[13];
    const float* e2n_bl   = (const float*)d_in[14];
    const float* e2n_Wr   = (const float*)d_in[15];
    const float* e2n_br   = (const float*)d_in[16];
    const float* e2n_We   = (const float*)d_in[17];
    const float* e2n_att  = (const float*)d_in[18];
    const float* e2n_bias = (const float*)d_in[19];
    float* out = (float*)d_out;

    // ---- workspace layout (~51 MB) ----
    char* w = (char*)d_ws;
    int*  cnt1   = (int*)w;   w += (size_t)N * 4;        // zeroed below
    int*  cnt2   = (int*)w;   w += (size_t)E * 4;        // zeroed below
    int*  off1   = (int*)w;   w += (size_t)(N + 4) * 4;
    int*  cur1   = (int*)w;   w += (size_t)N * 4;
    int*  src1   = (int*)w;   w += (size_t)E * 4;        // CSR payload: src node
    int*  pos1   = (int*)w;   w += (size_t)E * 4;        // edge -> CSR pos
    float* alphac = (float*)w; w += (size_t)E * 4 * 4;   // CSR-ordered alpha [E][4]
    int*  off2   = (int*)w;   w += (size_t)(E + 4) * 4;
    int*  cur2   = (int*)w;   w += (size_t)E * 4;
    int2* sf2    = (int2*)w;  w += (size_t)E2 * 8;       // CSR payload: {s, nf}
    u16*  xl_n   = (u16*)w;   w += (size_t)N * 256 * 2;
    u16*  xr_n   = (u16*)w;   w += (size_t)N * 256 * 2;
    u16*  xl_e   = (u16*)w;   w += (size_t)E * 128 * 2;
    u16*  proj   = (u16*)w;   w += (size_t)N * 128 * 2;
    u16*  Wlt    = (u16*)w;   w += (size_t)65536 * 2;
    u16*  Wrt    = (u16*)w;   w += (size_t)65536 * 2;
    u16*  Wet    = (u16*)w;   w += (size_t)32768 * 2;
    u16*  Wl2t   = (u16*)w;   w += (size_t)16384 * 2;
    u16*  Wr2t   = (u16*)w;   w += (size_t)16384 * 2;
    u16*  We2t   = (u16*)w;   w += (size_t)32768 * 2;

    hipMemsetAsync(d_ws, 0, (size_t)(N + E) * 4, stream);

    // ---- prep + CSR builds ----
    k_prep<<<896, 256, 0, stream>>>(n2n_Wl, n2n_Wr, n2n_We, e2n_Wl, e2n_Wr, e2n_We,
                                    Wlt, Wrt, Wet, Wl2t, Wr2t, We2t);
    k_hist<<<E / 256, 256, 0, stream>>>(node_adj + E, cnt1, E);
    k_scan<<<1, 1024, 0, stream>>>(cnt1, off1, cur1, N);
    k_scatter1<<<E / 256, 256, 0, stream>>>(node_adj, cur1, src1, pos1, E);
    k_hist<<<E2 / 256, 256, 0, stream>>>(edge_adj + E2, cnt2, E2);
    k_scan<<<1, 1024, 0, stream>>>(cnt2, off2, cur2, E);
    k_scatter2<<<E2 / 256, 256, 0, stream>>>(edge_adj, efea, cur2, sf2, E2);

    // ---- layer 1 (+ layer-2 trace GEMMs fused into k_edge_mm) ----
    k_node_gemm<<<N / 32, 256, 0, stream>>>(x_node, x_log, Wlt, n2n_bl, Wrt, n2n_br,
                                            xl_n, xr_n);
    k_edge_mm<<<E / 32, 512, 0, stream>>>(x_trace, node_adj, pos1, xl_n, xr_n,
                                          Wet, Wl2t, e2n_bl, Wr2t, e2n_br,
                                          n2n_att, alphac, xl_e, (u16*)(out + XT_OFF));
    k_fused1<<<N / 4, 256, 0, stream>>>(off1, src1, alphac, xl_n, n2n_bias, out);

    // ---- layer 2 ----
    k_proj_gemm<<<N / 32, 256, 0, stream>>>(out, We2t, proj);
    k_fused2<<<E / 4, 256, 0, stream>>>(off2, sf2, xl_e, proj,
                                        e2n_att, e2n_bias, out);
}

// Round 8
// 427.550 us; speedup vs baseline: 1.3357x; 1.0615x over previous
//
#include <hip/hip_runtime.h>
#include <hip/hip_bf16.h>

// Problem constants (match reference)
constexpr int N    = 8192;     // nodes
constexpr int E    = 131072;   // node-graph edges == trace rows
constexpr int E2   = 524288;   // line-graph edges

constexpr size_t XT_OFF  = (size_t)N * 128;
constexpr size_t XLG_OFF = XT_OFF + (size_t)E * 128;

typedef unsigned short u16;
typedef short s16x8 __attribute__((ext_vector_type(8)));
typedef float f32x4 __attribute__((ext_vector_type(4)));

__device__ __forceinline__ u16 f2bs(float f) {   // f32 -> bf16 bits, RNE
    unsigned x = __float_as_uint(f);
    return (u16)((x + 0x7FFF + ((x >> 16) & 1)) >> 16);
}
__device__ __forceinline__ float bs2f(u16 u) {
    return __uint_as_float((unsigned)u << 16);
}

// ---------------------------------------------------------------------------
// K0: weight pre-transpose f32 [K,Ncol] -> bf16 [Ncol,K] (one launch, all 6).
// Wet/Wl2t/Wr2t rows are PERMUTED within each 64-col window so that the MFMA
// output position (ct*16+lr) computes original col (lr*4+ct): lane lr then
// owns 4 CONTIGUOUS cols -> ushort4 gathers/stores in k_edge_mm.
__global__ __launch_bounds__(256) void k_prep(
    const float* __restrict__ Wl, const float* __restrict__ Wr,
    const float* __restrict__ We, const float* __restrict__ Wl2,
    const float* __restrict__ Wr2, const float* __restrict__ We2,
    u16* __restrict__ Wlt, u16* __restrict__ Wrt, u16* __restrict__ Wet,
    u16* __restrict__ Wl2t, u16* __restrict__ Wr2t, u16* __restrict__ We2t)
{
    const int gid = blockIdx.x * 256 + threadIdx.x;
    const float* src; u16* dst; int base, Kk, sh, perm;
    if      (gid <  65536) { src = Wl;  dst = Wlt;  base = 0;      Kk = 256; sh = 8; perm = 0; }
    else if (gid < 131072) { src = Wr;  dst = Wrt;  base = 65536;  Kk = 256; sh = 8; perm = 0; }
    else if (gid < 163840) { src = We;  dst = Wet;  base = 131072; Kk = 128; sh = 8; perm = 1; }
    else if (gid < 180224) { src = Wl2; dst = Wl2t; base = 163840; Kk = 128; sh = 7; perm = 1; }
    else if (gid < 196608) { src = Wr2; dst = Wr2t; base = 180224; Kk = 128; sh = 7; perm = 1; }
    else                   { src = We2; dst = We2t; base = 196608; Kk = 256; sh = 7; perm = 0; }
    const int l = gid - base;
    const int k = l >> sh, nn = l & ((1 << sh) - 1);
    int ns = nn;
    if (perm) ns = (nn & ~63) | ((nn & 3) << 4) | ((nn >> 2) & 15);
    dst[(size_t)ns * Kk + k] = f2bs(src[l]);
}

// ---------------------------------------------------------------------------
// CSR build: histogram -> single-block scan -> payload scatter
__global__ void k_hist(const int* __restrict__ dst, int* __restrict__ cnt, int nE)
{
    int i = blockIdx.x * 256 + threadIdx.x;
    if (i < nE) atomicAdd(&cnt[dst[i]], 1);
}

// 1024-thread single-block scan, 8 items/thread per 8192-tile
__global__ __launch_bounds__(1024) void k_scan(
    const int* __restrict__ cnt, int* __restrict__ off, int* __restrict__ cur, int n)
{
    __shared__ int tile[8192];
    __shared__ int wsum[16];
    const int tid = threadIdx.x, lane = tid & 63, wv = tid >> 6;
    int carry = 0;
    for (int base = 0; base < n; base += 8192) {
        for (int i = tid; i < 8192; i += 1024) tile[i] = cnt[base + i];
        __syncthreads();
        const int st = tid * 8;
        int s = 0;
        for (int k = 0; k < 8; ++k) { int v = tile[st + k]; tile[st + k] = s; s += v; }
        const int tsum = s;
        int incl = s;
        for (int o = 1; o < 64; o <<= 1) {
            int v = __shfl_up(incl, o);
            if (lane >= o) incl += v;
        }
        if (lane == 63) wsum[wv] = incl;
        __syncthreads();
        int woff = 0;
        for (int wq = 0; wq < wv; ++wq) woff += wsum[wq];
        int tot = 0;
        for (int wq = 0; wq < 16; ++wq) tot += wsum[wq];
        const int add = carry + woff + incl - tsum;
        for (int k = 0; k < 8; ++k) {
            int o2 = add + tile[st + k];
            off[base + st + k] = o2;
            cur[base + st + k] = o2;
        }
        carry += tot;
        __syncthreads();
    }
    if (tid == 0) off[n] = carry;
}

// layer-1 scatter: payload = src node; also inverse map pos1[e] for alpha write
__global__ void k_scatter1(const int* __restrict__ adj, int* __restrict__ cur,
                           int* __restrict__ srcc, int* __restrict__ pos1, int nE)
{
    int i = blockIdx.x * 256 + threadIdx.x;
    if (i < nE) {
        int pos = atomicAdd(&cur[adj[nE + i]], 1);
        srcc[pos] = adj[i];
        pos1[i] = pos;
    }
}

// layer-2 scatter: payload = {src line-edge, node-feature idx}
__global__ void k_scatter2(const int* __restrict__ eadj, const int* __restrict__ efea,
                           int* __restrict__ cur, int2* __restrict__ sf2, int nE)
{
    int i = blockIdx.x * 256 + threadIdx.x;
    if (i < nE) {
        int pos = atomicAdd(&cur[eadj[nE + i]], 1);
        sf2[pos] = make_int2(eadj[i], efea[i]);
    }
}

// ---------------------------------------------------------------------------
// K1 (MFMA): xl_n/xr_n = concat(x_node,x_log) @ {Wl,Wr} + bias -> bf16 [N,256]
__global__ __launch_bounds__(256) void k_node_gemm(
    const float* __restrict__ x_node, const float* __restrict__ x_log,
    const u16* __restrict__ Wlt, const float* __restrict__ bl,
    const u16* __restrict__ Wrt, const float* __restrict__ br,
    u16* __restrict__ xl, u16* __restrict__ xr)
{
    __shared__ u16 A[32][260];
    const int n0 = blockIdx.x * 32;
    const int tid = threadIdx.x;
    for (int i = tid; i < 32 * 64; i += 256) {
        const int r = i >> 6, k4 = (i & 63) << 2;
        const float* srcp = (k4 < 128) ? &x_node[(size_t)(n0 + r) * 128 + k4]
                                       : &x_log [(size_t)(n0 + r) * 128 + (k4 - 128)];
        const float4 v = *(const float4*)srcp;
        ushort4 o; o.x = f2bs(v.x); o.y = f2bs(v.y); o.z = f2bs(v.z); o.w = f2bs(v.w);
        *(ushort4*)&A[r][k4] = o;
    }
    __syncthreads();
    const int w = tid >> 6, lane = tid & 63, lr = lane & 15, lq = lane >> 4;
    const u16* Wt     = (w < 2) ? Wlt : Wrt;
    const float* bias = (w < 2) ? bl : br;
    u16* outp         = (w < 2) ? xl : xr;
    const int cb = (w & 1) * 128;
    f32x4 acc[2][8] = {};
    for (int kb = 0; kb < 8; ++kb) {
        s16x8 afr0 = *(const s16x8*)&A[lr][kb * 32 + lq * 8];
        s16x8 afr1 = *(const s16x8*)&A[16 + lr][kb * 32 + lq * 8];
#pragma unroll
        for (int ct = 0; ct < 8; ++ct) {
            const int n = cb + ct * 16 + lr;
            s16x8 bfr = *(const s16x8*)&Wt[(size_t)n * 256 + kb * 32 + lq * 8];
            acc[0][ct] = __builtin_amdgcn_mfma_f32_16x16x32_bf16(afr0, bfr, acc[0][ct], 0, 0, 0);
            acc[1][ct] = __builtin_amdgcn_mfma_f32_16x16x32_bf16(afr1, bfr, acc[1][ct], 0, 0, 0);
        }
    }
#pragma unroll
    for (int rt = 0; rt < 2; ++rt)
#pragma unroll
        for (int ct = 0; ct < 8; ++ct) {
            const int col = cb + ct * 16 + lr;
            const float bv = bias[col];
#pragma unroll
            for (int reg = 0; reg < 4; ++reg) {
                const int row = n0 + rt * 16 + lq * 4 + reg;
                outp[(size_t)row * 256 + col] = f2bs(acc[rt][ct][reg] + bv);
            }
        }
}

// ---------------------------------------------------------------------------
// K3 (MFMA, fused, wave-specialized, MULTI-TILE): 512 threads, 8 tiles of
// 32 edges per block. Weight fragments loaded ONCE into registers (64 VGPR),
// reused across all tiles. LDS double-buffered; one barrier per tile; stage
// of tile t+1 issued before compute of tile t (HBM latency hides under MFMA).
//   waves 0-3 (role 0): layer-1 logits (early gathers + Wet MFMA + reduce)
//   waves 4-7 (role 1): layer-2 GEMMs (Wl2 -> xl_e, Wr2 -> xrst staging)
constexpr int TPB_EDGE = 8;    // tiles per block
__global__ __launch_bounds__(512) void k_edge_mm(
    const float* __restrict__ x_trace,
    const int* __restrict__ adj,          // [2,E] src then dst
    const int* __restrict__ pos1,
    const u16* __restrict__ xl_n, const u16* __restrict__ xr_n,  // [N,256] bf16
    const u16* __restrict__ Wet,                                  // [256][128] perm
    const u16* __restrict__ Wl2t, const float* __restrict__ bl2,  // [128][128] perm
    const u16* __restrict__ Wr2t, const float* __restrict__ br2,
    const float* __restrict__ att,
    float* __restrict__ alpha, u16* __restrict__ xl_e, u16* __restrict__ xrst)
{
    __shared__ u16 A[2][32][132];
    __shared__ int ss[2][32], dd[2][32], pp[2][32];
    const int tid = threadIdx.x;
    const int w8 = tid >> 6;           // 0..7
    const int role = w8 >> 2;          // 0: logits, 1: layer-2 GEMM
    const int w = w8 & 3;
    const int lane = tid & 63, lr = lane & 15, lq = lane >> 4;

    // ---- resident weight fragments: 16 x s16x8 = 64 VGPR, loaded once
    s16x8 wf[4][4];
    const int cb2 = (w & 1) * 64;
    if (role == 0) {
#pragma unroll
        for (int kb = 0; kb < 4; ++kb)
#pragma unroll
            for (int ct = 0; ct < 4; ++ct)
                wf[kb][ct] = *(const s16x8*)&Wet[(size_t)(w * 64 + ct * 16 + lr) * 128 + kb * 32 + lq * 8];
    } else {
        const u16* Wt2 = (w < 2) ? Wl2t : Wr2t;
#pragma unroll
        for (int kb = 0; kb < 4; ++kb)
#pragma unroll
            for (int ct = 0; ct < 4; ++ct)
                wf[kb][ct] = *(const s16x8*)&Wt2[(size_t)(cb2 + ct * 16 + lr) * 128 + kb * 32 + lq * 8];
    }
    const float4 attq = *(const float4*)&att[w * 64 + lr * 4];
    const float4 b2q  = (role == 0) ? make_float4(0, 0, 0, 0)
        : *(const float4*)&((w < 2) ? bl2 : br2)[cb2 + lr * 4];

    const int tile0 = blockIdx.x * TPB_EDGE;
    // prologue: stage tile0 into buffer 0
    {
        const int e0s = tile0 * 32;
        const int i0 = tid, i1 = tid + 512;
        {
            const int r = i0 >> 5, k4 = (i0 & 31) << 2;
            const float4 v = *(const float4*)&x_trace[(size_t)(e0s + r) * 128 + k4];
            ushort4 o; o.x = f2bs(v.x); o.y = f2bs(v.y); o.z = f2bs(v.z); o.w = f2bs(v.w);
            *(ushort4*)&A[0][r][k4] = o;
        }
        {
            const int r = i1 >> 5, k4 = (i1 & 31) << 2;
            const float4 v = *(const float4*)&x_trace[(size_t)(e0s + r) * 128 + k4];
            ushort4 o; o.x = f2bs(v.x); o.y = f2bs(v.y); o.z = f2bs(v.z); o.w = f2bs(v.w);
            *(ushort4*)&A[0][r][k4] = o;
        }
        if (tid < 32) {
            ss[0][tid] = adj[e0s + tid];
            dd[0][tid] = adj[E + e0s + tid];
            pp[0][tid] = pos1[e0s + tid];
        }
    }

    for (int t = 0; t < TPB_EDGE; ++t) {
        __syncthreads();                       // buf b ready; buf b^1 free
        const int b = t & 1;
        const int e0 = (tile0 + t) * 32;
        // ---- issue stage of tile t+1 into the other buffer (overlaps compute)
        if (t + 1 < TPB_EDGE) {
            const int e0s = (tile0 + t + 1) * 32;
            const int bn = b ^ 1;
            {
                const int r = tid >> 5, k4 = (tid & 31) << 2;
                const float4 v = *(const float4*)&x_trace[(size_t)(e0s + r) * 128 + k4];
                ushort4 o; o.x = f2bs(v.x); o.y = f2bs(v.y); o.z = f2bs(v.z); o.w = f2bs(v.w);
                *(ushort4*)&A[bn][r][k4] = o;
            }
            {
                const int i1 = tid + 512;
                const int r = i1 >> 5, k4 = (i1 & 31) << 2;
                const float4 v = *(const float4*)&x_trace[(size_t)(e0s + r) * 128 + k4];
                ushort4 o; o.x = f2bs(v.x); o.y = f2bs(v.y); o.z = f2bs(v.z); o.w = f2bs(v.w);
                *(ushort4*)&A[bn][r][k4] = o;
            }
            if (tid < 32) {
                ss[bn][tid] = adj[e0s + tid];
                dd[bn][tid] = adj[E + e0s + tid];
                pp[bn][tid] = pos1[e0s + tid];
            }
        }

        if (role == 0) {
            // ---- EARLY gathers (xl_n/xr_n) for this tile
            const int co = w * 64 + lr * 4;
            ushort4 xlv[2][4], xrv[2][4];
#pragma unroll
            for (int rt = 0; rt < 2; ++rt)
#pragma unroll
                for (int reg = 0; reg < 4; ++reg) {
                    const int rowt = rt * 16 + lq * 4 + reg;
                    xlv[rt][reg] = *(const ushort4*)&xl_n[(size_t)ss[b][rowt] * 256 + co];
                    xrv[rt][reg] = *(const ushort4*)&xr_n[(size_t)dd[b][rowt] * 256 + co];
                }
            // ---- acc1 MFMA with resident Wet fragments
            f32x4 acc1[2][4] = {};
#pragma unroll
            for (int kb = 0; kb < 4; ++kb) {
                s16x8 afr0 = *(const s16x8*)&A[b][lr][kb * 32 + lq * 8];
                s16x8 afr1 = *(const s16x8*)&A[b][16 + lr][kb * 32 + lq * 8];
#pragma unroll
                for (int ct = 0; ct < 4; ++ct) {
                    acc1[0][ct] = __builtin_amdgcn_mfma_f32_16x16x32_bf16(afr0, wf[kb][ct], acc1[0][ct], 0, 0, 0);
                    acc1[1][ct] = __builtin_amdgcn_mfma_f32_16x16x32_bf16(afr1, wf[kb][ct], acc1[1][ct], 0, 0, 0);
                }
            }
            // ---- logits: combine, leaky, dot(att), 16-lane reduce
            float sums[2][4];
#pragma unroll
            for (int rt = 0; rt < 2; ++rt)
#pragma unroll
                for (int reg = 0; reg < 4; ++reg) {
                    float m0 = acc1[rt][0][reg] + bs2f(xlv[rt][reg].x) + bs2f(xrv[rt][reg].x);
                    float m1 = acc1[rt][1][reg] + bs2f(xlv[rt][reg].y) + bs2f(xrv[rt][reg].y);
                    float m2 = acc1[rt][2][reg] + bs2f(xlv[rt][reg].z) + bs2f(xrv[rt][reg].z);
                    float m3 = acc1[rt][3][reg] + bs2f(xlv[rt][reg].w) + bs2f(xrv[rt][reg].w);
                    m0 = m0 > 0.f ? m0 : 0.2f * m0;
                    m1 = m1 > 0.f ? m1 : 0.2f * m1;
                    m2 = m2 > 0.f ? m2 : 0.2f * m2;
                    m3 = m3 > 0.f ? m3 : 0.2f * m3;
                    sums[rt][reg] = m0 * attq.x + m1 * attq.y + m2 * attq.z + m3 * attq.w;
                }
#pragma unroll
            for (int rt = 0; rt < 2; ++rt)
#pragma unroll
                for (int reg = 0; reg < 4; ++reg) {
                    float p = sums[rt][reg];
                    p += __shfl_xor(p, 8);
                    p += __shfl_xor(p, 4);
                    p += __shfl_xor(p, 2);
                    p += __shfl_xor(p, 1);
                    if (lr == 0)
                        alpha[(size_t)pp[b][rt * 16 + lq * 4 + reg] * 4 + w] = p;
                }
        } else {
            // ---- acc2 MFMA with resident Wl2/Wr2 fragments
            f32x4 acc2[2][4] = {};
#pragma unroll
            for (int kb = 0; kb < 4; ++kb) {
                s16x8 afr0 = *(const s16x8*)&A[b][lr][kb * 32 + lq * 8];
                s16x8 afr1 = *(const s16x8*)&A[b][16 + lr][kb * 32 + lq * 8];
#pragma unroll
                for (int ct = 0; ct < 4; ++ct) {
                    acc2[0][ct] = __builtin_amdgcn_mfma_f32_16x16x32_bf16(afr0, wf[kb][ct], acc2[0][ct], 0, 0, 0);
                    acc2[1][ct] = __builtin_amdgcn_mfma_f32_16x16x32_bf16(afr1, wf[kb][ct], acc2[1][ct], 0, 0, 0);
                }
            }
#pragma unroll
            for (int rt = 0; rt < 2; ++rt)
#pragma unroll
                for (int reg = 0; reg < 4; ++reg) {
                    const int row = e0 + rt * 16 + lq * 4 + reg;
                    ushort4 o;
                    o.x = f2bs(acc2[rt][0][reg] + b2q.x);
                    o.y = f2bs(acc2[rt][1][reg] + b2q.y);
                    o.z = f2bs(acc2[rt][2][reg] + b2q.z);
                    o.w = f2bs(acc2[rt][3][reg] + b2q.w);
                    if (w < 2) *(ushort4*)&xl_e[(size_t)row * 128 + cb2 + lr * 4] = o;
                    else       *(ushort4*)&xrst[(size_t)row * 256 + cb2 + lr * 4] = o;
                }
        }
    }
}

// ---------------------------------------------------------------------------
// K4: layer-1 online-softmax + gather. One node per WAVE, 4 dims/lane.
// CSR payload arrays (src_csr, alpha_csr) -> sequential loads + ONE gather level.
__global__ __launch_bounds__(256) void k_fused1(
    const int* __restrict__ off, const int* __restrict__ srcc,
    const float* __restrict__ alphac,
    const u16* __restrict__ xl,
    const float* __restrict__ bias,
    float* __restrict__ out)
{
    const int wv = __builtin_amdgcn_readfirstlane(threadIdx.x >> 6);
    const int lane = threadIdx.x & 63;
    const int n = blockIdx.x * 4 + wv;
    const int c = lane * 4;            // dims c..c+3
    const int h = lane >> 4;           // head (64 dims / head, 16 lanes / head)
    const int beg = off[n], end = off[n + 1];
    float mx = -INFINITY, den = 0.f;
    float a0 = 0.f, a1 = 0.f, a2 = 0.f, a3 = 0.f;
    int i = beg;
    while (i < end) {
        const int rem = end - i;       // >= 1, wave-uniform
        int sa[8]; float pe[8];
#pragma unroll
        for (int k = 0; k < 8; ++k) {
            const int idx = i + (k < rem ? k : rem - 1);
            sa[k] = srcc[idx];
            pe[k] = alphac[(size_t)idx * 4 + h];
        }
        ushort4 xv[8];
#pragma unroll
        for (int k = 0; k < 8; ++k)
            xv[k] = *(const ushort4*)&xl[(size_t)sa[k] * 256 + c];
#pragma unroll
        for (int k = 0; k < 8; ++k) {
            const float p = (k < rem) ? pe[k] : -INFINITY;
            const float mnew = fmaxf(mx, p);
            const float sc = __expf(mx - mnew);
            const float ex = __expf(p - mnew);
            den = den * sc + ex;
            a0 = a0 * sc + ex * bs2f(xv[k].x);
            a1 = a1 * sc + ex * bs2f(xv[k].y);
            a2 = a2 * sc + ex * bs2f(xv[k].z);
            a3 = a3 * sc + ex * bs2f(xv[k].w);
            mx = mnew;
        }
        i += 8;
    }
    const float inv = 1.f / (den + 1e-16f);
    float4 r;
    r.x = a0 * inv + bias[c + 0];
    r.y = a1 * inv + bias[c + 1];
    r.z = a2 * inv + bias[c + 2];
    r.w = a3 * inv + bias[c + 3];
    if (lane < 32) *(float4*)&out[(size_t)n * 128 + c] = r;
    else           *(float4*)&out[XLG_OFF + (size_t)n * 128 + (c - 128)] = r;
}

// ---------------------------------------------------------------------------
// K5 (MFMA): proj = node_out @ e2n_We  [N,128] bf16
__global__ __launch_bounds__(256) void k_proj_gemm(
    const float* __restrict__ out_node, const u16* __restrict__ We2t,  // [128][256]
    u16* __restrict__ proj)
{
    __shared__ u16 A[32][260];
    const int n0 = blockIdx.x * 32;
    const int tid = threadIdx.x;
    for (int i = tid; i < 32 * 64; i += 256) {
        const int r = i >> 6, k4 = (i & 63) << 2;
        const float* srcp = (k4 < 128)
            ? &out_node[(size_t)(n0 + r) * 128 + k4]
            : &out_node[XLG_OFF + (size_t)(n0 + r) * 128 + (k4 - 128)];
        const float4 v = *(const float4*)srcp;
        ushort4 o; o.x = f2bs(v.x); o.y = f2bs(v.y); o.z = f2bs(v.z); o.w = f2bs(v.w);
        *(ushort4*)&A[r][k4] = o;
    }
    __syncthreads();
    const int w = tid >> 6, lane = tid & 63, lr = lane & 15, lq = lane >> 4;
    f32x4 acc[2][2] = {};
    for (int kb = 0; kb < 8; ++kb) {
        s16x8 afr0 = *(const s16x8*)&A[lr][kb * 32 + lq * 8];
        s16x8 afr1 = *(const s16x8*)&A[16 + lr][kb * 32 + lq * 8];
#pragma unroll
        for (int ct = 0; ct < 2; ++ct) {
            const int col = w * 32 + ct * 16 + lr;
            s16x8 bfr = *(const s16x8*)&We2t[(size_t)col * 256 + kb * 32 + lq * 8];
            acc[0][ct] = __builtin_amdgcn_mfma_f32_16x16x32_bf16(afr0, bfr, acc[0][ct], 0, 0, 0);
            acc[1][ct] = __builtin_amdgcn_mfma_f32_16x16x32_bf16(afr1, bfr, acc[1][ct], 0, 0, 0);
        }
    }
#pragma unroll
    for (int rt = 0; rt < 2; ++rt)
#pragma unroll
        for (int ct = 0; ct < 2; ++ct) {
            const int col = w * 32 + ct * 16 + lr;
#pragma unroll
            for (int reg = 0; reg < 4; ++reg) {
                const int row = n0 + rt * 16 + lq * 4 + reg;
                proj[(size_t)row * 128 + col] = f2bs(acc[rt][ct][reg]);
            }
        }
}

// ---------------------------------------------------------------------------
// K6: layer-2 fused logits + online softmax + aggregate. One row per WAVE,
// 2 dims/lane. CSR payload int2 {s, nf} -> sequential load + ONE gather level.
__global__ __launch_bounds__(256) void k_fused2(
    const int* __restrict__ off, const int2* __restrict__ sf2,
    const u16* __restrict__ xl,        // [E,128] trace@Wl2+bl2 bf16
    const u16* __restrict__ proj,      // [N,128] bf16
    const float* __restrict__ att,
    const float* __restrict__ bias,
    float* __restrict__ out)
{
    const int wv = __builtin_amdgcn_readfirstlane(threadIdx.x >> 6);
    const int lane = threadIdx.x & 63;
    const int d = blockIdx.x * 4 + wv;
    const int c = lane * 2;            // dims c, c+1 (head = lane>>4, 16 lanes/head)
    const u16* xrst = (const u16*)(out + XT_OFF);
    const unsigned xrp = *(const unsigned*)&xrst[(size_t)d * 256 + c];
    const float xr0 = bs2f((u16)(xrp & 0xffff));
    const float xr1 = bs2f((u16)(xrp >> 16));
    const float av0 = att[c], av1 = att[c + 1];
    const int beg = off[d], end = off[d + 1];
    float mx = -INFINITY, den = 0.f, a0 = 0.f, a1 = 0.f;
    int i = beg;
    while (i < end) {
        const int rem = end - i;       // >= 1, wave-uniform
        int2 sf[4];
#pragma unroll
        for (int k = 0; k < 4; ++k) sf[k] = sf2[i + (k < rem ? k : rem - 1)];
        unsigned xv[4], pv[4];
#pragma unroll
        for (int k = 0; k < 4; ++k) {
            xv[k] = *(const unsigned*)&xl[(size_t)sf[k].x * 128 + c];
            pv[k] = *(const unsigned*)&proj[(size_t)sf[k].y * 128 + c];
        }
#pragma unroll
        for (int k = 0; k < 4; ++k) {
            const float x0 = bs2f((u16)(xv[k] & 0xffff));
            const float x1 = bs2f((u16)(xv[k] >> 16));
            float m0 = x0 + xr0 + bs2f((u16)(pv[k] & 0xffff));
            float m1 = x1 + xr1 + bs2f((u16)(pv[k] >> 16));
            m0 = m0 > 0.f ? m0 : 0.2f * m0;
            m1 = m1 > 0.f ? m1 : 0.2f * m1;
            float pp = m0 * av0 + m1 * av1;
            pp += __shfl_xor(pp, 8, 16);
            pp += __shfl_xor(pp, 4, 16);
            pp += __shfl_xor(pp, 2, 16);
            pp += __shfl_xor(pp, 1, 16);
            const float p = (k < rem) ? pp : -INFINITY;
            const float mnew = fmaxf(mx, p);
            const float sc = __expf(mx - mnew);
            const float ex = __expf(p - mnew);
            den = den * sc + ex;
            a0 = a0 * sc + ex * x0;
            a1 = a1 * sc + ex * x1;
            mx = mnew;
        }
        i += 4;
    }
    const float inv = 1.f / (den + 1e-16f);
    float2 o2;
    o2.x = a0 * inv + bias[c];
    o2.y = a1 * inv + bias[c + 1];
    *(float2*)&out[XT_OFF + (size_t)d * 128 + c] = o2;
}

// ---------------------------------------------------------------------------
extern "C" void kernel_launch(void* const* d_in, const int* in_sizes, int n_in,
                              void* d_out, int out_size, void* d_ws, size_t ws_size,
                              hipStream_t stream)
{
    const float* x_node   = (const float*)d_in[0];
    const float* x_trace  = (const float*)d_in[1];
    const float* x_log    = (const float*)d_in[2];
    const int*   node_adj = (const int*)d_in[3];
    const int*   edge_adj = (const int*)d_in[4];
    const int*   efea     = (const int*)d_in[5];
    const float* n2n_Wl   = (const float*)d_in[6];
    const float* n2n_bl   = (const float*)d_in[7];
    const float* n2n_Wr   = (const float*)d_in[8];
    const float* n2n_br   = (const float*)d_in[9];
    const float* n2n_We   = (const float*)d_in[10];
    const float* n2n_att  = (const float*)d_in[11];
    const float* n2n_bias = (const float*)d_in[12];
    const float* e2n_Wl   = (const float*)d_in[13];
    const float* e2n_bl   = (const float*)d_in[14];
    const float* e2n_Wr   = (const float*)d_in[15];
    const float* e2n_br   = (const float*)d_in[16];
    const float* e2n_We   = (const float*)d_in[17];
    const float* e2n_att  = (const float*)d_in[18];
    const float* e2n_bias = (const float*)d_in[19];
    float* out = (float*)d_out;

    // ---- workspace layout (~51 MB) ----
    char* w = (char*)d_ws;
    int*  cnt1   = (int*)w;   w += (size_t)N * 4;        // zeroed below
    int*  cnt2   = (int*)w;   w += (size_t)E * 4;        // zeroed below
    int*  off1   = (int*)w;   w += (size_t)(N + 4) * 4;
    int*  cur1   = (int*)w;   w += (size_t)N * 4;
    int*  src1   = (int*)w;   w += (size_t)E * 4;        // CSR payload: src node
    int*  pos1   = (int*)w;   w += (size_t)E * 4;        // edge -> CSR pos
    float* alphac = (float*)w; w += (size_t)E * 4 * 4;   // CSR-ordered alpha [E][4]
    int*  off2   = (int*)w;   w += (size_t)(E + 4) * 4;
    int*  cur2   = (int*)w;   w += (size_t)E * 4;
    int2* sf2    = (int2*)w;  w += (size_t)E2 * 8;       // CSR payload: {s, nf}
    u16*  xl_n   = (u16*)w;   w += (size_t)N * 256 * 2;
    u16*  xr_n   = (u16*)w;   w += (size_t)N * 256 * 2;
    u16*  xl_e   = (u16*)w;   w += (size_t)E * 128 * 2;
    u16*  proj   = (u16*)w;   w += (size_t)N * 128 * 2;
    u16*  Wlt    = (u16*)w;   w += (size_t)65536 * 2;
    u16*  Wrt    = (u16*)w;   w += (size_t)65536 * 2;
    u16*  Wet    = (u16*)w;   w += (size_t)32768 * 2;
    u16*  Wl2t   = (u16*)w;   w += (size_t)16384 * 2;
    u16*  Wr2t   = (u16*)w;   w += (size_t)16384 * 2;
    u16*  We2t   = (u16*)w;   w += (size_t)32768 * 2;

    hipMemsetAsync(d_ws, 0, (size_t)(N + E) * 4, stream);

    // ---- prep + CSR builds ----
    k_prep<<<896, 256, 0, stream>>>(n2n_Wl, n2n_Wr, n2n_We, e2n_Wl, e2n_Wr, e2n_We,
                                    Wlt, Wrt, Wet, Wl2t, Wr2t, We2t);
    k_hist<<<E / 256, 256, 0, stream>>>(node_adj + E, cnt1, E);
    k_scan<<<1, 1024, 0, stream>>>(cnt1, off1, cur1, N);
    k_scatter1<<<E / 256, 256, 0, stream>>>(node_adj, cur1, src1, pos1, E);
    k_hist<<<E2 / 256, 256, 0, stream>>>(edge_adj + E2, cnt2, E2);
    k_scan<<<1, 1024, 0, stream>>>(cnt2, off2, cur2, E);
    k_scatter2<<<E2 / 256, 256, 0, stream>>>(edge_adj, efea, cur2, sf2, E2);

    // ---- layer 1 (+ layer-2 trace GEMMs fused into k_edge_mm) ----
    k_node_gemm<<<N / 32, 256, 0, stream>>>(x_node, x_log, Wlt, n2n_bl, Wrt, n2n_br,
                                            xl_n, xr_n);
    k_edge_mm<<<E / (32 * TPB_EDGE), 512, 0, stream>>>(x_trace, node_adj, pos1, xl_n, xr_n,
                                          Wet, Wl2t, e2n_bl, Wr2t, e2n_br,
                                          n2n_att, alphac, xl_e, (u16*)(out + XT_OFF));
    k_fused1<<<N / 4, 256, 0, stream>>>(off1, src1, alphac, xl_n, n2n_bias, out);

    // ---- layer 2 ----
    k_proj_gemm<<<N / 32, 256, 0, stream>>>(out, We2t, proj);
    k_fused2<<<E / 4, 256, 0, stream>>>(off2, sf2, xl_e, proj,
                                        e2n_att, e2n_bias, out);
}

// Round 9
// 400.391 us; speedup vs baseline: 1.4263x; 1.0678x over previous
//
#include <hip/hip_runtime.h>
#include <hip/hip_bf16.h>

// Problem constants (match reference)
constexpr int N    = 8192;     // nodes
constexpr int E    = 131072;   // node-graph edges == trace rows
constexpr int E2   = 524288;   // line-graph edges

constexpr size_t XT_OFF  = (size_t)N * 128;
constexpr size_t XLG_OFF = XT_OFF + (size_t)E * 128;

typedef unsigned short u16;
typedef short s16x8 __attribute__((ext_vector_type(8)));
typedef float f32x4 __attribute__((ext_vector_type(4)));

__device__ __forceinline__ u16 f2bs(float f) {   // f32 -> bf16 bits, RNE
    unsigned x = __float_as_uint(f);
    return (u16)((x + 0x7FFF + ((x >> 16) & 1)) >> 16);
}
__device__ __forceinline__ float bs2f(u16 u) {
    return __uint_as_float((unsigned)u << 16);
}

// ---------------------------------------------------------------------------
// K0: weight pre-transpose f32 [K,Ncol] -> bf16 [Ncol,K] (one launch, all 6).
// Wet/Wl2t/Wr2t rows are PERMUTED within each 64-col window so that the MFMA
// output position (ct*16+lr) computes original col (lr*4+ct): lane lr then
// owns 4 CONTIGUOUS cols -> ushort4 gathers/stores in k_edge_mm.
__global__ __launch_bounds__(256) void k_prep(
    const float* __restrict__ Wl, const float* __restrict__ Wr,
    const float* __restrict__ We, const float* __restrict__ Wl2,
    const float* __restrict__ Wr2, const float* __restrict__ We2,
    u16* __restrict__ Wlt, u16* __restrict__ Wrt, u16* __restrict__ Wet,
    u16* __restrict__ Wl2t, u16* __restrict__ Wr2t, u16* __restrict__ We2t)
{
    const int gid = blockIdx.x * 256 + threadIdx.x;
    const float* src; u16* dst; int base, Kk, sh, perm;
    if      (gid <  65536) { src = Wl;  dst = Wlt;  base = 0;      Kk = 256; sh = 8; perm = 0; }
    else if (gid < 131072) { src = Wr;  dst = Wrt;  base = 65536;  Kk = 256; sh = 8; perm = 0; }
    else if (gid < 163840) { src = We;  dst = Wet;  base = 131072; Kk = 128; sh = 8; perm = 1; }
    else if (gid < 180224) { src = Wl2; dst = Wl2t; base = 163840; Kk = 128; sh = 7; perm = 1; }
    else if (gid < 196608) { src = Wr2; dst = Wr2t; base = 180224; Kk = 128; sh = 7; perm = 1; }
    else                   { src = We2; dst = We2t; base = 196608; Kk = 256; sh = 7; perm = 0; }
    const int l = gid - base;
    const int k = l >> sh, nn = l & ((1 << sh) - 1);
    int ns = nn;
    if (perm) ns = (nn & ~63) | ((nn & 3) << 4) | ((nn >> 2) & 15);
    dst[(size_t)ns * Kk + k] = f2bs(src[l]);
}

// ---------------------------------------------------------------------------
// CSR build: merged histogram -> multi-block 2-phase scan -> merged scatter
__global__ void k_hist2(const int* __restrict__ d1, const int* __restrict__ d2,
                        int* __restrict__ c1, int* __restrict__ c2)
{
    int i = blockIdx.x * 256 + threadIdx.x;
    if (i < E) atomicAdd(&c1[d1[i]], 1);
    else { int j = i - E; atomicAdd(&c2[d2[j]], 1); }
}

// phase 1: per-tile (8192 elems) exclusive scan, tile total -> tsums[b]
__global__ __launch_bounds__(1024) void k_scan_part(
    const int* __restrict__ cnt, int* __restrict__ off, int* __restrict__ tsums)
{
    __shared__ int tile[8192];
    __shared__ int wsum[16];
    const int tid = threadIdx.x, lane = tid & 63, wv = tid >> 6;
    const int base = blockIdx.x * 8192;
    for (int i = tid; i < 8192; i += 1024) tile[i] = cnt[base + i];
    __syncthreads();
    const int st = tid * 8;
    int s = 0;
    for (int k = 0; k < 8; ++k) { int v = tile[st + k]; tile[st + k] = s; s += v; }
    const int tsum = s;
    int incl = s;
    for (int o = 1; o < 64; o <<= 1) {
        int v = __shfl_up(incl, o);
        if (lane >= o) incl += v;
    }
    if (lane == 63) wsum[wv] = incl;
    __syncthreads();
    int woff = 0;
    for (int wq = 0; wq < wv; ++wq) woff += wsum[wq];
    const int add = woff + incl - tsum;
    for (int k = 0; k < 8; ++k) off[base + st + k] = add + tile[st + k];
    if (tid == 1023) tsums[blockIdx.x] = woff + incl;   // tile total
}

// phase 2: add tile-prefix carry; write cur; last block writes off[n]
__global__ __launch_bounds__(1024) void k_scan_add(
    int* __restrict__ off, int* __restrict__ cur,
    const int* __restrict__ tsums, int ntiles, int n)
{
    const int b = blockIdx.x;
    int carry = 0;
    for (int t = 0; t < b; ++t) carry += tsums[t];
    const int base = b * 8192 + threadIdx.x * 8;
#pragma unroll
    for (int k = 0; k < 8; ++k) {
        int v = off[base + k] + carry;
        off[base + k] = v;
        cur[base + k] = v;
    }
    if (b == ntiles - 1 && threadIdx.x == 1023)
        off[n] = carry + tsums[b];
}

// merged scatter: layer-1 (payload src + inverse map) and layer-2 ({s, nf})
__global__ void k_scatterM(
    const int* __restrict__ adj, int* __restrict__ cur1,
    int* __restrict__ srcc, int* __restrict__ pos1,
    const int* __restrict__ eadj, const int* __restrict__ efea,
    int* __restrict__ cur2, int2* __restrict__ sf2)
{
    int i = blockIdx.x * 256 + threadIdx.x;
    if (i < E) {
        int pos = atomicAdd(&cur1[adj[E + i]], 1);
        srcc[pos] = adj[i];
        pos1[i] = pos;
    } else {
        int j = i - E;
        int pos = atomicAdd(&cur2[eadj[E2 + j]], 1);
        sf2[pos] = make_int2(eadj[j], efea[j]);
    }
}

// ---------------------------------------------------------------------------
// K1 (MFMA): xl_n/xr_n = concat(x_node,x_log) @ {Wl,Wr} + bias -> bf16 [N,256]
__global__ __launch_bounds__(256) void k_node_gemm(
    const float* __restrict__ x_node, const float* __restrict__ x_log,
    const u16* __restrict__ Wlt, const float* __restrict__ bl,
    const u16* __restrict__ Wrt, const float* __restrict__ br,
    u16* __restrict__ xl, u16* __restrict__ xr)
{
    __shared__ u16 A[32][260];
    const int n0 = blockIdx.x * 32;
    const int tid = threadIdx.x;
    for (int i = tid; i < 32 * 64; i += 256) {
        const int r = i >> 6, k4 = (i & 63) << 2;
        const float* srcp = (k4 < 128) ? &x_node[(size_t)(n0 + r) * 128 + k4]
                                       : &x_log [(size_t)(n0 + r) * 128 + (k4 - 128)];
        const float4 v = *(const float4*)srcp;
        ushort4 o; o.x = f2bs(v.x); o.y = f2bs(v.y); o.z = f2bs(v.z); o.w = f2bs(v.w);
        *(ushort4*)&A[r][k4] = o;
    }
    __syncthreads();
    const int w = tid >> 6, lane = tid & 63, lr = lane & 15, lq = lane >> 4;
    const u16* Wt     = (w < 2) ? Wlt : Wrt;
    const float* bias = (w < 2) ? bl : br;
    u16* outp         = (w < 2) ? xl : xr;
    const int cb = (w & 1) * 128;
    f32x4 acc[2][8] = {};
    for (int kb = 0; kb < 8; ++kb) {
        s16x8 afr0 = *(const s16x8*)&A[lr][kb * 32 + lq * 8];
        s16x8 afr1 = *(const s16x8*)&A[16 + lr][kb * 32 + lq * 8];
#pragma unroll
        for (int ct = 0; ct < 8; ++ct) {
            const int n = cb + ct * 16 + lr;
            s16x8 bfr = *(const s16x8*)&Wt[(size_t)n * 256 + kb * 32 + lq * 8];
            acc[0][ct] = __builtin_amdgcn_mfma_f32_16x16x32_bf16(afr0, bfr, acc[0][ct], 0, 0, 0);
            acc[1][ct] = __builtin_amdgcn_mfma_f32_16x16x32_bf16(afr1, bfr, acc[1][ct], 0, 0, 0);
        }
    }
#pragma unroll
    for (int rt = 0; rt < 2; ++rt)
#pragma unroll
        for (int ct = 0; ct < 8; ++ct) {
            const int col = cb + ct * 16 + lr;
            const float bv = bias[col];
#pragma unroll
            for (int reg = 0; reg < 4; ++reg) {
                const int row = n0 + rt * 16 + lq * 4 + reg;
                outp[(size_t)row * 256 + col] = f2bs(acc[rt][ct][reg] + bv);
            }
        }
}

// ---------------------------------------------------------------------------
// K3 (MFMA, fused, wave-specialized, MULTI-TILE): 512 threads, TPB_EDGE tiles
// of 32 edges per block. Weight fragments resident in registers; LDS
// double-buffered; one barrier per tile.
//   waves 0-3 (role 0): layer-1 logits (early gathers + Wet MFMA + reduce)
//   waves 4-7 (role 1): layer-2 GEMMs (Wl2 -> xl_e, Wr2 -> xrst staging)
constexpr int TPB_EDGE = 4;    // tiles per block (grid = 1024 -> 4 blocks/CU)
__global__ __launch_bounds__(512) void k_edge_mm(
    const float* __restrict__ x_trace,
    const int* __restrict__ adj,          // [2,E] src then dst
    const int* __restrict__ pos1,
    const u16* __restrict__ xl_n, const u16* __restrict__ xr_n,  // [N,256] bf16
    const u16* __restrict__ Wet,                                  // [256][128] perm
    const u16* __restrict__ Wl2t, const float* __restrict__ bl2,  // [128][128] perm
    const u16* __restrict__ Wr2t, const float* __restrict__ br2,
    const float* __restrict__ att,
    float* __restrict__ alpha, u16* __restrict__ xl_e, u16* __restrict__ xrst)
{
    __shared__ u16 A[2][32][132];
    __shared__ int ss[2][32], dd[2][32], pp[2][32];
    const int tid = threadIdx.x;
    const int w8 = tid >> 6;           // 0..7
    const int role = w8 >> 2;          // 0: logits, 1: layer-2 GEMM
    const int w = w8 & 3;
    const int lane = tid & 63, lr = lane & 15, lq = lane >> 4;

    // ---- resident weight fragments: 16 x s16x8 = 64 VGPR, loaded once
    s16x8 wf[4][4];
    const int cb2 = (w & 1) * 64;
    if (role == 0) {
#pragma unroll
        for (int kb = 0; kb < 4; ++kb)
#pragma unroll
            for (int ct = 0; ct < 4; ++ct)
                wf[kb][ct] = *(const s16x8*)&Wet[(size_t)(w * 64 + ct * 16 + lr) * 128 + kb * 32 + lq * 8];
    } else {
        const u16* Wt2 = (w < 2) ? Wl2t : Wr2t;
#pragma unroll
        for (int kb = 0; kb < 4; ++kb)
#pragma unroll
            for (int ct = 0; ct < 4; ++ct)
                wf[kb][ct] = *(const s16x8*)&Wt2[(size_t)(cb2 + ct * 16 + lr) * 128 + kb * 32 + lq * 8];
    }
    const float4 attq = *(const float4*)&att[w * 64 + lr * 4];
    const float4 b2q  = (role == 0) ? make_float4(0, 0, 0, 0)
        : *(const float4*)&((w < 2) ? bl2 : br2)[cb2 + lr * 4];

    const int tile0 = blockIdx.x * TPB_EDGE;
    // prologue: stage tile0 into buffer 0
    {
        const int e0s = tile0 * 32;
        const int i0 = tid, i1 = tid + 512;
        {
            const int r = i0 >> 5, k4 = (i0 & 31) << 2;
            const float4 v = *(const float4*)&x_trace[(size_t)(e0s + r) * 128 + k4];
            ushort4 o; o.x = f2bs(v.x); o.y = f2bs(v.y); o.z = f2bs(v.z); o.w = f2bs(v.w);
            *(ushort4*)&A[0][r][k4] = o;
        }
        {
            const int r = i1 >> 5, k4 = (i1 & 31) << 2;
            const float4 v = *(const float4*)&x_trace[(size_t)(e0s + r) * 128 + k4];
            ushort4 o; o.x = f2bs(v.x); o.y = f2bs(v.y); o.z = f2bs(v.z); o.w = f2bs(v.w);
            *(ushort4*)&A[0][r][k4] = o;
        }
        if (tid < 32) {
            ss[0][tid] = adj[e0s + tid];
            dd[0][tid] = adj[E + e0s + tid];
            pp[0][tid] = pos1[e0s + tid];
        }
    }

    for (int t = 0; t < TPB_EDGE; ++t) {
        __syncthreads();                       // buf b ready; buf b^1 free
        const int b = t & 1;
        const int e0 = (tile0 + t) * 32;
        // ---- issue stage of tile t+1 into the other buffer (overlaps compute)
        if (t + 1 < TPB_EDGE) {
            const int e0s = (tile0 + t + 1) * 32;
            const int bn = b ^ 1;
            {
                const int r = tid >> 5, k4 = (tid & 31) << 2;
                const float4 v = *(const float4*)&x_trace[(size_t)(e0s + r) * 128 + k4];
                ushort4 o; o.x = f2bs(v.x); o.y = f2bs(v.y); o.z = f2bs(v.z); o.w = f2bs(v.w);
                *(ushort4*)&A[bn][r][k4] = o;
            }
            {
                const int i1 = tid + 512;
                const int r = i1 >> 5, k4 = (i1 & 31) << 2;
                const float4 v = *(const float4*)&x_trace[(size_t)(e0s + r) * 128 + k4];
                ushort4 o; o.x = f2bs(v.x); o.y = f2bs(v.y); o.z = f2bs(v.z); o.w = f2bs(v.w);
                *(ushort4*)&A[bn][r][k4] = o;
            }
            if (tid < 32) {
                ss[bn][tid] = adj[e0s + tid];
                dd[bn][tid] = adj[E + e0s + tid];
                pp[bn][tid] = pos1[e0s + tid];
            }
        }

        if (role == 0) {
            // ---- EARLY gathers (xl_n/xr_n) for this tile
            const int co = w * 64 + lr * 4;
            ushort4 xlv[2][4], xrv[2][4];
#pragma unroll
            for (int rt = 0; rt < 2; ++rt)
#pragma unroll
                for (int reg = 0; reg < 4; ++reg) {
                    const int rowt = rt * 16 + lq * 4 + reg;
                    xlv[rt][reg] = *(const ushort4*)&xl_n[(size_t)ss[b][rowt] * 256 + co];
                    xrv[rt][reg] = *(const ushort4*)&xr_n[(size_t)dd[b][rowt] * 256 + co];
                }
            // ---- acc1 MFMA with resident Wet fragments
            f32x4 acc1[2][4] = {};
#pragma unroll
            for (int kb = 0; kb < 4; ++kb) {
                s16x8 afr0 = *(const s16x8*)&A[b][lr][kb * 32 + lq * 8];
                s16x8 afr1 = *(const s16x8*)&A[b][16 + lr][kb * 32 + lq * 8];
#pragma unroll
                for (int ct = 0; ct < 4; ++ct) {
                    acc1[0][ct] = __builtin_amdgcn_mfma_f32_16x16x32_bf16(afr0, wf[kb][ct], acc1[0][ct], 0, 0, 0);
                    acc1[1][ct] = __builtin_amdgcn_mfma_f32_16x16x32_bf16(afr1, wf[kb][ct], acc1[1][ct], 0, 0, 0);
                }
            }
            // ---- logits: combine, leaky, dot(att), 16-lane reduce
            float sums[2][4];
#pragma unroll
            for (int rt = 0; rt < 2; ++rt)
#pragma unroll
                for (int reg = 0; reg < 4; ++reg) {
                    float m0 = acc1[rt][0][reg] + bs2f(xlv[rt][reg].x) + bs2f(xrv[rt][reg].x);
                    float m1 = acc1[rt][1][reg] + bs2f(xlv[rt][reg].y) + bs2f(xrv[rt][reg].y);
                    float m2 = acc1[rt][2][reg] + bs2f(xlv[rt][reg].z) + bs2f(xrv[rt][reg].z);
                    float m3 = acc1[rt][3][reg] + bs2f(xlv[rt][reg].w) + bs2f(xrv[rt][reg].w);
                    m0 = m0 > 0.f ? m0 : 0.2f * m0;
                    m1 = m1 > 0.f ? m1 : 0.2f * m1;
                    m2 = m2 > 0.f ? m2 : 0.2f * m2;
                    m3 = m3 > 0.f ? m3 : 0.2f * m3;
                    sums[rt][reg] = m0 * attq.x + m1 * attq.y + m2 * attq.z + m3 * attq.w;
                }
#pragma unroll
            for (int rt = 0; rt < 2; ++rt)
#pragma unroll
                for (int reg = 0; reg < 4; ++reg) {
                    float p = sums[rt][reg];
                    p += __shfl_xor(p, 8);
                    p += __shfl_xor(p, 4);
                    p += __shfl_xor(p, 2);
                    p += __shfl_xor(p, 1);
                    if (lr == 0)
                        alpha[(size_t)pp[b][rt * 16 + lq * 4 + reg] * 4 + w] = p;
                }
        } else {
            // ---- acc2 MFMA with resident Wl2/Wr2 fragments
            f32x4 acc2[2][4] = {};
#pragma unroll
            for (int kb = 0; kb < 4; ++kb) {
                s16x8 afr0 = *(const s16x8*)&A[b][lr][kb * 32 + lq * 8];
                s16x8 afr1 = *(const s16x8*)&A[b][16 + lr][kb * 32 + lq * 8];
#pragma unroll
                for (int ct = 0; ct < 4; ++ct) {
                    acc2[0][ct] = __builtin_amdgcn_mfma_f32_16x16x32_bf16(afr0, wf[kb][ct], acc2[0][ct], 0, 0, 0);
                    acc2[1][ct] = __builtin_amdgcn_mfma_f32_16x16x32_bf16(afr1, wf[kb][ct], acc2[1][ct], 0, 0, 0);
                }
            }
#pragma unroll
            for (int rt = 0; rt < 2; ++rt)
#pragma unroll
                for (int reg = 0; reg < 4; ++reg) {
                    const int row = e0 + rt * 16 + lq * 4 + reg;
                    ushort4 o;
                    o.x = f2bs(acc2[rt][0][reg] + b2q.x);
                    o.y = f2bs(acc2[rt][1][reg] + b2q.y);
                    o.z = f2bs(acc2[rt][2][reg] + b2q.z);
                    o.w = f2bs(acc2[rt][3][reg] + b2q.w);
                    if (w < 2) *(ushort4*)&xl_e[(size_t)row * 128 + cb2 + lr * 4] = o;
                    else       *(ushort4*)&xrst[(size_t)row * 256 + cb2 + lr * 4] = o;
                }
        }
    }
}

// ---------------------------------------------------------------------------
// K4: layer-1 online-softmax + gather. One node per WAVE, 4 dims/lane.
// CSR payload arrays (src_csr, alpha_csr) -> sequential loads + ONE gather level.
__global__ __launch_bounds__(256) void k_fused1(
    const int* __restrict__ off, const int* __restrict__ srcc,
    const float* __restrict__ alphac,
    const u16* __restrict__ xl,
    const float* __restrict__ bias,
    float* __restrict__ out)
{
    const int wv = __builtin_amdgcn_readfirstlane(threadIdx.x >> 6);
    const int lane = threadIdx.x & 63;
    const int n = blockIdx.x * 4 + wv;
    const int c = lane * 4;            // dims c..c+3
    const int h = lane >> 4;           // head (64 dims / head, 16 lanes / head)
    const int beg = off[n], end = off[n + 1];
    float mx = -INFINITY, den = 0.f;
    float a0 = 0.f, a1 = 0.f, a2 = 0.f, a3 = 0.f;
    int i = beg;
    while (i < end) {
        const int rem = end - i;       // >= 1, wave-uniform
        int sa[8]; float pe[8];
#pragma unroll
        for (int k = 0; k < 8; ++k) {
            const int idx = i + (k < rem ? k : rem - 1);
            sa[k] = srcc[idx];
            pe[k] = alphac[(size_t)idx * 4 + h];
        }
        ushort4 xv[8];
#pragma unroll
        for (int k = 0; k < 8; ++k)
            xv[k] = *(const ushort4*)&xl[(size_t)sa[k] * 256 + c];
#pragma unroll
        for (int k = 0; k < 8; ++k) {
            const float p = (k < rem) ? pe[k] : -INFINITY;
            const float mnew = fmaxf(mx, p);
            const float sc = __expf(mx - mnew);
            const float ex = __expf(p - mnew);
            den = den * sc + ex;
            a0 = a0 * sc + ex * bs2f(xv[k].x);
            a1 = a1 * sc + ex * bs2f(xv[k].y);
            a2 = a2 * sc + ex * bs2f(xv[k].z);
            a3 = a3 * sc + ex * bs2f(xv[k].w);
            mx = mnew;
        }
        i += 8;
    }
    const float inv = 1.f / (den + 1e-16f);
    float4 r;
    r.x = a0 * inv + bias[c + 0];
    r.y = a1 * inv + bias[c + 1];
    r.z = a2 * inv + bias[c + 2];
    r.w = a3 * inv + bias[c + 3];
    if (lane < 32) *(float4*)&out[(size_t)n * 128 + c] = r;
    else           *(float4*)&out[XLG_OFF + (size_t)n * 128 + (c - 128)] = r;
}

// ---------------------------------------------------------------------------
// K5 (MFMA): proj = node_out @ e2n_We  [N,128] bf16
__global__ __launch_bounds__(256) void k_proj_gemm(
    const float* __restrict__ out_node, const u16* __restrict__ We2t,  // [128][256]
    u16* __restrict__ proj)
{
    __shared__ u16 A[32][260];
    const int n0 = blockIdx.x * 32;
    const int tid = threadIdx.x;
    for (int i = tid; i < 32 * 64; i += 256) {
        const int r = i >> 6, k4 = (i & 63) << 2;
        const float* srcp = (k4 < 128)
            ? &out_node[(size_t)(n0 + r) * 128 + k4]
            : &out_node[XLG_OFF + (size_t)(n0 + r) * 128 + (k4 - 128)];
        const float4 v = *(const float4*)srcp;
        ushort4 o; o.x = f2bs(v.x); o.y = f2bs(v.y); o.z = f2bs(v.z); o.w = f2bs(v.w);
        *(ushort4*)&A[r][k4] = o;
    }
    __syncthreads();
    const int w = tid >> 6, lane = tid & 63, lr = lane & 15, lq = lane >> 4;
    f32x4 acc[2][2] = {};
    for (int kb = 0; kb < 8; ++kb) {
        s16x8 afr0 = *(const s16x8*)&A[lr][kb * 32 + lq * 8];
        s16x8 afr1 = *(const s16x8*)&A[16 + lr][kb * 32 + lq * 8];
#pragma unroll
        for (int ct = 0; ct < 2; ++ct) {
            const int col = w * 32 + ct * 16 + lr;
            s16x8 bfr = *(const s16x8*)&We2t[(size_t)col * 256 + kb * 32 + lq * 8];
            acc[0][ct] = __builtin_amdgcn_mfma_f32_16x16x32_bf16(afr0, bfr, acc[0][ct], 0, 0, 0);
            acc[1][ct] = __builtin_amdgcn_mfma_f32_16x16x32_bf16(afr1, bfr, acc[1][ct], 0, 0, 0);
        }
    }
#pragma unroll
    for (int rt = 0; rt < 2; ++rt)
#pragma unroll
        for (int ct = 0; ct < 2; ++ct) {
            const int col = w * 32 + ct * 16 + lr;
#pragma unroll
            for (int reg = 0; reg < 4; ++reg) {
                const int row = n0 + rt * 16 + lq * 4 + reg;
                proj[(size_t)row * 128 + col] = f2bs(acc[rt][ct][reg]);
            }
        }
}

// ---------------------------------------------------------------------------
// K6: layer-2 fused logits + online softmax + aggregate. One row per WAVE,
// 2 dims/lane. CSR payload int2 {s, nf} -> sequential load + ONE gather level.
__global__ __launch_bounds__(256) void k_fused2(
    const int* __restrict__ off, const int2* __restrict__ sf2,
    const u16* __restrict__ xl,        // [E,128] trace@Wl2+bl2 bf16
    const u16* __restrict__ proj,      // [N,128] bf16
    const float* __restrict__ att,
    const float* __restrict__ bias,
    float* __restrict__ out)
{
    const int wv = __builtin_amdgcn_readfirstlane(threadIdx.x >> 6);
    const int lane = threadIdx.x & 63;
    const int d = blockIdx.x * 4 + wv;
    const int c = lane * 2;            // dims c, c+1 (head = lane>>4, 16 lanes/head)
    const u16* xrst = (const u16*)(out + XT_OFF);
    const unsigned xrp = *(const unsigned*)&xrst[(size_t)d * 256 + c];
    const float xr0 = bs2f((u16)(xrp & 0xffff));
    const float xr1 = bs2f((u16)(xrp >> 16));
    const float av0 = att[c], av1 = att[c + 1];
    const int beg = off[d], end = off[d + 1];
    float mx = -INFINITY, den = 0.f, a0 = 0.f, a1 = 0.f;
    int i = beg;
    while (i < end) {
        const int rem = end - i;       // >= 1, wave-uniform
        int2 sf[4];
#pragma unroll
        for (int k = 0; k < 4; ++k) sf[k] = sf2[i + (k < rem ? k : rem - 1)];
        unsigned xv[4], pv[4];
#pragma unroll
        for (int k = 0; k < 4; ++k) {
            xv[k] = *(const unsigned*)&xl[(size_t)sf[k].x * 128 + c];
            pv[k] = *(const unsigned*)&proj[(size_t)sf[k].y * 128 + c];
        }
#pragma unroll
        for (int k = 0; k < 4; ++k) {
            const float x0 = bs2f((u16)(xv[k] & 0xffff));
            const float x1 = bs2f((u16)(xv[k] >> 16));
            float m0 = x0 + xr0 + bs2f((u16)(pv[k] & 0xffff));
            float m1 = x1 + xr1 + bs2f((u16)(pv[k] >> 16));
            m0 = m0 > 0.f ? m0 : 0.2f * m0;
            m1 = m1 > 0.f ? m1 : 0.2f * m1;
            float pp = m0 * av0 + m1 * av1;
            pp += __shfl_xor(pp, 8, 16);
            pp += __shfl_xor(pp, 4, 16);
            pp += __shfl_xor(pp, 2, 16);
            pp += __shfl_xor(pp, 1, 16);
            const float p = (k < rem) ? pp : -INFINITY;
            const float mnew = fmaxf(mx, p);
            const float sc = __expf(mx - mnew);
            const float ex = __expf(p - mnew);
            den = den * sc + ex;
            a0 = a0 * sc + ex * x0;
            a1 = a1 * sc + ex * x1;
            mx = mnew;
        }
        i += 4;
    }
    const float inv = 1.f / (den + 1e-16f);
    float2 o2;
    o2.x = a0 * inv + bias[c];
    o2.y = a1 * inv + bias[c + 1];
    *(float2*)&out[XT_OFF + (size_t)d * 128 + c] = o2;
}

// ---------------------------------------------------------------------------
extern "C" void kernel_launch(void* const* d_in, const int* in_sizes, int n_in,
                              void* d_out, int out_size, void* d_ws, size_t ws_size,
                              hipStream_t stream)
{
    const float* x_node   = (const float*)d_in[0];
    const float* x_trace  = (const float*)d_in[1];
    const float* x_log    = (const float*)d_in[2];
    const int*   node_adj = (const int*)d_in[3];
    const int*   edge_adj = (const int*)d_in[4];
    const int*   efea     = (const int*)d_in[5];
    const float* n2n_Wl   = (const float*)d_in[6];
    const float* n2n_bl   = (const float*)d_in[7];
    const float* n2n_Wr   = (const float*)d_in[8];
    const float* n2n_br   = (const float*)d_in[9];
    const float* n2n_We   = (const float*)d_in[10];
    const float* n2n_att  = (const float*)d_in[11];
    const float* n2n_bias = (const float*)d_in[12];
    const float* e2n_Wl   = (const float*)d_in[13];
    const float* e2n_bl   = (const float*)d_in[14];
    const float* e2n_Wr   = (const float*)d_in[15];
    const float* e2n_br   = (const float*)d_in[16];
    const float* e2n_We   = (const float*)d_in[17];
    const float* e2n_att  = (const float*)d_in[18];
    const float* e2n_bias = (const float*)d_in[19];
    float* out = (float*)d_out;

    // ---- workspace layout (~51 MB) ----
    char* w = (char*)d_ws;
    int*  cnt1   = (int*)w;   w += (size_t)N * 4;        // zeroed below
    int*  cnt2   = (int*)w;   w += (size_t)E * 4;        // zeroed below
    int*  off1   = (int*)w;   w += (size_t)(N + 4) * 4;
    int*  cur1   = (int*)w;   w += (size_t)N * 4;
    int*  src1   = (int*)w;   w += (size_t)E * 4;        // CSR payload: src node
    int*  pos1   = (int*)w;   w += (size_t)E * 4;        // edge -> CSR pos
    float* alphac = (float*)w; w += (size_t)E * 4 * 4;   // CSR-ordered alpha [E][4]
    int*  off2   = (int*)w;   w += (size_t)(E + 4) * 4;
    int*  cur2   = (int*)w;   w += (size_t)E * 4;
    int2* sf2    = (int2*)w;  w += (size_t)E2 * 8;       // CSR payload: {s, nf}
    u16*  xl_n   = (u16*)w;   w += (size_t)N * 256 * 2;
    u16*  xr_n   = (u16*)w;   w += (size_t)N * 256 * 2;
    u16*  xl_e   = (u16*)w;   w += (size_t)E * 128 * 2;
    u16*  proj   = (u16*)w;   w += (size_t)N * 128 * 2;
    u16*  Wlt    = (u16*)w;   w += (size_t)65536 * 2;
    u16*  Wrt    = (u16*)w;   w += (size_t)65536 * 2;
    u16*  Wet    = (u16*)w;   w += (size_t)32768 * 2;
    u16*  Wl2t   = (u16*)w;   w += (size_t)16384 * 2;
    u16*  Wr2t   = (u16*)w;   w += (size_t)16384 * 2;
    u16*  We2t   = (u16*)w;   w += (size_t)32768 * 2;
    int*  tsum1  = (int*)w;   w += 64;                   // scan tile totals (N: 1)
    int*  tsum2  = (int*)w;   w += 64;                   // scan tile totals (E: 16)

    hipMemsetAsync(d_ws, 0, (size_t)(N + E) * 4, stream);

    // ---- prep + CSR builds ----
    k_prep<<<896, 256, 0, stream>>>(n2n_Wl, n2n_Wr, n2n_We, e2n_Wl, e2n_Wr, e2n_We,
                                    Wlt, Wrt, Wet, Wl2t, Wr2t, We2t);
    k_hist2<<<(E + E2) / 256, 256, 0, stream>>>(node_adj + E, edge_adj + E2, cnt1, cnt2);
    k_scan_part<<<N / 8192, 1024, 0, stream>>>(cnt1, off1, tsum1);
    k_scan_part<<<E / 8192, 1024, 0, stream>>>(cnt2, off2, tsum2);
    k_scan_add<<<N / 8192, 1024, 0, stream>>>(off1, cur1, tsum1, N / 8192, N);
    k_scan_add<<<E / 8192, 1024, 0, stream>>>(off2, cur2, tsum2, E / 8192, E);
    k_scatterM<<<(E + E2) / 256, 256, 0, stream>>>(node_adj, cur1, src1, pos1,
                                                   edge_adj, efea, cur2, sf2);

    // ---- layer 1 (+ layer-2 trace GEMMs fused into k_edge_mm) ----
    k_node_gemm<<<N / 32, 256, 0, stream>>>(x_node, x_log, Wlt, n2n_bl, Wrt, n2n_br,
                                            xl_n, xr_n);
    k_edge_mm<<<E / (32 * TPB_EDGE), 512, 0, stream>>>(x_trace, node_adj, pos1, xl_n, xr_n,
                                          Wet, Wl2t, e2n_bl, Wr2t, e2n_br,
                                          n2n_att, alphac, xl_e, (u16*)(out + XT_OFF));
    k_fused1<<<N / 4, 256, 0, stream>>>(off1, src1, alphac, xl_n, n2n_bias, out);

    // ---- layer 2 ----
    k_proj_gemm<<<N / 32, 256, 0, stream>>>(out, We2t, proj);
    k_fused2<<<E / 4, 256, 0, stream>>>(off2, sf2, xl_e, proj,
                                        e2n_att, e2n_bias, out);
}

// Round 10
// 387.630 us; speedup vs baseline: 1.4733x; 1.0329x over previous
//
#include <hip/hip_runtime.h>
#include <hip/hip_bf16.h>

// Problem constants (match reference)
constexpr int N    = 8192;     // nodes
constexpr int E    = 131072;   // node-graph edges == trace rows
constexpr int E2   = 524288;   // line-graph edges

constexpr size_t XT_OFF  = (size_t)N * 128;
constexpr size_t XLG_OFF = XT_OFF + (size_t)E * 128;

typedef unsigned short u16;
typedef short s16x8 __attribute__((ext_vector_type(8)));
typedef float f32x4 __attribute__((ext_vector_type(4)));

__device__ __forceinline__ u16 f2bs(float f) {   // f32 -> bf16 bits, RNE
    unsigned x = __float_as_uint(f);
    return (u16)((x + 0x7FFF + ((x >> 16) & 1)) >> 16);
}
__device__ __forceinline__ float bs2f(u16 u) {
    return __uint_as_float((unsigned)u << 16);
}

// ---------------------------------------------------------------------------
// K0 (merged): weight pre-transpose (gid < 229376) + CSR histograms (rest).
// Wet/Wl2t/Wr2t rows PERMUTED within each 64-col window so the MFMA output
// position (ct*16+lr) computes original col (lr*4+ct) -> ushort4 accesses.
__global__ __launch_bounds__(256) void k_setup(
    const float* __restrict__ Wl, const float* __restrict__ Wr,
    const float* __restrict__ We, const float* __restrict__ Wl2,
    const float* __restrict__ Wr2, const float* __restrict__ We2,
    u16* __restrict__ Wlt, u16* __restrict__ Wrt, u16* __restrict__ Wet,
    u16* __restrict__ Wl2t, u16* __restrict__ Wr2t, u16* __restrict__ We2t,
    const int* __restrict__ d1, const int* __restrict__ d2,
    int* __restrict__ c1, int* __restrict__ c2)
{
    const int gid = blockIdx.x * 256 + threadIdx.x;
    if (gid < 229376) {
        const float* src; u16* dst; int base, Kk, sh, perm;
        if      (gid <  65536) { src = Wl;  dst = Wlt;  base = 0;      Kk = 256; sh = 8; perm = 0; }
        else if (gid < 131072) { src = Wr;  dst = Wrt;  base = 65536;  Kk = 256; sh = 8; perm = 0; }
        else if (gid < 163840) { src = We;  dst = Wet;  base = 131072; Kk = 128; sh = 8; perm = 1; }
        else if (gid < 180224) { src = Wl2; dst = Wl2t; base = 163840; Kk = 128; sh = 7; perm = 1; }
        else if (gid < 196608) { src = Wr2; dst = Wr2t; base = 180224; Kk = 128; sh = 7; perm = 1; }
        else                   { src = We2; dst = We2t; base = 196608; Kk = 256; sh = 7; perm = 0; }
        const int l = gid - base;
        const int k = l >> sh, nn = l & ((1 << sh) - 1);
        int ns = nn;
        if (perm) ns = (nn & ~63) | ((nn & 3) << 4) | ((nn >> 2) & 15);
        dst[(size_t)ns * Kk + k] = f2bs(src[l]);
    } else {
        const int j = gid - 229376;
        if (j < E) atomicAdd(&c1[d1[j]], 1);
        else       atomicAdd(&c2[d2[j - E]], 1);
    }
}

// ---------------------------------------------------------------------------
// Merged 2-phase scans: block 0 -> N-array (1 tile); blocks 1..16 -> E-array.
__global__ __launch_bounds__(1024) void k_scan_part2(
    const int* __restrict__ cnt1, int* __restrict__ off1, int* __restrict__ tsum1,
    const int* __restrict__ cnt2, int* __restrict__ off2, int* __restrict__ tsum2)
{
    __shared__ int tile[8192];
    __shared__ int wsum[16];
    const int tid = threadIdx.x, lane = tid & 63, wv = tid >> 6;
    const int b = blockIdx.x;
    const int* cnt; int* off; int* tsums; int base, tb;
    if (b == 0) { cnt = cnt1; off = off1; tsums = tsum1; base = 0; tb = 0; }
    else        { cnt = cnt2; off = off2; tsums = tsum2; base = (b - 1) * 8192; tb = b - 1; }
    for (int i = tid; i < 8192; i += 1024) tile[i] = cnt[base + i];
    __syncthreads();
    const int st = tid * 8;
    int s = 0;
    for (int k = 0; k < 8; ++k) { int v = tile[st + k]; tile[st + k] = s; s += v; }
    const int tsum = s;
    int incl = s;
    for (int o = 1; o < 64; o <<= 1) {
        int v = __shfl_up(incl, o);
        if (lane >= o) incl += v;
    }
    if (lane == 63) wsum[wv] = incl;
    __syncthreads();
    int woff = 0;
    for (int wq = 0; wq < wv; ++wq) woff += wsum[wq];
    const int add = woff + incl - tsum;
    for (int k = 0; k < 8; ++k) off[base + st + k] = add + tile[st + k];
    if (tid == 1023) tsums[tb] = woff + incl;
}

__global__ __launch_bounds__(1024) void k_scan_add2(
    int* __restrict__ off1, int* __restrict__ cur1, const int* __restrict__ tsum1,
    int* __restrict__ off2, int* __restrict__ cur2, const int* __restrict__ tsum2)
{
    const int b = blockIdx.x;
    if (b == 0) {
        const int base = threadIdx.x * 8;
#pragma unroll
        for (int k = 0; k < 8; ++k) cur1[base + k] = off1[base + k];
        if (threadIdx.x == 1023) off1[N] = tsum1[0];
    } else {
        const int tb = b - 1;
        int carry = 0;
        for (int t = 0; t < tb; ++t) carry += tsum2[t];
        const int base = tb * 8192 + threadIdx.x * 8;
#pragma unroll
        for (int k = 0; k < 8; ++k) {
            int v = off2[base + k] + carry;
            off2[base + k] = v;
            cur2[base + k] = v;
        }
        if (tb == E / 8192 - 1 && threadIdx.x == 1023)
            off2[E] = carry + tsum2[tb];
    }
}

// merged scatter: layer-1 (payload src + inverse map) and layer-2 ({s, nf})
__global__ void k_scatterM(
    const int* __restrict__ adj, int* __restrict__ cur1,
    int* __restrict__ srcc, int* __restrict__ pos1,
    const int* __restrict__ eadj, const int* __restrict__ efea,
    int* __restrict__ cur2, int2* __restrict__ sf2)
{
    int i = blockIdx.x * 256 + threadIdx.x;
    if (i < E) {
        int pos = atomicAdd(&cur1[adj[E + i]], 1);
        srcc[pos] = adj[i];
        pos1[i] = pos;
    } else {
        int j = i - E;
        int pos = atomicAdd(&cur2[eadj[E2 + j]], 1);
        sf2[pos] = make_int2(eadj[j], efea[j]);
    }
}

// ---------------------------------------------------------------------------
// K1 (MFMA): xl_n/xr_n = concat(x_node,x_log) @ {Wl,Wr} + bias -> bf16 [N,256]
__global__ __launch_bounds__(256) void k_node_gemm(
    const float* __restrict__ x_node, const float* __restrict__ x_log,
    const u16* __restrict__ Wlt, const float* __restrict__ bl,
    const u16* __restrict__ Wrt, const float* __restrict__ br,
    u16* __restrict__ xl, u16* __restrict__ xr)
{
    __shared__ u16 A[32][260];
    const int n0 = blockIdx.x * 32;
    const int tid = threadIdx.x;
    for (int i = tid; i < 32 * 64; i += 256) {
        const int r = i >> 6, k4 = (i & 63) << 2;
        const float* srcp = (k4 < 128) ? &x_node[(size_t)(n0 + r) * 128 + k4]
                                       : &x_log [(size_t)(n0 + r) * 128 + (k4 - 128)];
        const float4 v = *(const float4*)srcp;
        ushort4 o; o.x = f2bs(v.x); o.y = f2bs(v.y); o.z = f2bs(v.z); o.w = f2bs(v.w);
        *(ushort4*)&A[r][k4] = o;
    }
    __syncthreads();
    const int w = tid >> 6, lane = tid & 63, lr = lane & 15, lq = lane >> 4;
    const u16* Wt     = (w < 2) ? Wlt : Wrt;
    const float* bias = (w < 2) ? bl : br;
    u16* outp         = (w < 2) ? xl : xr;
    const int cb = (w & 1) * 128;
    f32x4 acc[2][8] = {};
    for (int kb = 0; kb < 8; ++kb) {
        s16x8 afr0 = *(const s16x8*)&A[lr][kb * 32 + lq * 8];
        s16x8 afr1 = *(const s16x8*)&A[16 + lr][kb * 32 + lq * 8];
#pragma unroll
        for (int ct = 0; ct < 8; ++ct) {
            const int n = cb + ct * 16 + lr;
            s16x8 bfr = *(const s16x8*)&Wt[(size_t)n * 256 + kb * 32 + lq * 8];
            acc[0][ct] = __builtin_amdgcn_mfma_f32_16x16x32_bf16(afr0, bfr, acc[0][ct], 0, 0, 0);
            acc[1][ct] = __builtin_amdgcn_mfma_f32_16x16x32_bf16(afr1, bfr, acc[1][ct], 0, 0, 0);
        }
    }
#pragma unroll
    for (int rt = 0; rt < 2; ++rt)
#pragma unroll
        for (int ct = 0; ct < 8; ++ct) {
            const int col = cb + ct * 16 + lr;
            const float bv = bias[col];
#pragma unroll
            for (int reg = 0; reg < 4; ++reg) {
                const int row = n0 + rt * 16 + lq * 4 + reg;
                outp[(size_t)row * 256 + col] = f2bs(acc[rt][ct][reg] + bv);
            }
        }
}

// ---------------------------------------------------------------------------
// K3 (MFMA, fused, wave-specialized, MULTI-TILE): 512 threads, TPB_EDGE tiles
// of 32 edges per block. Weight fragments resident in registers; LDS
// double-buffered; one barrier per tile.
//   waves 0-3 (role 0): layer-1 logits (early gathers + Wet MFMA + reduce)
//   waves 4-7 (role 1): layer-2 GEMMs (Wl2 -> xl_e, Wr2 -> xrst staging)
constexpr int TPB_EDGE = 4;    // tiles per block (grid = 1024)
__global__ __launch_bounds__(512) void k_edge_mm(
    const float* __restrict__ x_trace,
    const int* __restrict__ adj,          // [2,E] src then dst
    const int* __restrict__ pos1,
    const u16* __restrict__ xl_n, const u16* __restrict__ xr_n,  // [N,256] bf16
    const u16* __restrict__ Wet,                                  // [256][128] perm
    const u16* __restrict__ Wl2t, const float* __restrict__ bl2,  // [128][128] perm
    const u16* __restrict__ Wr2t, const float* __restrict__ br2,
    const float* __restrict__ att,
    float* __restrict__ alpha, u16* __restrict__ xl_e, u16* __restrict__ xrst)
{
    __shared__ u16 A[2][32][132];
    __shared__ int ss[2][32], dd[2][32], pp[2][32];
    const int tid = threadIdx.x;
    const int w8 = tid >> 6;           // 0..7
    const int role = w8 >> 2;          // 0: logits, 1: layer-2 GEMM
    const int w = w8 & 3;
    const int lane = tid & 63, lr = lane & 15, lq = lane >> 4;

    // ---- resident weight fragments: 16 x s16x8 = 64 VGPR, loaded once
    s16x8 wf[4][4];
    const int cb2 = (w & 1) * 64;
    if (role == 0) {
#pragma unroll
        for (int kb = 0; kb < 4; ++kb)
#pragma unroll
            for (int ct = 0; ct < 4; ++ct)
                wf[kb][ct] = *(const s16x8*)&Wet[(size_t)(w * 64 + ct * 16 + lr) * 128 + kb * 32 + lq * 8];
    } else {
        const u16* Wt2 = (w < 2) ? Wl2t : Wr2t;
#pragma unroll
        for (int kb = 0; kb < 4; ++kb)
#pragma unroll
            for (int ct = 0; ct < 4; ++ct)
                wf[kb][ct] = *(const s16x8*)&Wt2[(size_t)(cb2 + ct * 16 + lr) * 128 + kb * 32 + lq * 8];
    }
    const float4 attq = *(const float4*)&att[w * 64 + lr * 4];
    const float4 b2q  = (role == 0) ? make_float4(0, 0, 0, 0)
        : *(const float4*)&((w < 2) ? bl2 : br2)[cb2 + lr * 4];

    const int tile0 = blockIdx.x * TPB_EDGE;
    // prologue: stage tile0 into buffer 0
    {
        const int e0s = tile0 * 32;
        const int i0 = tid, i1 = tid + 512;
        {
            const int r = i0 >> 5, k4 = (i0 & 31) << 2;
            const float4 v = *(const float4*)&x_trace[(size_t)(e0s + r) * 128 + k4];
            ushort4 o; o.x = f2bs(v.x); o.y = f2bs(v.y); o.z = f2bs(v.z); o.w = f2bs(v.w);
            *(ushort4*)&A[0][r][k4] = o;
        }
        {
            const int r = i1 >> 5, k4 = (i1 & 31) << 2;
            const float4 v = *(const float4*)&x_trace[(size_t)(e0s + r) * 128 + k4];
            ushort4 o; o.x = f2bs(v.x); o.y = f2bs(v.y); o.z = f2bs(v.z); o.w = f2bs(v.w);
            *(ushort4*)&A[0][r][k4] = o;
        }
        if (tid < 32) {
            ss[0][tid] = adj[e0s + tid];
            dd[0][tid] = adj[E + e0s + tid];
            pp[0][tid] = pos1[e0s + tid];
        }
    }

    for (int t = 0; t < TPB_EDGE; ++t) {
        __syncthreads();                       // buf b ready; buf b^1 free
        const int b = t & 1;
        const int e0 = (tile0 + t) * 32;
        // ---- issue stage of tile t+1 into the other buffer (overlaps compute)
        if (t + 1 < TPB_EDGE) {
            const int e0s = (tile0 + t + 1) * 32;
            const int bn = b ^ 1;
            {
                const int r = tid >> 5, k4 = (tid & 31) << 2;
                const float4 v = *(const float4*)&x_trace[(size_t)(e0s + r) * 128 + k4];
                ushort4 o; o.x = f2bs(v.x); o.y = f2bs(v.y); o.z = f2bs(v.z); o.w = f2bs(v.w);
                *(ushort4*)&A[bn][r][k4] = o;
            }
            {
                const int i1 = tid + 512;
                const int r = i1 >> 5, k4 = (i1 & 31) << 2;
                const float4 v = *(const float4*)&x_trace[(size_t)(e0s + r) * 128 + k4];
                ushort4 o; o.x = f2bs(v.x); o.y = f2bs(v.y); o.z = f2bs(v.z); o.w = f2bs(v.w);
                *(ushort4*)&A[bn][r][k4] = o;
            }
            if (tid < 32) {
                ss[bn][tid] = adj[e0s + tid];
                dd[bn][tid] = adj[E + e0s + tid];
                pp[bn][tid] = pos1[e0s + tid];
            }
        }

        if (role == 0) {
            // ---- EARLY gathers (xl_n/xr_n) for this tile
            const int co = w * 64 + lr * 4;
            ushort4 xlv[2][4], xrv[2][4];
#pragma unroll
            for (int rt = 0; rt < 2; ++rt)
#pragma unroll
                for (int reg = 0; reg < 4; ++reg) {
                    const int rowt = rt * 16 + lq * 4 + reg;
                    xlv[rt][reg] = *(const ushort4*)&xl_n[(size_t)ss[b][rowt] * 256 + co];
                    xrv[rt][reg] = *(const ushort4*)&xr_n[(size_t)dd[b][rowt] * 256 + co];
                }
            // ---- acc1 MFMA with resident Wet fragments
            f32x4 acc1[2][4] = {};
#pragma unroll
            for (int kb = 0; kb < 4; ++kb) {
                s16x8 afr0 = *(const s16x8*)&A[b][lr][kb * 32 + lq * 8];
                s16x8 afr1 = *(const s16x8*)&A[b][16 + lr][kb * 32 + lq * 8];
#pragma unroll
                for (int ct = 0; ct < 4; ++ct) {
                    acc1[0][ct] = __builtin_amdgcn_mfma_f32_16x16x32_bf16(afr0, wf[kb][ct], acc1[0][ct], 0, 0, 0);
                    acc1[1][ct] = __builtin_amdgcn_mfma_f32_16x16x32_bf16(afr1, wf[kb][ct], acc1[1][ct], 0, 0, 0);
                }
            }
            // ---- logits: combine, leaky, dot(att), 16-lane reduce
            float sums[2][4];
#pragma unroll
            for (int rt = 0; rt < 2; ++rt)
#pragma unroll
                for (int reg = 0; reg < 4; ++reg) {
                    float m0 = acc1[rt][0][reg] + bs2f(xlv[rt][reg].x) + bs2f(xrv[rt][reg].x);
                    float m1 = acc1[rt][1][reg] + bs2f(xlv[rt][reg].y) + bs2f(xrv[rt][reg].y);
                    float m2 = acc1[rt][2][reg] + bs2f(xlv[rt][reg].z) + bs2f(xrv[rt][reg].z);
                    float m3 = acc1[rt][3][reg] + bs2f(xlv[rt][reg].w) + bs2f(xrv[rt][reg].w);
                    m0 = m0 > 0.f ? m0 : 0.2f * m0;
                    m1 = m1 > 0.f ? m1 : 0.2f * m1;
                    m2 = m2 > 0.f ? m2 : 0.2f * m2;
                    m3 = m3 > 0.f ? m3 : 0.2f * m3;
                    sums[rt][reg] = m0 * attq.x + m1 * attq.y + m2 * attq.z + m3 * attq.w;
                }
#pragma unroll
            for (int rt = 0; rt < 2; ++rt)
#pragma unroll
                for (int reg = 0; reg < 4; ++reg) {
                    float p = sums[rt][reg];
                    p += __shfl_xor(p, 8);
                    p += __shfl_xor(p, 4);
                    p += __shfl_xor(p, 2);
                    p += __shfl_xor(p, 1);
                    if (lr == 0)
                        alpha[(size_t)pp[b][rt * 16 + lq * 4 + reg] * 4 + w] = p;
                }
        } else {
            // ---- acc2 MFMA with resident Wl2/Wr2 fragments
            f32x4 acc2[2][4] = {};
#pragma unroll
            for (int kb = 0; kb < 4; ++kb) {
                s16x8 afr0 = *(const s16x8*)&A[b][lr][kb * 32 + lq * 8];
                s16x8 afr1 = *(const s16x8*)&A[b][16 + lr][kb * 32 + lq * 8];
#pragma unroll
                for (int ct = 0; ct < 4; ++ct) {
                    acc2[0][ct] = __builtin_amdgcn_mfma_f32_16x16x32_bf16(afr0, wf[kb][ct], acc2[0][ct], 0, 0, 0);
                    acc2[1][ct] = __builtin_amdgcn_mfma_f32_16x16x32_bf16(afr1, wf[kb][ct], acc2[1][ct], 0, 0, 0);
                }
            }
#pragma unroll
            for (int rt = 0; rt < 2; ++rt)
#pragma unroll
                for (int reg = 0; reg < 4; ++reg) {
                    const int row = e0 + rt * 16 + lq * 4 + reg;
                    ushort4 o;
                    o.x = f2bs(acc2[rt][0][reg] + b2q.x);
                    o.y = f2bs(acc2[rt][1][reg] + b2q.y);
                    o.z = f2bs(acc2[rt][2][reg] + b2q.z);
                    o.w = f2bs(acc2[rt][3][reg] + b2q.w);
                    if (w < 2) *(ushort4*)&xl_e[(size_t)row * 128 + cb2 + lr * 4] = o;
                    else       *(ushort4*)&xrst[(size_t)row * 256 + cb2 + lr * 4] = o;
                }
        }
    }
}

// ---------------------------------------------------------------------------
// K4 (fused with proj): layer-1 online-softmax + gather (one node per WAVE,
// 16 waves = 16 nodes/block), then in-block proj MFMA epilogue:
// proj[16 rows] = out_rows[16,256] @ e2n_We  (identical math to old k_proj).
__global__ __launch_bounds__(1024) void k_fused1(
    const int* __restrict__ off, const int* __restrict__ srcc,
    const float* __restrict__ alphac,
    const u16* __restrict__ xl,
    const float* __restrict__ bias,
    const u16* __restrict__ We2t,      // [128][256] (row-major, K inner)
    float* __restrict__ out, u16* __restrict__ proj)
{
    __shared__ u16 Alds[16][264];
    const int wv = __builtin_amdgcn_readfirstlane(threadIdx.x >> 6);
    const int lane = threadIdx.x & 63;
    const int n0 = blockIdx.x * 16;
    const int n = n0 + wv;
    const int c = lane * 4;            // dims c..c+3
    const int h = lane >> 4;           // head (64 dims / head, 16 lanes / head)
    const int beg = off[n], end = off[n + 1];
    float mx = -INFINITY, den = 0.f;
    float a0 = 0.f, a1 = 0.f, a2 = 0.f, a3 = 0.f;
    int i = beg;
    while (i < end) {
        const int rem = end - i;       // >= 1, wave-uniform
        int sa[8]; float pe[8];
#pragma unroll
        for (int k = 0; k < 8; ++k) {
            const int idx = i + (k < rem ? k : rem - 1);
            sa[k] = srcc[idx];
            pe[k] = alphac[(size_t)idx * 4 + h];
        }
        ushort4 xv[8];
#pragma unroll
        for (int k = 0; k < 8; ++k)
            xv[k] = *(const ushort4*)&xl[(size_t)sa[k] * 256 + c];
#pragma unroll
        for (int k = 0; k < 8; ++k) {
            const float p = (k < rem) ? pe[k] : -INFINITY;
            const float mnew = fmaxf(mx, p);
            const float sc = __expf(mx - mnew);
            const float ex = __expf(p - mnew);
            den = den * sc + ex;
            a0 = a0 * sc + ex * bs2f(xv[k].x);
            a1 = a1 * sc + ex * bs2f(xv[k].y);
            a2 = a2 * sc + ex * bs2f(xv[k].z);
            a3 = a3 * sc + ex * bs2f(xv[k].w);
            mx = mnew;
        }
        i += 8;
    }
    const float inv = 1.f / (den + 1e-16f);
    float4 r;
    r.x = a0 * inv + bias[c + 0];
    r.y = a1 * inv + bias[c + 1];
    r.z = a2 * inv + bias[c + 2];
    r.w = a3 * inv + bias[c + 3];
    if (lane < 32) *(float4*)&out[(size_t)n * 128 + c] = r;
    else           *(float4*)&out[XLG_OFF + (size_t)n * 128 + (c - 128)] = r;
    // stage bf16 row for the proj MFMA (same values as out write)
    {
        ushort4 o; o.x = f2bs(r.x); o.y = f2bs(r.y); o.z = f2bs(r.z); o.w = f2bs(r.w);
        *(ushort4*)&Alds[wv][c] = o;
    }
    __syncthreads();
    // ---- proj epilogue: 8 waves, each 16 cols (same indexing as old k_proj)
    if (wv < 8) {
        const int lr = lane & 15, lq = lane >> 4;
        const int colb = wv * 16;
        f32x4 acc = {};
        for (int kb = 0; kb < 8; ++kb) {
            s16x8 afr = *(const s16x8*)&Alds[lr][kb * 32 + lq * 8];
            s16x8 bfr = *(const s16x8*)&We2t[(size_t)(colb + lr) * 256 + kb * 32 + lq * 8];
            acc = __builtin_amdgcn_mfma_f32_16x16x32_bf16(afr, bfr, acc, 0, 0, 0);
        }
#pragma unroll
        for (int reg = 0; reg < 4; ++reg) {
            const int row = n0 + lq * 4 + reg;
            proj[(size_t)row * 128 + colb + lr] = f2bs(acc[reg]);
        }
    }
}

// ---------------------------------------------------------------------------
// K6: layer-2 fused logits + online softmax + aggregate. One row per WAVE,
// 2 dims/lane. CSR payload int2 {s, nf} -> sequential load + ONE gather level.
__global__ __launch_bounds__(256) void k_fused2(
    const int* __restrict__ off, const int2* __restrict__ sf2,
    const u16* __restrict__ xl,        // [E,128] trace@Wl2+bl2 bf16
    const u16* __restrict__ proj,      // [N,128] bf16
    const float* __restrict__ att,
    const float* __restrict__ bias,
    float* __restrict__ out)
{
    const int wv = __builtin_amdgcn_readfirstlane(threadIdx.x >> 6);
    const int lane = threadIdx.x & 63;
    const int d = blockIdx.x * 4 + wv;
    const int c = lane * 2;            // dims c, c+1 (head = lane>>4, 16 lanes/head)
    const u16* xrst = (const u16*)(out + XT_OFF);
    const unsigned xrp = *(const unsigned*)&xrst[(size_t)d * 256 + c];
    const float xr0 = bs2f((u16)(xrp & 0xffff));
    const float xr1 = bs2f((u16)(xrp >> 16));
    const float av0 = att[c], av1 = att[c + 1];
    const int beg = off[d], end = off[d + 1];
    float mx = -INFINITY, den = 0.f, a0 = 0.f, a1 = 0.f;
    int i = beg;
    while (i < end) {
        const int rem = end - i;       // >= 1, wave-uniform
        int2 sf[4];
#pragma unroll
        for (int k = 0; k < 4; ++k) sf[k] = sf2[i + (k < rem ? k : rem - 1)];
        unsigned xv[4], pv[4];
#pragma unroll
        for (int k = 0; k < 4; ++k) {
            xv[k] = *(const unsigned*)&xl[(size_t)sf[k].x * 128 + c];
            pv[k] = *(const unsigned*)&proj[(size_t)sf[k].y * 128 + c];
        }
#pragma unroll
        for (int k = 0; k < 4; ++k) {
            const float x0 = bs2f((u16)(xv[k] & 0xffff));
            const float x1 = bs2f((u16)(xv[k] >> 16));
            float m0 = x0 + xr0 + bs2f((u16)(pv[k] & 0xffff));
            float m1 = x1 + xr1 + bs2f((u16)(pv[k] >> 16));
            m0 = m0 > 0.f ? m0 : 0.2f * m0;
            m1 = m1 > 0.f ? m1 : 0.2f * m1;
            float pp = m0 * av0 + m1 * av1;
            pp += __shfl_xor(pp, 8, 16);
            pp += __shfl_xor(pp, 4, 16);
            pp += __shfl_xor(pp, 2, 16);
            pp += __shfl_xor(pp, 1, 16);
            const float p = (k < rem) ? pp : -INFINITY;
            const float mnew = fmaxf(mx, p);
            const float sc = __expf(mx - mnew);
            const float ex = __expf(p - mnew);
            den = den * sc + ex;
            a0 = a0 * sc + ex * x0;
            a1 = a1 * sc + ex * x1;
            mx = mnew;
        }
        i += 4;
    }
    const float inv = 1.f / (den + 1e-16f);
    float2 o2;
    o2.x = a0 * inv + bias[c];
    o2.y = a1 * inv + bias[c + 1];
    *(float2*)&out[XT_OFF + (size_t)d * 128 + c] = o2;
}

// ---------------------------------------------------------------------------
extern "C" void kernel_launch(void* const* d_in, const int* in_sizes, int n_in,
                              void* d_out, int out_size, void* d_ws, size_t ws_size,
                              hipStream_t stream)
{
    const float* x_node   = (const float*)d_in[0];
    const float* x_trace  = (const float*)d_in[1];
    const float* x_log    = (const float*)d_in[2];
    const int*   node_adj = (const int*)d_in[3];
    const int*   edge_adj = (const int*)d_in[4];
    const int*   efea     = (const int*)d_in[5];
    const float* n2n_Wl   = (const float*)d_in[6];
    const float* n2n_bl   = (const float*)d_in[7];
    const float* n2n_Wr   = (const float*)d_in[8];
    const float* n2n_br   = (const float*)d_in[9];
    const float* n2n_We   = (const float*)d_in[10];
    const float* n2n_att  = (const float*)d_in[11];
    const float* n2n_bias = (const float*)d_in[12];
    const float* e2n_Wl   = (const float*)d_in[13];
    const float* e2n_bl   = (const float*)d_in[14];
    const float* e2n_Wr   = (const float*)d_in[15];
    const float* e2n_br   = (const float*)d_in[16];
    const float* e2n_We   = (const float*)d_in[17];
    const float* e2n_att  = (const float*)d_in[18];
    const float* e2n_bias = (const float*)d_in[19];
    float* out = (float*)d_out;

    // ---- workspace layout (~51 MB) ----
    char* w = (char*)d_ws;
    int*  cnt1   = (int*)w;   w += (size_t)N * 4;        // zeroed below
    int*  cnt2   = (int*)w;   w += (size_t)E * 4;        // zeroed below
    int*  off1   = (int*)w;   w += (size_t)(N + 4) * 4;
    int*  cur1   = (int*)w;   w += (size_t)N * 4;
    int*  src1   = (int*)w;   w += (size_t)E * 4;        // CSR payload: src node
    int*  pos1   = (int*)w;   w += (size_t)E * 4;        // edge -> CSR pos
    float* alphac = (float*)w; w += (size_t)E * 4 * 4;   // CSR-ordered alpha [E][4]
    int*  off2   = (int*)w;   w += (size_t)(E + 4) * 4;
    int*  cur2   = (int*)w;   w += (size_t)E * 4;
    int2* sf2    = (int2*)w;  w += (size_t)E2 * 8;       // CSR payload: {s, nf}
    u16*  xl_n   = (u16*)w;   w += (size_t)N * 256 * 2;
    u16*  xr_n   = (u16*)w;   w += (size_t)N * 256 * 2;
    u16*  xl_e   = (u16*)w;   w += (size_t)E * 128 * 2;
    u16*  proj   = (u16*)w;   w += (size_t)N * 128 * 2;
    u16*  Wlt    = (u16*)w;   w += (size_t)65536 * 2;
    u16*  Wrt    = (u16*)w;   w += (size_t)65536 * 2;
    u16*  Wet    = (u16*)w;   w += (size_t)32768 * 2;
    u16*  Wl2t   = (u16*)w;   w += (size_t)16384 * 2;
    u16*  Wr2t   = (u16*)w;   w += (size_t)16384 * 2;
    u16*  We2t   = (u16*)w;   w += (size_t)32768 * 2;
    int*  tsum1  = (int*)w;   w += 64;                   // scan tile totals (N: 1)
    int*  tsum2  = (int*)w;   w += 64;                   // scan tile totals (E: 16)

    hipMemsetAsync(d_ws, 0, (size_t)(N + E) * 4, stream);

    // ---- setup (prep + hist merged) + CSR builds ----
    k_setup<<<3456, 256, 0, stream>>>(n2n_Wl, n2n_Wr, n2n_We, e2n_Wl, e2n_Wr, e2n_We,
                                      Wlt, Wrt, Wet, Wl2t, Wr2t, We2t,
                                      node_adj + E, edge_adj + E2, cnt1, cnt2);
    k_scan_part2<<<1 + E / 8192, 1024, 0, stream>>>(cnt1, off1, tsum1, cnt2, off2, tsum2);
    k_scan_add2<<<1 + E / 8192, 1024, 0, stream>>>(off1, cur1, tsum1, off2, cur2, tsum2);
    k_scatterM<<<(E + E2) / 256, 256, 0, stream>>>(node_adj, cur1, src1, pos1,
                                                   edge_adj, efea, cur2, sf2);

    // ---- layer 1 (+ layer-2 trace GEMMs fused into k_edge_mm) ----
    k_node_gemm<<<N / 32, 256, 0, stream>>>(x_node, x_log, Wlt, n2n_bl, Wrt, n2n_br,
                                            xl_n, xr_n);
    k_edge_mm<<<E / (32 * TPB_EDGE), 512, 0, stream>>>(x_trace, node_adj, pos1, xl_n, xr_n,
                                          Wet, Wl2t, e2n_bl, Wr2t, e2n_br,
                                          n2n_att, alphac, xl_e, (u16*)(out + XT_OFF));
    k_fused1<<<N / 16, 1024, 0, stream>>>(off1, src1, alphac, xl_n, n2n_bias,
                                          We2t, out, proj);

    // ---- layer 2 ----
    k_fused2<<<E / 4, 256, 0, stream>>>(off2, sf2, xl_e, proj,
                                        e2n_att, e2n_bias, out);
}